// Round 1
// baseline (597.915 us; speedup 1.0000x reference)
//
#include <hip/hip_runtime.h>
#include <math.h>

#define EPSF 1.1920929e-07f

// ---------------------------------------------------------------------------
// Generic K=256 GEMM: C[m, n] = A[m, :] . W[n, :] + bias[n], 64x64 tiles,
// 256 threads, 4x4 accum per thread, transposed LDS tiles for float4 reads.
// Three weight regions (per-block uniform select) so q|kv|sr fuse into one
// pass; exact GELU applied for n0 >= geluFrom (the sr region).
// ---------------------------------------------------------------------------
__global__ __launch_bounds__(256) void gemm_k256(
    const float* __restrict__ A, int lda,
    const float* __restrict__ W0, const float* __restrict__ B0,
    const float* __restrict__ W1, const float* __restrict__ B1,
    const float* __restrict__ W2, const float* __restrict__ B2,
    int r1, int r2, int geluFrom,
    float* __restrict__ C, int ldc)
{
    __shared__ float As[16][68];   // [k][m], pad 68 -> 16B-aligned rows, 2-way max bank alias
    __shared__ float Ws[16][68];   // [k][n]
    const int m0 = blockIdx.y << 6;
    const int n0 = blockIdx.x << 6;
    const float* Wp; const float* Bp; int noff;
    if (n0 < r1)      { Wp = W0; Bp = B0; noff = 0;  }
    else if (n0 < r2) { Wp = W1; Bp = B1; noff = r1; }
    else              { Wp = W2; Bp = B2; noff = r2; }
    const int t  = threadIdx.x;
    const int lr = t >> 2;          // 0..63
    const int lk = (t & 3) << 2;    // 0,4,8,12
    const int tx = t & 15;
    const int ty = t >> 4;
    const float* Arow = A + (size_t)(m0 + lr) * lda + lk;
    const float* Wrow = Wp + ((size_t)(n0 - noff + lr) << 8) + lk;
    float acc[4][4] = {{0.f}};
    for (int k0 = 0; k0 < 256; k0 += 16) {
        float4 av = *(const float4*)(Arow + k0);
        float4 wv = *(const float4*)(Wrow + k0);
        __syncthreads();
        As[lk+0][lr] = av.x; As[lk+1][lr] = av.y; As[lk+2][lr] = av.z; As[lk+3][lr] = av.w;
        Ws[lk+0][lr] = wv.x; Ws[lk+1][lr] = wv.y; Ws[lk+2][lr] = wv.z; Ws[lk+3][lr] = wv.w;
        __syncthreads();
#pragma unroll
        for (int kk = 0; kk < 16; ++kk) {
            float4 a = *(const float4*)&As[kk][ty << 2];
            float4 b = *(const float4*)&Ws[kk][tx << 2];
            acc[0][0] += a.x*b.x; acc[0][1] += a.x*b.y; acc[0][2] += a.x*b.z; acc[0][3] += a.x*b.w;
            acc[1][0] += a.y*b.x; acc[1][1] += a.y*b.y; acc[1][2] += a.y*b.z; acc[1][3] += a.y*b.w;
            acc[2][0] += a.z*b.x; acc[2][1] += a.z*b.y; acc[2][2] += a.z*b.z; acc[2][3] += a.z*b.w;
            acc[3][0] += a.w*b.x; acc[3][1] += a.w*b.y; acc[3][2] += a.w*b.z; acc[3][3] += a.w*b.w;
        }
    }
    const bool doGelu = (n0 >= geluFrom);
#pragma unroll
    for (int i = 0; i < 4; ++i) {
        size_t mrow = (size_t)(m0 + (ty << 2) + i) * ldc;
#pragma unroll
        for (int j = 0; j < 4; ++j) {
            int n = n0 + (tx << 2) + j;
            float v = acc[i][j] + Bp[n - noff];
            if (doGelu) v = 0.5f * v * (1.0f + erff(v * 0.70710678118654752f));
            C[mrow + n] = v;
        }
    }
}

// ---------------------------------------------------------------------------
// In-place per-head L2 normalize of q (cols 0..255) and k (cols 256..511)
// of the fused (16384,1024) buffer. One block per token row.
// ---------------------------------------------------------------------------
__global__ __launch_bounds__(256) void normqk_kernel(float* __restrict__ buf)
{
    const int r = blockIdx.x, t = threadIdx.x;
    const size_t base = (size_t)r << 10;
    float q = buf[base + t];
    float s = q * q;
    for (int off = 16; off; off >>= 1) s += __shfl_xor(s, off, 32);
    buf[base + t] = q / fmaxf(sqrtf(s), EPSF);
    float k = buf[base + 256 + t];
    float s2 = k * k;
    for (int off = 16; off; off >>= 1) s2 += __shfl_xor(s2, off, 32);
    buf[base + 256 + t] = k / fmaxf(sqrtf(s2), EPSF);
}

// ---------------------------------------------------------------------------
// MoE gating: per token, 10 dots (4 routed, 2 mix, 4 shared), softmaxes,
// top-2 routed renorm, emit 8 per-head multipliers.
// ---------------------------------------------------------------------------
__global__ __launch_bounds__(64) void gate_kernel(
    const float* __restrict__ x,
    const float* __restrict__ wg,   // (4,256) routed
    const float* __restrict__ wg0,  // (2,256)
    const float* __restrict__ wg1,  // (4,256) shared
    float* __restrict__ gate)       // (16384,8)
{
    __shared__ float xs[256];
    __shared__ float dots[10];
    const int r = blockIdx.x;
    const int t = threadIdx.x;
    const float* xr = x + ((size_t)r << 8);
    xs[t] = xr[t]; xs[t+64] = xr[t+64]; xs[t+128] = xr[t+128]; xs[t+192] = xr[t+192];
    __syncthreads();
    for (int f = 0; f < 10; ++f) {
        const float* wf = (f < 4) ? (wg + f*256) : (f < 6) ? (wg0 + (f-4)*256) : (wg1 + (f-6)*256);
        float s = xs[t]*wf[t] + xs[t+64]*wf[t+64] + xs[t+128]*wf[t+128] + xs[t+192]*wf[t+192];
        for (int off = 32; off; off >>= 1) s += __shfl_xor(s, off, 64);
        if (t == 0) dots[f] = s;
    }
    __syncthreads();
    if (t == 0) {
        float e[4];
        float m = fmaxf(fmaxf(dots[0],dots[1]), fmaxf(dots[2],dots[3]));
        float ssum = 0.f;
        for (int i = 0; i < 4; ++i) { e[i] = expf(dots[i]-m); ssum += e[i]; }
        for (int i = 0; i < 4; ++i) e[i] /= ssum;
        int i1 = 0;
        for (int i = 1; i < 4; ++i) if (e[i] > e[i1]) i1 = i;       // first-index ties
        int i2 = -1;
        for (int i = 0; i < 4; ++i) if (i != i1 && (i2 < 0 || e[i] > e[i2])) i2 = i;
        float rs = fmaxf(e[i1] + e[i2], EPSF);
        float rg[4] = {0.f,0.f,0.f,0.f};
        rg[i1] = e[i1] / rs * 2.f;
        rg[i2] = e[i2] / rs * 2.f;
        float sh[4];
        float m1 = fmaxf(fmaxf(dots[6],dots[7]), fmaxf(dots[8],dots[9]));
        float s1 = 0.f;
        for (int i = 0; i < 4; ++i) { sh[i] = expf(dots[6+i]-m1); s1 += sh[i]; }
        float mm = fmaxf(dots[4], dots[5]);
        float e0 = expf(dots[4]-mm), e1 = expf(dots[5]-mm);
        float w00 = e0/(e0+e1)*2.f, w01 = e1/(e0+e1)*2.f;
        float* gr = gate + ((size_t)r << 3);
        for (int i = 0; i < 4; ++i) gr[i]   = w00 * (sh[i]/s1*4.f);
        for (int i = 0; i < 4; ++i) gr[4+i] = w01 * rg[i];
    }
}

// ---------------------------------------------------------------------------
// 8x8 average pool of gelu(sr) (cols 768.. of fused buffer) + LayerNorm.
// One block per (b, pooled position); thread = channel.
// ---------------------------------------------------------------------------
__global__ __launch_bounds__(256) void pool_ln_kernel(
    const float* __restrict__ buf,
    const float* __restrict__ g, const float* __restrict__ bb,
    float* __restrict__ xp)          // (256,256)
{
    __shared__ float r1[256], r2[256];
    const int blk = blockIdx.x;
    const int b = blk >> 6, p = blk & 63;
    const int py = p >> 3, px = p & 7;
    const int t = threadIdx.x;
    float acc = 0.f;
    for (int dy = 0; dy < 8; ++dy)
#pragma unroll
        for (int dx = 0; dx < 8; ++dx) {
            int s = ((py*8+dy) << 6) + px*8 + dx;
            acc += buf[(((size_t)(b*4096+s)) << 10) + 768 + t];
        }
    acc *= (1.0f/64.0f);
    r1[t] = acc; r2[t] = acc*acc;
    __syncthreads();
    for (int off = 128; off; off >>= 1) {
        if (t < off) { r1[t] += r1[t+off]; r2[t] += r2[t+off]; }
        __syncthreads();
    }
    float mu  = r1[0] * (1.0f/256.0f);
    float var = r2[0] * (1.0f/256.0f) - mu*mu;
    float rstd = rsqrtf(var + 1e-5f);
    xp[((size_t)blk << 8) + t] = (acc - mu) * rstd * g[t] + bb[t];
}

// ---------------------------------------------------------------------------
// Pooled kv: kv2 = xp @ kv_w^T + kv_b, k half L2-normalized per head.
// Outputs laid out (B,H,PL,32) for the attention kernel.
// ---------------------------------------------------------------------------
__global__ __launch_bounds__(256) void kvpool_kernel(
    const float* __restrict__ xp,
    const float* __restrict__ kv_w, const float* __restrict__ kv_b,
    float* __restrict__ kpool, float* __restrict__ vpool)
{
    __shared__ float xs[256];
    __shared__ float row[512];
    __shared__ float inv[8];
    const int blk = blockIdx.x;     // b*64+p
    const int t = threadIdx.x;
    xs[t] = xp[((size_t)blk << 8) + t];
    __syncthreads();
    for (int o = t; o < 512; o += 256) {
        const float* wr = kv_w + ((size_t)o << 8);
        float s = kv_b[o];
        for (int k = 0; k < 256; ++k) s += xs[k]*wr[k];
        row[o] = s;
    }
    __syncthreads();
    if (t < 8) {
        float s = 0.f;
        for (int dd = 0; dd < 32; ++dd) { float v = row[t*32+dd]; s += v*v; }
        inv[t] = 1.0f / fmaxf(sqrtf(s), EPSF);
    }
    __syncthreads();
    const int b = blk >> 6, p = blk & 63, h = t >> 5, dd = t & 31;
    size_t o = ((((size_t)(b*8+h))*64 + p) << 5) + dd;
    kpool[o] = row[t] * inv[h];
    vpool[o] = row[256 + t];
}

// ---------------------------------------------------------------------------
// CPB MLP: relu(table @ w1^T + b1) @ w2^T + b2 -> (4096, 8)
// ---------------------------------------------------------------------------
__global__ __launch_bounds__(256) void cpb_kernel(
    const float* __restrict__ tbl,
    const float* __restrict__ w1, const float* __restrict__ b1,
    const float* __restrict__ w2, const float* __restrict__ b2,
    float* __restrict__ cpb)
{
    __shared__ float hid[512];
    const int r = blockIdx.x, t = threadIdx.x;
    const float c0 = tbl[(size_t)r*2], c1 = tbl[(size_t)r*2+1];
    for (int i = t; i < 512; i += 256)
        hid[i] = fmaxf(c0*w1[i*2] + c1*w1[i*2+1] + b1[i], 0.f);
    __syncthreads();
    const int h = t >> 5, dd = t & 31;
    float s = 0.f;
    for (int i = dd; i < 512; i += 32) s += hid[i] * w2[h*512+i];
    for (int off = 16; off; off >>= 1) s += __shfl_xor(s, off, 32);
    if (dd == 0) cpb[((size_t)r << 3) + h] = s + b2[h];
}

// ---------------------------------------------------------------------------
// Attention: one block per (b, n), 256 threads = (head, dim).
// 73 logits/head (9 local zero-padded-window + 64 pooled), softmax,
// post-softmax learnable-token add on local weights, weighted value sum,
// per-head MoE gate, write to cols 768.. of fused buffer (sr scratch reuse).
// ---------------------------------------------------------------------------
__global__ __launch_bounds__(256) void attn_kernel(
    float* __restrict__ buf,
    const float* __restrict__ kpool,
    const float* __restrict__ vpool,
    const float* __restrict__ cpb,
    const int*   __restrict__ rpi,
    const float* __restrict__ temp,
    const float* __restrict__ qe,
    const float* __restrict__ rpb,
    const float* __restrict__ lt,    // (8,32,9)
    const float* __restrict__ lb,    // (8,9)
    const float* __restrict__ gate)
{
    __shared__ float qs[256], qn[256], aw[584];
    __shared__ int   nbr[9];
    __shared__ float mxs[8], invs[8];
    const int blk = blockIdx.x;
    const int b = blk >> 12;
    const int n = blk & 4095;
    const int y = n >> 6, x = n & 63;
    const int t = threadIdx.x;
    const int h = t >> 5, d = t & 31;
    const size_t rowbase = (size_t)blk << 10;
    float qv = buf[rowbase + t];                       // already L2-normalized
    float spt = log1pf(expf(temp[h]));                 // softplus(temperature)
    int cy = (y == 0 || y == 63) ? 2 : 3;
    int cx = (x == 0 || x == 63) ? 2 : 3;
    float sls = logf((float)(cy * cx) + 64.0f);
    qn[t] = qv;
    qs[t] = (qv + qe[t]) * spt * sls;
    if (t < 9) {
        int dy = t / 3 - 1, dx = t % 3 - 1;
        int yy = y + dy, xx = x + dx;
        nbr[t] = (yy >= 0 && yy < 64 && xx >= 0 && xx < 64) ? ((yy << 6) | xx) : -1;
    }
    __syncthreads();
    // logits
    for (int id = t; id < 584; id += 256) {
        int hh = id / 73;
        int j  = id - hh * 73;
        float acc;
        if (j < 9) {
            acc = rpb[hh * 9 + j];                     // zero-padded k -> dot = 0
            int m = nbr[j];
            if (m >= 0) {
                const float* kp = buf + (((size_t)(b*4096 + m)) << 10) + 256 + hh*32;
                float s = 0.f;
#pragma unroll
                for (int dd = 0; dd < 32; ++dd) s += qs[hh*32+dd] * kp[dd];
                acc += s;
            }
        } else {
            int p = j - 9;
            const float* kp = kpool + ((((size_t)(b*8+hh))*64 + p) << 5);
            float s = 0.f;
#pragma unroll
            for (int dd = 0; dd < 32; ++dd) s += qs[hh*32+dd] * kp[dd];
            acc = s + cpb[((size_t)rpi[(size_t)n*64 + p] << 3) + hh];
        }
        aw[id] = acc;
    }
    __syncthreads();
    if (t < 8) {
        float m = -1e30f;
        for (int j = 0; j < 73; ++j) m = fmaxf(m, aw[t*73+j]);
        float s = 0.f;
        for (int j = 0; j < 73; ++j) s += expf(aw[t*73+j] - m);
        mxs[t] = m; invs[t] = 1.0f / s;
    }
    __syncthreads();
    // softmax + post-softmax learnable-token add (local only)
    for (int id = t; id < 584; id += 256) {
        int hh = id / 73;
        int j  = id - hh * 73;
        float wv = expf(aw[id] - mxs[hh]) * invs[hh];
        if (j < 9) {
            float s = 0.f;
#pragma unroll
            for (int dd = 0; dd < 32; ++dd) s += qn[hh*32+dd] * lt[(hh*32+dd)*9 + j];
            wv += s + lb[hh*9 + j];
        }
        aw[id] = wv;
    }
    __syncthreads();
    // value accumulation
    float acc = 0.f;
#pragma unroll
    for (int j = 0; j < 9; ++j) {
        int m = nbr[j];
        if (m >= 0) acc += aw[h*73+j] * buf[(((size_t)(b*4096+m)) << 10) + 512 + t];
    }
    const float* vp  = vpool + (((size_t)(b*8+h)) << 11) + d;
    const float* awp = aw + h*73 + 9;
    for (int p = 0; p < 64; ++p) acc += awp[p] * vp[p << 5];
    acc *= gate[((size_t)blk << 3) + h];
    buf[rowbase + 768 + t] = acc;
}

// ---------------------------------------------------------------------------
extern "C" void kernel_launch(void* const* d_in, const int* in_sizes, int n_in,
                              void* d_out, int out_size, void* d_ws, size_t ws_size,
                              hipStream_t stream)
{
    const float* x    = (const float*)d_in[0];
    const float* tbl  = (const float*)d_in[1];
    const float* q_w  = (const float*)d_in[2];
    const float* q_b  = (const float*)d_in[3];
    const float* kv_w = (const float*)d_in[4];
    const float* kv_b = (const float*)d_in[5];
    const float* temp = (const float*)d_in[6];
    const float* qe   = (const float*)d_in[7];
    const float* rpb  = (const float*)d_in[8];
    const float* lt   = (const float*)d_in[9];
    const float* lb   = (const float*)d_in[10];
    const float* c1w  = (const float*)d_in[11];
    const float* c1b  = (const float*)d_in[12];
    const float* c2w  = (const float*)d_in[13];
    const float* c2b  = (const float*)d_in[14];
    const float* sr_w = (const float*)d_in[15];
    const float* sr_b = (const float*)d_in[16];
    const float* ng   = (const float*)d_in[17];
    const float* nbias= (const float*)d_in[18];
    const float* wg   = (const float*)d_in[19];
    const float* wg0  = (const float*)d_in[20];
    const float* wg1  = (const float*)d_in[21];
    const float* pw   = (const float*)d_in[22];
    const float* pb   = (const float*)d_in[23];
    const int*   rpi  = (const int*)d_in[24];
    (void)in_sizes; (void)n_in; (void)out_size; (void)ws_size;

    // workspace layout (floats): fused buf (16384x1024: q|kv|sr->attn_out),
    // xp, kpool, vpool, cpb, gate  -> 65.4 MB total
    float* buf   = (float*)d_ws;
    float* xp    = buf + (size_t)16384*1024;
    float* kpool = xp + 65536;
    float* vpool = kpool + 65536;
    float* cpbb  = vpool + 65536;
    float* gateb = cpbb + 32768;
    float* out   = (float*)d_out;

    // 1) fused GEMM: q (cols 0-255), kv (256-767), gelu(sr) (768-1023)
    gemm_k256<<<dim3(16,256),256,0,stream>>>(x,256, q_w,q_b, kv_w,kv_b, sr_w,sr_b,
                                             256,768,768, buf,1024);
    // 2) in-place L2 norm of q and k halves
    normqk_kernel<<<16384,256,0,stream>>>(buf);
    // 3) MoE gates (independent of 1-2)
    gate_kernel<<<16384,64,0,stream>>>(x, wg, wg0, wg1, gateb);
    // 4) 8x8 avg-pool + LayerNorm of gelu(sr)
    pool_ln_kernel<<<256,256,0,stream>>>(buf, ng, nbias, xp);
    // 5) pooled kv + k-norm
    kvpool_kernel<<<256,256,0,stream>>>(xp, kv_w, kv_b, kpool, vpool);
    // 6) CPB bias table
    cpb_kernel<<<4096,256,0,stream>>>(tbl, c1w, c1b, c2w, c2b, cpbb);
    // 7) attention (writes gated head outputs into buf cols 768-1023)
    attn_kernel<<<16384,256,0,stream>>>(buf, kpool, vpool, cpbb, rpi,
                                        temp, qe, rpb, lt, lb, gateb);
    // 8) output projection
    gemm_k256<<<dim3(4,256),256,0,stream>>>(buf+768,1024, pw,pb, pw,pb, pw,pb,
                                            1<<30,1<<30,1<<30, out,256);
}

// Round 2
// 591.790 us; speedup vs baseline: 1.0104x; 1.0104x over previous
//
#include <hip/hip_runtime.h>
#include <math.h>

#define EPSF 1.1920929e-07f

// ---------------------------------------------------------------------------
// Generic K=256 GEMM: C[m, n] = A[m, :] . W[n, :] + bias[n], 64x64 tiles,
// 256 threads, 4x4 accum per thread, transposed LDS tiles for float4 reads.
// Three weight regions (per-block uniform select) so q|kv|sr fuse into one
// pass; exact GELU applied for n0 >= geluFrom (the sr region).
// ---------------------------------------------------------------------------
__global__ __launch_bounds__(256) void gemm_k256(
    const float* __restrict__ A, int lda,
    const float* __restrict__ W0, const float* __restrict__ B0,
    const float* __restrict__ W1, const float* __restrict__ B1,
    const float* __restrict__ W2, const float* __restrict__ B2,
    int r1, int r2, int geluFrom,
    float* __restrict__ C, int ldc)
{
    __shared__ float As[16][68];
    __shared__ float Ws[16][68];
    const int m0 = blockIdx.y << 6;
    const int n0 = blockIdx.x << 6;
    const float* Wp; const float* Bp; int noff;
    if (n0 < r1)      { Wp = W0; Bp = B0; noff = 0;  }
    else if (n0 < r2) { Wp = W1; Bp = B1; noff = r1; }
    else              { Wp = W2; Bp = B2; noff = r2; }
    const int t  = threadIdx.x;
    const int lr = t >> 2;
    const int lk = (t & 3) << 2;
    const int tx = t & 15;
    const int ty = t >> 4;
    const float* Arow = A + (size_t)(m0 + lr) * lda + lk;
    const float* Wrow = Wp + ((size_t)(n0 - noff + lr) << 8) + lk;
    float acc[4][4] = {{0.f}};
    for (int k0 = 0; k0 < 256; k0 += 16) {
        float4 av = *(const float4*)(Arow + k0);
        float4 wv = *(const float4*)(Wrow + k0);
        __syncthreads();
        As[lk+0][lr] = av.x; As[lk+1][lr] = av.y; As[lk+2][lr] = av.z; As[lk+3][lr] = av.w;
        Ws[lk+0][lr] = wv.x; Ws[lk+1][lr] = wv.y; Ws[lk+2][lr] = wv.z; Ws[lk+3][lr] = wv.w;
        __syncthreads();
#pragma unroll
        for (int kk = 0; kk < 16; ++kk) {
            float4 a = *(const float4*)&As[kk][ty << 2];
            float4 b = *(const float4*)&Ws[kk][tx << 2];
            acc[0][0] += a.x*b.x; acc[0][1] += a.x*b.y; acc[0][2] += a.x*b.z; acc[0][3] += a.x*b.w;
            acc[1][0] += a.y*b.x; acc[1][1] += a.y*b.y; acc[1][2] += a.y*b.z; acc[1][3] += a.y*b.w;
            acc[2][0] += a.z*b.x; acc[2][1] += a.z*b.y; acc[2][2] += a.z*b.z; acc[2][3] += a.z*b.w;
            acc[3][0] += a.w*b.x; acc[3][1] += a.w*b.y; acc[3][2] += a.w*b.z; acc[3][3] += a.w*b.w;
        }
    }
    const bool doGelu = (n0 >= geluFrom);
#pragma unroll
    for (int i = 0; i < 4; ++i) {
        size_t mrow = (size_t)(m0 + (ty << 2) + i) * ldc;
#pragma unroll
        for (int j = 0; j < 4; ++j) {
            int n = n0 + (tx << 2) + j;
            float v = acc[i][j] + Bp[n - noff];
            if (doGelu) v = 0.5f * v * (1.0f + erff(v * 0.70710678118654752f));
            C[mrow + n] = v;
        }
    }
}

// ---------------------------------------------------------------------------
__global__ __launch_bounds__(256) void normqk_kernel(float* __restrict__ buf)
{
    const int r = blockIdx.x, t = threadIdx.x;
    const size_t base = (size_t)r << 10;
    float q = buf[base + t];
    float s = q * q;
    for (int off = 16; off; off >>= 1) s += __shfl_xor(s, off, 32);
    buf[base + t] = q / fmaxf(sqrtf(s), EPSF);
    float k = buf[base + 256 + t];
    float s2 = k * k;
    for (int off = 16; off; off >>= 1) s2 += __shfl_xor(s2, off, 32);
    buf[base + 256 + t] = k / fmaxf(sqrtf(s2), EPSF);
}

// ---------------------------------------------------------------------------
__global__ __launch_bounds__(64) void gate_kernel(
    const float* __restrict__ x,
    const float* __restrict__ wg,
    const float* __restrict__ wg0,
    const float* __restrict__ wg1,
    float* __restrict__ gate)
{
    __shared__ float xs[256];
    __shared__ float dots[10];
    const int r = blockIdx.x;
    const int t = threadIdx.x;
    const float* xr = x + ((size_t)r << 8);
    xs[t] = xr[t]; xs[t+64] = xr[t+64]; xs[t+128] = xr[t+128]; xs[t+192] = xr[t+192];
    __syncthreads();
    for (int f = 0; f < 10; ++f) {
        const float* wf = (f < 4) ? (wg + f*256) : (f < 6) ? (wg0 + (f-4)*256) : (wg1 + (f-6)*256);
        float s = xs[t]*wf[t] + xs[t+64]*wf[t+64] + xs[t+128]*wf[t+128] + xs[t+192]*wf[t+192];
        for (int off = 32; off; off >>= 1) s += __shfl_xor(s, off, 64);
        if (t == 0) dots[f] = s;
    }
    __syncthreads();
    if (t == 0) {
        float e[4];
        float m = fmaxf(fmaxf(dots[0],dots[1]), fmaxf(dots[2],dots[3]));
        float ssum = 0.f;
        for (int i = 0; i < 4; ++i) { e[i] = expf(dots[i]-m); ssum += e[i]; }
        for (int i = 0; i < 4; ++i) e[i] /= ssum;
        int i1 = 0;
        for (int i = 1; i < 4; ++i) if (e[i] > e[i1]) i1 = i;
        int i2 = -1;
        for (int i = 0; i < 4; ++i) if (i != i1 && (i2 < 0 || e[i] > e[i2])) i2 = i;
        float rs = fmaxf(e[i1] + e[i2], EPSF);
        float rg[4] = {0.f,0.f,0.f,0.f};
        rg[i1] = e[i1] / rs * 2.f;
        rg[i2] = e[i2] / rs * 2.f;
        float sh[4];
        float m1 = fmaxf(fmaxf(dots[6],dots[7]), fmaxf(dots[8],dots[9]));
        float s1 = 0.f;
        for (int i = 0; i < 4; ++i) { sh[i] = expf(dots[6+i]-m1); s1 += sh[i]; }
        float mm = fmaxf(dots[4], dots[5]);
        float e0 = expf(dots[4]-mm), e1 = expf(dots[5]-mm);
        float w00 = e0/(e0+e1)*2.f, w01 = e1/(e0+e1)*2.f;
        float* gr = gate + ((size_t)r << 3);
        for (int i = 0; i < 4; ++i) gr[i]   = w00 * (sh[i]/s1*4.f);
        for (int i = 0; i < 4; ++i) gr[4+i] = w01 * rg[i];
    }
}

// ---------------------------------------------------------------------------
__global__ __launch_bounds__(256) void pool_ln_kernel(
    const float* __restrict__ buf,
    const float* __restrict__ g, const float* __restrict__ bb,
    float* __restrict__ xp)
{
    __shared__ float r1[256], r2[256];
    const int blk = blockIdx.x;
    const int b = blk >> 6, p = blk & 63;
    const int py = p >> 3, px = p & 7;
    const int t = threadIdx.x;
    float acc = 0.f;
    for (int dy = 0; dy < 8; ++dy)
#pragma unroll
        for (int dx = 0; dx < 8; ++dx) {
            int s = ((py*8+dy) << 6) + px*8 + dx;
            acc += buf[(((size_t)(b*4096+s)) << 10) + 768 + t];
        }
    acc *= (1.0f/64.0f);
    r1[t] = acc; r2[t] = acc*acc;
    __syncthreads();
    for (int off = 128; off; off >>= 1) {
        if (t < off) { r1[t] += r1[t+off]; r2[t] += r2[t+off]; }
        __syncthreads();
    }
    float mu  = r1[0] * (1.0f/256.0f);
    float var = r2[0] * (1.0f/256.0f) - mu*mu;
    float rstd = rsqrtf(var + 1e-5f);
    xp[((size_t)blk << 8) + t] = (acc - mu) * rstd * g[t] + bb[t];
}

// ---------------------------------------------------------------------------
__global__ __launch_bounds__(256) void kvpool_kernel(
    const float* __restrict__ xp,
    const float* __restrict__ kv_w, const float* __restrict__ kv_b,
    float* __restrict__ kpool, float* __restrict__ vpool)
{
    __shared__ float xs[256];
    __shared__ float row[512];
    __shared__ float inv[8];
    const int blk = blockIdx.x;
    const int t = threadIdx.x;
    xs[t] = xp[((size_t)blk << 8) + t];
    __syncthreads();
    for (int o = t; o < 512; o += 256) {
        const float* wr = kv_w + ((size_t)o << 8);
        float s = kv_b[o];
        for (int k = 0; k < 256; ++k) s += xs[k]*wr[k];
        row[o] = s;
    }
    __syncthreads();
    if (t < 8) {
        float s = 0.f;
        for (int dd = 0; dd < 32; ++dd) { float v = row[t*32+dd]; s += v*v; }
        inv[t] = 1.0f / fmaxf(sqrtf(s), EPSF);
    }
    __syncthreads();
    const int b = blk >> 6, p = blk & 63, h = t >> 5, dd = t & 31;
    size_t o = ((((size_t)(b*8+h))*64 + p) << 5) + dd;
    kpool[o] = row[t] * inv[h];
    vpool[o] = row[256 + t];
}

// ---------------------------------------------------------------------------
__global__ __launch_bounds__(256) void cpb_kernel(
    const float* __restrict__ tbl,
    const float* __restrict__ w1, const float* __restrict__ b1,
    const float* __restrict__ w2, const float* __restrict__ b2,
    float* __restrict__ cpb)
{
    __shared__ float hid[512];
    const int r = blockIdx.x, t = threadIdx.x;
    const float c0 = tbl[(size_t)r*2], c1 = tbl[(size_t)r*2+1];
    for (int i = t; i < 512; i += 256)
        hid[i] = fmaxf(c0*w1[i*2] + c1*w1[i*2+1] + b1[i], 0.f);
    __syncthreads();
    const int h = t >> 5, dd = t & 31;
    float s = 0.f;
    for (int i = dd; i < 512; i += 32) s += hid[i] * w2[h*512+i];
    for (int off = 16; off; off >>= 1) s += __shfl_xor(s, off, 32);
    if (dd == 0) cpb[((size_t)r << 3) + h] = s + b2[h];
}

// ---------------------------------------------------------------------------
// Tiled attention: one block per (b, h, 8x8 token tile). 256 threads.
// LDS: 10x10 k/v halo (rows padded to 36 floats for bank spread), 64x32
// pooled k/v (same pad), 64x74 weight matrix. k-phase LDS is overwritten
// by v data after the logits barrier. q rows / logits / softmax state /
// learnable-token term stay in registers (4 threads per token, width-4
// shuffle reduce).
// ---------------------------------------------------------------------------
__global__ __launch_bounds__(256) void attn_tiled(
    float* __restrict__ buf,
    const float* __restrict__ kpool,
    const float* __restrict__ vpool,
    const float* __restrict__ cpb,
    const int*   __restrict__ rpi,
    const float* __restrict__ temp,
    const float* __restrict__ qe,
    const float* __restrict__ rpb,
    const float* __restrict__ lt,    // (8,32,9)
    const float* __restrict__ lb,    // (8,1,9)
    const float* __restrict__ gate)
{
    __shared__ float kvh[100*36];    // halo rows, k then v
    __shared__ float kpL[64*36];     // pooled rows, k then v
    __shared__ float aw[64*74];      // final attention weights
    const int tile = blockIdx.x;     // 0..63
    const int h    = blockIdx.y;     // 0..7
    const int b    = blockIdx.z;     // 0..3
    const int ty0  = (tile >> 3) << 3;
    const int tx0  = (tile & 7) << 3;
    const int t    = threadIdx.x;
    const int n    = t >> 2;         // local token 0..63
    const int sub  = t & 3;
    const int y    = ty0 + (n >> 3);
    const int x    = tx0 + (n & 7);
    const int ng   = (y << 6) | x;   // global token
    const size_t rowbase = ((size_t)(b*4096 + ng)) << 10;

    // ---- cooperative loads: k halo + pooled k ----
    for (int i = t; i < 3200; i += 256) {
        int r = i >> 5, d = i & 31;
        int hy = ty0 + r/10 - 1, hx = tx0 + r%10 - 1;
        float v = 0.f;
        if (hy >= 0 && hy < 64 && hx >= 0 && hx < 64)
            v = buf[(((size_t)(b*4096 + ((hy<<6)|hx))) << 10) + 256 + h*32 + d];
        kvh[r*36 + d] = v;
    }
    {
        const float* src = kpool + ((size_t)(b*8+h) << 11);
        for (int i = t; i < 2048; i += 256)
            kpL[(i >> 5)*36 + (i & 31)] = src[i];
    }

    // ---- per-thread q row in registers ----
    float4 q4[8];
    {
        const float4* qp = (const float4*)(buf + rowbase + h*32);
#pragma unroll
        for (int i = 0; i < 8; ++i) q4[i] = qp[i];
    }
    // learnable-token term (needs un-scaled q): j = sub + 4*i, i<3
    float ltv[3] = {0.f, 0.f, 0.f};
#pragma unroll
    for (int i = 0; i < 3; ++i) {
        int j = sub + 4*i;
        if (j < 9) {
            float s = 0.f;
            const float* lp = lt + (h*32)*9 + j;
#pragma unroll
            for (int dd = 0; dd < 8; ++dd) {
                s += q4[dd].x * lp[(4*dd+0)*9] + q4[dd].y * lp[(4*dd+1)*9]
                   + q4[dd].z * lp[(4*dd+2)*9] + q4[dd].w * lp[(4*dd+3)*9];
            }
            ltv[i] = s + lb[h*9 + j];
        }
    }
    // scale q: (qn + qe) * softplus(temp) * sls
    {
        float spt = log1pf(expf(temp[h]));
        int cy = (y == 0 || y == 63) ? 2 : 3;
        int cx = (x == 0 || x == 63) ? 2 : 3;
        float sc = spt * logf((float)(cy*cx) + 64.0f);
        const float4* qep = (const float4*)(qe + h*32);
#pragma unroll
        for (int i = 0; i < 8; ++i) {
            float4 e = qep[i];
            q4[i].x = (q4[i].x + e.x) * sc;
            q4[i].y = (q4[i].y + e.y) * sc;
            q4[i].z = (q4[i].z + e.z) * sc;
            q4[i].w = (q4[i].w + e.w) * sc;
        }
    }
    __syncthreads();

    // ---- logits in registers: j = sub + 4*i ----
    float sv[19];
#pragma unroll
    for (int i = 0; i < 19; ++i) {
        int j = sub + 4*i;
        float s = -1e30f;
        if (j < 9) {
            int hr = ((n>>3) + j/3)*10 + (n&7) + j%3;
            const float4* kr = (const float4*)(kvh + hr*36);
            float d0 = 0.f;
#pragma unroll
            for (int dd = 0; dd < 8; ++dd) {
                float4 kv = kr[dd];
                d0 += q4[dd].x*kv.x + q4[dd].y*kv.y + q4[dd].z*kv.z + q4[dd].w*kv.w;
            }
            s = d0 + rpb[h*9 + j];
        } else if (j < 73) {
            int p = j - 9;
            const float4* kr = (const float4*)(kpL + p*36);
            float d0 = 0.f;
#pragma unroll
            for (int dd = 0; dd < 8; ++dd) {
                float4 kv = kr[dd];
                d0 += q4[dd].x*kv.x + q4[dd].y*kv.y + q4[dd].z*kv.z + q4[dd].w*kv.w;
            }
            s = d0 + cpb[((size_t)rpi[(size_t)ng*64 + p] << 3) + h];
        }
        sv[i] = s;
    }
    __syncthreads();   // k reads done; safe to overwrite with v

    // ---- cooperative loads: v halo + pooled v (overwrite k LDS) ----
    for (int i = t; i < 3200; i += 256) {
        int r = i >> 5, d = i & 31;
        int hy = ty0 + r/10 - 1, hx = tx0 + r%10 - 1;
        float v = 0.f;
        if (hy >= 0 && hy < 64 && hx >= 0 && hx < 64)
            v = buf[(((size_t)(b*4096 + ((hy<<6)|hx))) << 10) + 512 + h*32 + d];
        kvh[r*36 + d] = v;
    }
    {
        const float* src = vpool + ((size_t)(b*8+h) << 11);
        for (int i = t; i < 2048; i += 256)
            kpL[(i >> 5)*36 + (i & 31)] = src[i];
    }

    // ---- softmax (width-4 shuffle reduce across the token's 4 threads) ----
    float m = -1e30f;
#pragma unroll
    for (int i = 0; i < 19; ++i) m = fmaxf(m, sv[i]);
    m = fmaxf(m, __shfl_xor(m, 1, 4));
    m = fmaxf(m, __shfl_xor(m, 2, 4));
    float ssum = 0.f;
#pragma unroll
    for (int i = 0; i < 19; ++i) ssum += __builtin_expf(sv[i] - m);
    ssum += __shfl_xor(ssum, 1, 4);
    ssum += __shfl_xor(ssum, 2, 4);
    float iv = 1.0f / ssum;
#pragma unroll
    for (int i = 0; i < 19; ++i) {
        int j = sub + 4*i;
        if (j < 73) {
            float w = __builtin_expf(sv[i] - m) * iv;
            if (i < 3 && j < 9) w += ltv[i];
            aw[n*74 + j] = w;
        }
    }
    __syncthreads();

    // ---- weighted value sum: thread = (token n, dims d0..d0+7) ----
    const int d0 = sub << 3;
    float4 a0 = {0.f,0.f,0.f,0.f}, a1 = {0.f,0.f,0.f,0.f};
#pragma unroll
    for (int j = 0; j < 9; ++j) {
        float w = aw[n*74 + j];
        int hr = ((n>>3) + j/3)*10 + (n&7) + j%3;
        const float4* vr = (const float4*)(kvh + hr*36 + d0);
        float4 v0 = vr[0], v1 = vr[1];
        a0.x += w*v0.x; a0.y += w*v0.y; a0.z += w*v0.z; a0.w += w*v0.w;
        a1.x += w*v1.x; a1.y += w*v1.y; a1.z += w*v1.z; a1.w += w*v1.w;
    }
    for (int p = 0; p < 64; ++p) {
        float w = aw[n*74 + 9 + p];
        const float4* vr = (const float4*)(kpL + p*36 + d0);
        float4 v0 = vr[0], v1 = vr[1];
        a0.x += w*v0.x; a0.y += w*v0.y; a0.z += w*v0.z; a0.w += w*v0.w;
        a1.x += w*v1.x; a1.y += w*v1.y; a1.z += w*v1.z; a1.w += w*v1.w;
    }
    float g = gate[((size_t)(b*4096 + ng) << 3) + h];
    a0.x *= g; a0.y *= g; a0.z *= g; a0.w *= g;
    a1.x *= g; a1.y *= g; a1.z *= g; a1.w *= g;
    float* outp = buf + rowbase + 768 + h*32 + d0;
    ((float4*)outp)[0] = a0;
    ((float4*)outp)[1] = a1;
}

// ---------------------------------------------------------------------------
extern "C" void kernel_launch(void* const* d_in, const int* in_sizes, int n_in,
                              void* d_out, int out_size, void* d_ws, size_t ws_size,
                              hipStream_t stream)
{
    const float* x    = (const float*)d_in[0];
    const float* tbl  = (const float*)d_in[1];
    const float* q_w  = (const float*)d_in[2];
    const float* q_b  = (const float*)d_in[3];
    const float* kv_w = (const float*)d_in[4];
    const float* kv_b = (const float*)d_in[5];
    const float* temp = (const float*)d_in[6];
    const float* qe   = (const float*)d_in[7];
    const float* rpb  = (const float*)d_in[8];
    const float* lt   = (const float*)d_in[9];
    const float* lb   = (const float*)d_in[10];
    const float* c1w  = (const float*)d_in[11];
    const float* c1b  = (const float*)d_in[12];
    const float* c2w  = (const float*)d_in[13];
    const float* c2b  = (const float*)d_in[14];
    const float* sr_w = (const float*)d_in[15];
    const float* sr_b = (const float*)d_in[16];
    const float* ng   = (const float*)d_in[17];
    const float* nbias= (const float*)d_in[18];
    const float* wg   = (const float*)d_in[19];
    const float* wg0  = (const float*)d_in[20];
    const float* wg1  = (const float*)d_in[21];
    const float* pw   = (const float*)d_in[22];
    const float* pb   = (const float*)d_in[23];
    const int*   rpi  = (const int*)d_in[24];
    (void)in_sizes; (void)n_in; (void)out_size; (void)ws_size;

    float* buf   = (float*)d_ws;
    float* xp    = buf + (size_t)16384*1024;
    float* kpool = xp + 65536;
    float* vpool = kpool + 65536;
    float* cpbb  = vpool + 65536;
    float* gateb = cpbb + 32768;
    float* out   = (float*)d_out;

    // 1) fused GEMM: q (cols 0-255), kv (256-767), gelu(sr) (768-1023)
    gemm_k256<<<dim3(16,256),256,0,stream>>>(x,256, q_w,q_b, kv_w,kv_b, sr_w,sr_b,
                                             256,768,768, buf,1024);
    // 2) in-place L2 norm of q and k halves
    normqk_kernel<<<16384,256,0,stream>>>(buf);
    // 3) MoE gates
    gate_kernel<<<16384,64,0,stream>>>(x, wg, wg0, wg1, gateb);
    // 4) 8x8 avg-pool + LayerNorm of gelu(sr)
    pool_ln_kernel<<<256,256,0,stream>>>(buf, ng, nbias, xp);
    // 5) pooled kv + k-norm
    kvpool_kernel<<<256,256,0,stream>>>(xp, kv_w, kv_b, kpool, vpool);
    // 6) CPB bias table
    cpb_kernel<<<4096,256,0,stream>>>(tbl, c1w, c1b, c2w, c2b, cpbb);
    // 7) tiled attention (writes gated head outputs into buf cols 768-1023)
    attn_tiled<<<dim3(64,8,4),256,0,stream>>>(buf, kpool, vpool, cpbb, rpi,
                                              temp, qe, rpb, lt, lb, gateb);
    // 8) output projection
    gemm_k256<<<dim3(4,256),256,0,stream>>>(buf+768,1024, pw,pb, pw,pb, pw,pb,
                                            1<<30,1<<30,1<<30, out,256);
}

// Round 3
// 440.676 us; speedup vs baseline: 1.3568x; 1.3429x over previous
//
#include <hip/hip_runtime.h>
#include <math.h>

#define EPSF 1.1920929e-07f

// ---------------------------------------------------------------------------
// Generic K=256 GEMM: C[m, n] = A[m, :] . W[n, :] + bias[n], 64x64 tiles,
// 256 threads, 4x4 accum per thread. Three weight regions so q|kv|sr fuse;
// exact GELU for n0 >= geluFrom.
// ---------------------------------------------------------------------------
__global__ __launch_bounds__(256) void gemm_k256(
    const float* __restrict__ A, int lda,
    const float* __restrict__ W0, const float* __restrict__ B0,
    const float* __restrict__ W1, const float* __restrict__ B1,
    const float* __restrict__ W2, const float* __restrict__ B2,
    int r1, int r2, int geluFrom,
    float* __restrict__ C, int ldc)
{
    __shared__ float As[16][68];
    __shared__ float Ws[16][68];
    const int m0 = blockIdx.y << 6;
    const int n0 = blockIdx.x << 6;
    const float* Wp; const float* Bp; int noff;
    if (n0 < r1)      { Wp = W0; Bp = B0; noff = 0;  }
    else if (n0 < r2) { Wp = W1; Bp = B1; noff = r1; }
    else              { Wp = W2; Bp = B2; noff = r2; }
    const int t  = threadIdx.x;
    const int lr = t >> 2;
    const int lk = (t & 3) << 2;
    const int tx = t & 15;
    const int ty = t >> 4;
    const float* Arow = A + (size_t)(m0 + lr) * lda + lk;
    const float* Wrow = Wp + ((size_t)(n0 - noff + lr) << 8) + lk;
    float acc[4][4] = {{0.f}};
    for (int k0 = 0; k0 < 256; k0 += 16) {
        float4 av = *(const float4*)(Arow + k0);
        float4 wv = *(const float4*)(Wrow + k0);
        __syncthreads();
        As[lk+0][lr] = av.x; As[lk+1][lr] = av.y; As[lk+2][lr] = av.z; As[lk+3][lr] = av.w;
        Ws[lk+0][lr] = wv.x; Ws[lk+1][lr] = wv.y; Ws[lk+2][lr] = wv.z; Ws[lk+3][lr] = wv.w;
        __syncthreads();
#pragma unroll
        for (int kk = 0; kk < 16; ++kk) {
            float4 a = *(const float4*)&As[kk][ty << 2];
            float4 b = *(const float4*)&Ws[kk][tx << 2];
            acc[0][0] += a.x*b.x; acc[0][1] += a.x*b.y; acc[0][2] += a.x*b.z; acc[0][3] += a.x*b.w;
            acc[1][0] += a.y*b.x; acc[1][1] += a.y*b.y; acc[1][2] += a.y*b.z; acc[1][3] += a.y*b.w;
            acc[2][0] += a.z*b.x; acc[2][1] += a.z*b.y; acc[2][2] += a.z*b.z; acc[2][3] += a.z*b.w;
            acc[3][0] += a.w*b.x; acc[3][1] += a.w*b.y; acc[3][2] += a.w*b.z; acc[3][3] += a.w*b.w;
        }
    }
    const bool doGelu = (n0 >= geluFrom);
#pragma unroll
    for (int i = 0; i < 4; ++i) {
        size_t mrow = (size_t)(m0 + (ty << 2) + i) * ldc;
#pragma unroll
        for (int j = 0; j < 4; ++j) {
            int n = n0 + (tx << 2) + j;
            float v = acc[i][j] + Bp[n - noff];
            if (doGelu) v = 0.5f * v * (1.0f + erff(v * 0.70710678118654752f));
            C[mrow + n] = v;
        }
    }
}

// ---------------------------------------------------------------------------
__global__ __launch_bounds__(256) void normqk_kernel(float* __restrict__ buf)
{
    const int r = blockIdx.x, t = threadIdx.x;
    const size_t base = (size_t)r << 10;
    float q = buf[base + t];
    float s = q * q;
    for (int off = 16; off; off >>= 1) s += __shfl_xor(s, off, 32);
    buf[base + t] = q / fmaxf(sqrtf(s), EPSF);
    float k = buf[base + 256 + t];
    float s2 = k * k;
    for (int off = 16; off; off >>= 1) s2 += __shfl_xor(s2, off, 32);
    buf[base + 256 + t] = k / fmaxf(sqrtf(s2), EPSF);
}

// ---------------------------------------------------------------------------
__global__ __launch_bounds__(64) void gate_kernel(
    const float* __restrict__ x,
    const float* __restrict__ wg,
    const float* __restrict__ wg0,
    const float* __restrict__ wg1,
    float* __restrict__ gate)
{
    __shared__ float xs[256];
    __shared__ float dots[10];
    const int r = blockIdx.x;
    const int t = threadIdx.x;
    const float* xr = x + ((size_t)r << 8);
    xs[t] = xr[t]; xs[t+64] = xr[t+64]; xs[t+128] = xr[t+128]; xs[t+192] = xr[t+192];
    __syncthreads();
    for (int f = 0; f < 10; ++f) {
        const float* wf = (f < 4) ? (wg + f*256) : (f < 6) ? (wg0 + (f-4)*256) : (wg1 + (f-6)*256);
        float s = xs[t]*wf[t] + xs[t+64]*wf[t+64] + xs[t+128]*wf[t+128] + xs[t+192]*wf[t+192];
        for (int off = 32; off; off >>= 1) s += __shfl_xor(s, off, 64);
        if (t == 0) dots[f] = s;
    }
    __syncthreads();
    if (t == 0) {
        float e[4];
        float m = fmaxf(fmaxf(dots[0],dots[1]), fmaxf(dots[2],dots[3]));
        float ssum = 0.f;
        for (int i = 0; i < 4; ++i) { e[i] = expf(dots[i]-m); ssum += e[i]; }
        for (int i = 0; i < 4; ++i) e[i] /= ssum;
        int i1 = 0;
        for (int i = 1; i < 4; ++i) if (e[i] > e[i1]) i1 = i;
        int i2 = -1;
        for (int i = 0; i < 4; ++i) if (i != i1 && (i2 < 0 || e[i] > e[i2])) i2 = i;
        float rs = fmaxf(e[i1] + e[i2], EPSF);
        float rg[4] = {0.f,0.f,0.f,0.f};
        rg[i1] = e[i1] / rs * 2.f;
        rg[i2] = e[i2] / rs * 2.f;
        float sh[4];
        float m1 = fmaxf(fmaxf(dots[6],dots[7]), fmaxf(dots[8],dots[9]));
        float s1 = 0.f;
        for (int i = 0; i < 4; ++i) { sh[i] = expf(dots[6+i]-m1); s1 += sh[i]; }
        float mm = fmaxf(dots[4], dots[5]);
        float e0 = expf(dots[4]-mm), e1 = expf(dots[5]-mm);
        float w00 = e0/(e0+e1)*2.f, w01 = e1/(e0+e1)*2.f;
        float* gr = gate + ((size_t)r << 3);
        for (int i = 0; i < 4; ++i) gr[i]   = w00 * (sh[i]/s1*4.f);
        for (int i = 0; i < 4; ++i) gr[4+i] = w01 * rg[i];
    }
}

// ---------------------------------------------------------------------------
__global__ __launch_bounds__(256) void pool_ln_kernel(
    const float* __restrict__ buf,
    const float* __restrict__ g, const float* __restrict__ bb,
    float* __restrict__ xp)
{
    __shared__ float r1[256], r2[256];
    const int blk = blockIdx.x;
    const int b = blk >> 6, p = blk & 63;
    const int py = p >> 3, px = p & 7;
    const int t = threadIdx.x;
    float acc = 0.f;
    for (int dy = 0; dy < 8; ++dy)
#pragma unroll
        for (int dx = 0; dx < 8; ++dx) {
            int s = ((py*8+dy) << 6) + px*8 + dx;
            acc += buf[(((size_t)(b*4096+s)) << 10) + 768 + t];
        }
    acc *= (1.0f/64.0f);
    r1[t] = acc; r2[t] = acc*acc;
    __syncthreads();
    for (int off = 128; off; off >>= 1) {
        if (t < off) { r1[t] += r1[t+off]; r2[t] += r2[t+off]; }
        __syncthreads();
    }
    float mu  = r1[0] * (1.0f/256.0f);
    float var = r2[0] * (1.0f/256.0f) - mu*mu;
    float rstd = rsqrtf(var + 1e-5f);
    xp[((size_t)blk << 8) + t] = (acc - mu) * rstd * g[t] + bb[t];
}

// ---------------------------------------------------------------------------
__global__ __launch_bounds__(256) void kvpool_kernel(
    const float* __restrict__ xp,
    const float* __restrict__ kv_w, const float* __restrict__ kv_b,
    float* __restrict__ kpool, float* __restrict__ vpool)
{
    __shared__ float xs[256];
    __shared__ float row[512];
    __shared__ float inv[8];
    const int blk = blockIdx.x;
    const int t = threadIdx.x;
    xs[t] = xp[((size_t)blk << 8) + t];
    __syncthreads();
    for (int o = t; o < 512; o += 256) {
        const float* wr = kv_w + ((size_t)o << 8);
        float s = kv_b[o];
        for (int k = 0; k < 256; ++k) s += xs[k]*wr[k];
        row[o] = s;
    }
    __syncthreads();
    if (t < 8) {
        float s = 0.f;
        for (int dd = 0; dd < 32; ++dd) { float v = row[t*32+dd]; s += v*v; }
        inv[t] = 1.0f / fmaxf(sqrtf(s), EPSF);
    }
    __syncthreads();
    const int b = blk >> 6, p = blk & 63, h = t >> 5, dd = t & 31;
    size_t o = ((((size_t)(b*8+h))*64 + p) << 5) + dd;
    kpool[o] = row[t] * inv[h];
    vpool[o] = row[256 + t];
}

// ---------------------------------------------------------------------------
__global__ __launch_bounds__(256) void cpb_kernel(
    const float* __restrict__ tbl,
    const float* __restrict__ w1, const float* __restrict__ b1,
    const float* __restrict__ w2, const float* __restrict__ b2,
    float* __restrict__ cpb)
{
    __shared__ float hid[512];
    const int r = blockIdx.x, t = threadIdx.x;
    const float c0 = tbl[(size_t)r*2], c1 = tbl[(size_t)r*2+1];
    for (int i = t; i < 512; i += 256)
        hid[i] = fmaxf(c0*w1[i*2] + c1*w1[i*2+1] + b1[i], 0.f);
    __syncthreads();
    const int h = t >> 5, dd = t & 31;
    float s = 0.f;
    for (int i = dd; i < 512; i += 32) s += hid[i] * w2[h*512+i];
    for (int off = 16; off; off >>= 1) s += __shfl_xor(s, off, 32);
    if (dd == 0) cpb[((size_t)r << 3) + h] = s + b2[h];
}

// ---------------------------------------------------------------------------
// Tiled attention v2: one block per (b, h, 8x8 token tile), 256 threads.
// No register state crosses a barrier (fixes the v1 spill catastrophe).
//
// Logits: lane = token (64 lanes), wave = j-group (j = wave + 4s). q row
// lives in 8 float4 regs loaded straight from global (one cache line per
// lane, read once); k rows are wave-uniform -> every ds_read_b128 is a
// same-address broadcast; local-vs-pooled branch is wave-uniform.
// Learnable-token term folded into the logits loop via
// dot(q_raw, lt_j) = dot(q_scaled, lt_j)/sc - dot(qe, lt_j)  (dq[9] const).
// Softmax + value phases re-read from LDS; v loads overlap softmax math.
// ---------------------------------------------------------------------------
__global__ __launch_bounds__(256, 3) void attn_tiled(
    const float* __restrict__ buf,
    float* __restrict__ obuf,
    const float* __restrict__ kpool,
    const float* __restrict__ vpool,
    const float* __restrict__ cpb,
    const int*   __restrict__ rpi,
    const float* __restrict__ temp,
    const float* __restrict__ qe,
    const float* __restrict__ rpb,
    const float* __restrict__ lt,    // (8,32,9)
    const float* __restrict__ lb,    // (8,1,9)
    const float* __restrict__ gate)
{
    __shared__ float kvh[100*36];    // halo rows (k, then overwritten by v)
    __shared__ float kpL[64*36];     // pooled rows (k, then v)
    __shared__ float aw[64*74];      // logits -> final attention weights
    __shared__ float ltb[9*64];      // learnable-token add, [j][n]
    __shared__ float dq[12];         // dot(qe_h, lt[:, j])
    const int tile = blockIdx.x;     // 0..63
    const int h    = blockIdx.y;     // 0..7
    const int b    = blockIdx.z;     // 0..3
    const int ty0  = (tile >> 3) << 3;
    const int tx0  = (tile & 7) << 3;
    const int t    = threadIdx.x;

    // ---- stage k-halo + pooled k; dq ----
    for (int i = t; i < 3200; i += 256) {
        int r = i >> 5, d = i & 31;
        int hy = ty0 + r/10 - 1, hx = tx0 + r%10 - 1;
        float v = 0.f;
        if (hy >= 0 && hy < 64 && hx >= 0 && hx < 64)
            v = buf[(((size_t)(b*4096 + ((hy<<6)|hx))) << 10) + 256 + h*32 + d];
        kvh[r*36 + d] = v;
    }
    {
        const float* src = kpool + ((size_t)(b*8+h) << 11);
        for (int i = t; i < 2048; i += 256)
            kpL[(i >> 5)*36 + (i & 31)] = src[i];
    }
    if (t < 9) {
        float s = 0.f;
        for (int dd = 0; dd < 32; ++dd)
            s += qe[h*32+dd] * lt[(h*32+dd)*9 + t];
        dq[t] = s;
    }

    // ---- per-lane q row (scaled) in registers; lane = token ----
    const int n   = t & 63;
    const int g   = t >> 6;          // wave id = j-group
    const int y   = ty0 + (n >> 3);
    const int x   = tx0 + (n & 7);
    const int ngl = (y << 6) | x;
    const float spt = log1pf(expf(temp[h]));
    const int cy = (y == 0 || y == 63) ? 2 : 3;
    const int cx = (x == 0 || x == 63) ? 2 : 3;
    const float sc = spt * logf((float)(cy*cx) + 64.0f);
    const float inv_sc = 1.0f / sc;
    float4 q4[8];
    {
        const float4* qp = (const float4*)(buf + (((size_t)(b*4096 + ngl)) << 10) + h*32);
        const float4* qep = (const float4*)(qe + h*32);
#pragma unroll
        for (int i = 0; i < 8; ++i) {
            float4 qv = qp[i], e = qep[i];
            q4[i].x = (qv.x + e.x) * sc;
            q4[i].y = (qv.y + e.y) * sc;
            q4[i].z = (qv.z + e.z) * sc;
            q4[i].w = (qv.w + e.w) * sc;
        }
    }
    __syncthreads();

    // ---- logits (wave-uniform j) ----
    for (int j = g; j < 73; j += 4) {
        float acc;
        if (j < 9) {
            int hr = ((n>>3) + j/3)*10 + (n&7) + (j%3);
            const float4* kr = (const float4*)(kvh + hr*36);
            float d0 = 0.f;
#pragma unroll
            for (int dd = 0; dd < 8; ++dd) {
                float4 kv = kr[dd];
                d0 += q4[dd].x*kv.x + q4[dd].y*kv.y + q4[dd].z*kv.z + q4[dd].w*kv.w;
            }
            acc = d0 + rpb[h*9 + j];
            // learnable-token term (post-softmax add), via scaled-q identity
            const float* lp = lt + (h*32)*9 + j;
            float s = 0.f;
#pragma unroll
            for (int dd = 0; dd < 8; ++dd) {
                s += q4[dd].x * lp[(4*dd+0)*9] + q4[dd].y * lp[(4*dd+1)*9]
                   + q4[dd].z * lp[(4*dd+2)*9] + q4[dd].w * lp[(4*dd+3)*9];
            }
            ltb[j*64 + n] = s * inv_sc - dq[j] + lb[h*9 + j];
        } else {
            int p = j - 9;
            const float4* kr = (const float4*)(kpL + p*36);
            float d0 = 0.f;
#pragma unroll
            for (int dd = 0; dd < 8; ++dd) {
                float4 kv = kr[dd];
                d0 += q4[dd].x*kv.x + q4[dd].y*kv.y + q4[dd].z*kv.z + q4[dd].w*kv.w;
            }
            acc = d0 + cpb[((size_t)rpi[(size_t)ngl*64 + p] << 3) + h];
        }
        aw[n*74 + j] = acc;
    }
    __syncthreads();

    // ---- stage v-halo + pooled v (overwrite k LDS); overlaps softmax ----
    for (int i = t; i < 3200; i += 256) {
        int r = i >> 5, d = i & 31;
        int hy = ty0 + r/10 - 1, hx = tx0 + r%10 - 1;
        float v = 0.f;
        if (hy >= 0 && hy < 64 && hx >= 0 && hx < 64)
            v = buf[(((size_t)(b*4096 + ((hy<<6)|hx))) << 10) + 512 + h*32 + d];
        kvh[r*36 + d] = v;
    }
    {
        const float* src = vpool + ((size_t)(b*8+h) << 11);
        for (int i = t; i < 2048; i += 256)
            kpL[(i >> 5)*36 + (i & 31)] = src[i];
    }

    // ---- softmax over LDS row (thread = (token, sub), width-4 reduce) ----
    {
        const int sn = t >> 2, sub = t & 3;
        float m = -1e30f;
        for (int j = sub; j < 73; j += 4) m = fmaxf(m, aw[sn*74 + j]);
        m = fmaxf(m, __shfl_xor(m, 1, 4));
        m = fmaxf(m, __shfl_xor(m, 2, 4));
        float ssum = 0.f;
        for (int j = sub; j < 73; j += 4) ssum += __builtin_expf(aw[sn*74 + j] - m);
        ssum += __shfl_xor(ssum, 1, 4);
        ssum += __shfl_xor(ssum, 2, 4);
        float iv = 1.0f / ssum;
        for (int j = sub; j < 73; j += 4) {
            float w = __builtin_expf(aw[sn*74 + j] - m) * iv;
            if (j < 9) w += ltb[j*64 + sn];
            aw[sn*74 + j] = w;
        }
    }
    __syncthreads();

    // ---- weighted value sum: thread = (token, 8-dim sub) ----
    {
        const int sn = t >> 2, sub = t & 3;
        const int d0 = sub << 3;
        float4 a0 = {0.f,0.f,0.f,0.f}, a1 = {0.f,0.f,0.f,0.f};
#pragma unroll
        for (int j = 0; j < 9; ++j) {
            float w = aw[sn*74 + j];
            int hr = ((sn>>3) + j/3)*10 + (sn&7) + (j%3);
            const float4* vr = (const float4*)(kvh + hr*36 + d0);
            float4 v0 = vr[0], v1 = vr[1];
            a0.x += w*v0.x; a0.y += w*v0.y; a0.z += w*v0.z; a0.w += w*v0.w;
            a1.x += w*v1.x; a1.y += w*v1.y; a1.z += w*v1.z; a1.w += w*v1.w;
        }
#pragma unroll 4
        for (int p = 0; p < 64; ++p) {
            float w = aw[sn*74 + 9 + p];
            const float4* vr = (const float4*)(kpL + p*36 + d0);
            float4 v0 = vr[0], v1 = vr[1];
            a0.x += w*v0.x; a0.y += w*v0.y; a0.z += w*v0.z; a0.w += w*v0.w;
            a1.x += w*v1.x; a1.y += w*v1.y; a1.z += w*v1.z; a1.w += w*v1.w;
        }
        const int sy = ty0 + (sn >> 3), sx = tx0 + (sn & 7);
        const int sng = (sy << 6) | sx;
        float gt = gate[((size_t)(b*4096 + sng) << 3) + h];
        a0.x *= gt; a0.y *= gt; a0.z *= gt; a0.w *= gt;
        a1.x *= gt; a1.y *= gt; a1.z *= gt; a1.w *= gt;
        float* outp = obuf + (((size_t)(b*4096 + sng)) << 10) + 768 + h*32 + d0;
        ((float4*)outp)[0] = a0;
        ((float4*)outp)[1] = a1;
    }
}

// ---------------------------------------------------------------------------
extern "C" void kernel_launch(void* const* d_in, const int* in_sizes, int n_in,
                              void* d_out, int out_size, void* d_ws, size_t ws_size,
                              hipStream_t stream)
{
    const float* x    = (const float*)d_in[0];
    const float* tbl  = (const float*)d_in[1];
    const float* q_w  = (const float*)d_in[2];
    const float* q_b  = (const float*)d_in[3];
    const float* kv_w = (const float*)d_in[4];
    const float* kv_b = (const float*)d_in[5];
    const float* temp = (const float*)d_in[6];
    const float* qe   = (const float*)d_in[7];
    const float* rpb  = (const float*)d_in[8];
    const float* lt   = (const float*)d_in[9];
    const float* lb   = (const float*)d_in[10];
    const float* c1w  = (const float*)d_in[11];
    const float* c1b  = (const float*)d_in[12];
    const float* c2w  = (const float*)d_in[13];
    const float* c2b  = (const float*)d_in[14];
    const float* sr_w = (const float*)d_in[15];
    const float* sr_b = (const float*)d_in[16];
    const float* ng   = (const float*)d_in[17];
    const float* nbias= (const float*)d_in[18];
    const float* wg   = (const float*)d_in[19];
    const float* wg0  = (const float*)d_in[20];
    const float* wg1  = (const float*)d_in[21];
    const float* pw   = (const float*)d_in[22];
    const float* pb   = (const float*)d_in[23];
    const int*   rpi  = (const int*)d_in[24];
    (void)in_sizes; (void)n_in; (void)out_size; (void)ws_size;

    float* buf   = (float*)d_ws;
    float* xp    = buf + (size_t)16384*1024;
    float* kpool = xp + 65536;
    float* vpool = kpool + 65536;
    float* cpbb  = vpool + 65536;
    float* gateb = cpbb + 32768;
    float* out   = (float*)d_out;

    // 1) fused GEMM: q (cols 0-255), kv (256-767), gelu(sr) (768-1023)
    gemm_k256<<<dim3(16,256),256,0,stream>>>(x,256, q_w,q_b, kv_w,kv_b, sr_w,sr_b,
                                             256,768,768, buf,1024);
    // 2) in-place L2 norm of q and k halves
    normqk_kernel<<<16384,256,0,stream>>>(buf);
    // 3) MoE gates
    gate_kernel<<<16384,64,0,stream>>>(x, wg, wg0, wg1, gateb);
    // 4) 8x8 avg-pool + LayerNorm of gelu(sr)
    pool_ln_kernel<<<256,256,0,stream>>>(buf, ng, nbias, xp);
    // 5) pooled kv + k-norm
    kvpool_kernel<<<256,256,0,stream>>>(xp, kv_w, kv_b, kpool, vpool);
    // 6) CPB bias table
    cpb_kernel<<<4096,256,0,stream>>>(tbl, c1w, c1b, c2w, c2b, cpbb);
    // 7) tiled attention (writes gated head outputs into buf cols 768-1023)
    attn_tiled<<<dim3(64,8,4),256,0,stream>>>(buf, buf, kpool, vpool, cpbb, rpi,
                                              temp, qe, rpb, lt, lb, gateb);
    // 8) output projection
    gemm_k256<<<dim3(4,256),256,0,stream>>>(buf+768,1024, pw,pb, pw,pb, pw,pb,
                                            1<<30,1<<30,1<<30, out,256);
}

// Round 4
// 319.768 us; speedup vs baseline: 1.8698x; 1.3781x over previous
//
#include <hip/hip_runtime.h>
#include <math.h>

#define EPSF 1.1920929e-07f

typedef __attribute__((ext_vector_type(8))) short short8;
typedef __attribute__((ext_vector_type(4))) float f32x4;

// float -> bf16 (RNE) without relying on __hip_bfloat16 ABI
static __device__ __forceinline__ unsigned short f2bf(float f) {
    unsigned int u = __float_as_uint(f);
    return (unsigned short)((u + 0x7FFFu + ((u >> 16) & 1u)) >> 16);
}

// ---------------------------------------------------------------------------
// x (16384x256 f32) -> bf16
// ---------------------------------------------------------------------------
__global__ __launch_bounds__(256) void convert_x(
    const float* __restrict__ x, unsigned short* __restrict__ xbf)
{
    const int e = (blockIdx.x * 256 + threadIdx.x) * 4;   // < 4194304 exact
    float4 v = *(const float4*)(x + e);
    ushort4 o;
    o.x = f2bf(v.x); o.y = f2bf(v.y); o.z = f2bf(v.z); o.w = f2bf(v.w);
    *(ushort4*)(xbf + e) = o;
}

// ---------------------------------------------------------------------------
// weights -> bf16: wcat rows 0..255 = q_w, 256..767 = kv_w, 768..1023 = sr_w;
// then pw (256x256). 320 blocks x 256 thr x 4 elems = 327680 exact.
// ---------------------------------------------------------------------------
__global__ __launch_bounds__(256) void convert_w(
    const float* __restrict__ q_w, const float* __restrict__ kv_w,
    const float* __restrict__ sr_w, const float* __restrict__ pw,
    unsigned short* __restrict__ wcat, unsigned short* __restrict__ pwbf)
{
    const int e = (blockIdx.x * 256 + threadIdx.x) * 4;
    if (e < 262144) {
        int n = e >> 8, k = e & 255;
        const float* src = (n < 256) ? (q_w + n*256) :
                           (n < 768) ? (kv_w + (n-256)*256) : (sr_w + (n-768)*256);
        float4 v = *(const float4*)(src + k);
        ushort4 o;
        o.x = f2bf(v.x); o.y = f2bf(v.y); o.z = f2bf(v.z); o.w = f2bf(v.w);
        *(ushort4*)(wcat + e) = o;
    } else {
        int e2 = e - 262144;
        float4 v = *(const float4*)(pw + e2);
        ushort4 o;
        o.x = f2bf(v.x); o.y = f2bf(v.y); o.z = f2bf(v.z); o.w = f2bf(v.w);
        *(ushort4*)(pwbf + e2) = o;
    }
}

// ---------------------------------------------------------------------------
// MFMA bf16 GEMM, K=256: C[m,n] = A[m,:] . W[n,:] + bias[n]. 128x128 block
// tile, 4 waves of 64x64, 16x16x32 MFMA, fp32 accum. Epilogue: bias, then
// per-(row,head) L2-norm for cols < normUntil (head = 32 cols, covered by
// 2 acc c-tiles x 16 lanes -> 4 xor-shuffles), exact GELU for col >= geluFrom.
// Fragment layouts per cdna_hip_programming.md §3 (m89/m91-verified):
//   A/B: [idx=lane&15][k=(lane>>4)*8+j]; C/D: col=lane&15, row=(lane>>4)*4+reg.
// ---------------------------------------------------------------------------
__global__ __launch_bounds__(256) void gemm_mfma(
    const unsigned short* __restrict__ A,   // (M,256) bf16
    const unsigned short* __restrict__ W,   // (Ntot,256) bf16
    const float* __restrict__ B0, const float* __restrict__ B1,
    const float* __restrict__ B2,
    int r1, int r2, int normUntil, int geluFrom,
    float* __restrict__ C, int ldc)
{
    __shared__ unsigned short At[128*32];
    __shared__ unsigned short Bt[128*32];
    const int m0 = blockIdx.y << 7;
    const int n0 = blockIdx.x << 7;
    const int t  = threadIdx.x;
    const int w  = t >> 6;
    const int l  = t & 63;
    const int wm = (w >> 1) << 6;
    const int wn = (w & 1) << 6;
    const int col16 = l & 15;
    const int quad  = l >> 4;
    const int srow = t >> 2;           // 0..63
    const int skp  = (t & 3) << 3;     // element offset 0,8,16,24

    const float* Bp; int noff;
    if (n0 < r1)      { Bp = B0; noff = 0;  }
    else if (n0 < r2) { Bp = B1; noff = r1; }
    else              { Bp = B2; noff = r2; }

    f32x4 acc[4][4];
#pragma unroll
    for (int r = 0; r < 4; ++r)
#pragma unroll
        for (int c = 0; c < 4; ++c)
            acc[r][c] = (f32x4){0.f, 0.f, 0.f, 0.f};

    for (int k0 = 0; k0 < 256; k0 += 32) {
        uint4 a0 = *(const uint4*)(A + (size_t)(m0 + srow)      * 256 + k0 + skp);
        uint4 a1 = *(const uint4*)(A + (size_t)(m0 + 64 + srow) * 256 + k0 + skp);
        uint4 b0 = *(const uint4*)(W + (size_t)(n0 + srow)      * 256 + k0 + skp);
        uint4 b1 = *(const uint4*)(W + (size_t)(n0 + 64 + srow) * 256 + k0 + skp);
        __syncthreads();
        *(uint4*)(At + srow*32 + skp)      = a0;
        *(uint4*)(At + (64+srow)*32 + skp) = a1;
        *(uint4*)(Bt + srow*32 + skp)      = b0;
        *(uint4*)(Bt + (64+srow)*32 + skp) = b1;
        __syncthreads();
        short8 af[4], bf[4];
#pragma unroll
        for (int r = 0; r < 4; ++r)
            af[r] = *(const short8*)(At + (wm + 16*r + col16)*32 + quad*8);
#pragma unroll
        for (int c = 0; c < 4; ++c)
            bf[c] = *(const short8*)(Bt + (wn + 16*c + col16)*32 + quad*8);
#pragma unroll
        for (int r = 0; r < 4; ++r)
#pragma unroll
            for (int c = 0; c < 4; ++c)
                acc[r][c] = __builtin_amdgcn_mfma_f32_16x16x32_bf16(
                    af[r], bf[c], acc[r][c], 0, 0, 0);
    }

    // epilogue
    float bias_c[4];
#pragma unroll
    for (int c = 0; c < 4; ++c)
        bias_c[c] = Bp[n0 + wn + 16*c + col16 - noff];
    const bool doNorm = (n0 < normUntil);
    const bool doGelu = (n0 >= geluFrom);
#pragma unroll
    for (int r = 0; r < 4; ++r) {
#pragma unroll
        for (int reg = 0; reg < 4; ++reg) {
            const int row = m0 + wm + 16*r + quad*4 + reg;
            float v[4];
#pragma unroll
            for (int c = 0; c < 4; ++c) v[c] = acc[r][c][reg] + bias_c[c];
            if (doNorm) {
#pragma unroll
                for (int hp = 0; hp < 2; ++hp) {
                    float s = v[2*hp]*v[2*hp] + v[2*hp+1]*v[2*hp+1];
                    s += __shfl_xor(s, 1); s += __shfl_xor(s, 2);
                    s += __shfl_xor(s, 4); s += __shfl_xor(s, 8);
                    float inv = 1.0f / fmaxf(sqrtf(s), EPSF);
                    v[2*hp]   *= inv;
                    v[2*hp+1] *= inv;
                }
            }
            if (doGelu) {
#pragma unroll
                for (int c = 0; c < 4; ++c)
                    v[c] = 0.5f * v[c] * (1.0f + erff(v[c] * 0.70710678118654752f));
            }
#pragma unroll
            for (int c = 0; c < 4; ++c)
                C[(size_t)row * ldc + n0 + wn + 16*c + col16] = v[c];
        }
    }
}

// ---------------------------------------------------------------------------
__global__ __launch_bounds__(64) void gate_kernel(
    const float* __restrict__ x,
    const float* __restrict__ wg,
    const float* __restrict__ wg0,
    const float* __restrict__ wg1,
    float* __restrict__ gate)
{
    __shared__ float xs[256];
    __shared__ float dots[10];
    const int r = blockIdx.x;
    const int t = threadIdx.x;
    const float* xr = x + ((size_t)r << 8);
    xs[t] = xr[t]; xs[t+64] = xr[t+64]; xs[t+128] = xr[t+128]; xs[t+192] = xr[t+192];
    __syncthreads();
    for (int f = 0; f < 10; ++f) {
        const float* wf = (f < 4) ? (wg + f*256) : (f < 6) ? (wg0 + (f-4)*256) : (wg1 + (f-6)*256);
        float s = xs[t]*wf[t] + xs[t+64]*wf[t+64] + xs[t+128]*wf[t+128] + xs[t+192]*wf[t+192];
        for (int off = 32; off; off >>= 1) s += __shfl_xor(s, off, 64);
        if (t == 0) dots[f] = s;
    }
    __syncthreads();
    if (t == 0) {
        float e[4];
        float m = fmaxf(fmaxf(dots[0],dots[1]), fmaxf(dots[2],dots[3]));
        float ssum = 0.f;
        for (int i = 0; i < 4; ++i) { e[i] = expf(dots[i]-m); ssum += e[i]; }
        for (int i = 0; i < 4; ++i) e[i] /= ssum;
        int i1 = 0;
        for (int i = 1; i < 4; ++i) if (e[i] > e[i1]) i1 = i;
        int i2 = -1;
        for (int i = 0; i < 4; ++i) if (i != i1 && (i2 < 0 || e[i] > e[i2])) i2 = i;
        float rs = fmaxf(e[i1] + e[i2], EPSF);
        float rg[4] = {0.f,0.f,0.f,0.f};
        rg[i1] = e[i1] / rs * 2.f;
        rg[i2] = e[i2] / rs * 2.f;
        float sh[4];
        float m1 = fmaxf(fmaxf(dots[6],dots[7]), fmaxf(dots[8],dots[9]));
        float s1 = 0.f;
        for (int i = 0; i < 4; ++i) { sh[i] = expf(dots[6+i]-m1); s1 += sh[i]; }
        float mm = fmaxf(dots[4], dots[5]);
        float e0 = expf(dots[4]-mm), e1 = expf(dots[5]-mm);
        float w00 = e0/(e0+e1)*2.f, w01 = e1/(e0+e1)*2.f;
        float* gr = gate + ((size_t)r << 3);
        for (int i = 0; i < 4; ++i) gr[i]   = w00 * (sh[i]/s1*4.f);
        for (int i = 0; i < 4; ++i) gr[4+i] = w01 * rg[i];
    }
}

// ---------------------------------------------------------------------------
__global__ __launch_bounds__(256) void pool_ln_kernel(
    const float* __restrict__ buf,
    const float* __restrict__ g, const float* __restrict__ bb,
    float* __restrict__ xp)
{
    __shared__ float r1[256], r2[256];
    const int blk = blockIdx.x;
    const int b = blk >> 6, p = blk & 63;
    const int py = p >> 3, px = p & 7;
    const int t = threadIdx.x;
    float acc = 0.f;
    for (int dy = 0; dy < 8; ++dy)
#pragma unroll
        for (int dx = 0; dx < 8; ++dx) {
            int s = ((py*8+dy) << 6) + px*8 + dx;
            acc += buf[(((size_t)(b*4096+s)) << 10) + 768 + t];
        }
    acc *= (1.0f/64.0f);
    r1[t] = acc; r2[t] = acc*acc;
    __syncthreads();
    for (int off = 128; off; off >>= 1) {
        if (t < off) { r1[t] += r1[t+off]; r2[t] += r2[t+off]; }
        __syncthreads();
    }
    float mu  = r1[0] * (1.0f/256.0f);
    float var = r2[0] * (1.0f/256.0f) - mu*mu;
    float rstd = rsqrtf(var + 1e-5f);
    xp[((size_t)blk << 8) + t] = (acc - mu) * rstd * g[t] + bb[t];
}

// ---------------------------------------------------------------------------
__global__ __launch_bounds__(256) void kvpool_kernel(
    const float* __restrict__ xp,
    const float* __restrict__ kv_w, const float* __restrict__ kv_b,
    float* __restrict__ kpool, float* __restrict__ vpool)
{
    __shared__ float xs[256];
    __shared__ float row[512];
    __shared__ float inv[8];
    const int blk = blockIdx.x;
    const int t = threadIdx.x;
    xs[t] = xp[((size_t)blk << 8) + t];
    __syncthreads();
    for (int o = t; o < 512; o += 256) {
        const float* wr = kv_w + ((size_t)o << 8);
        float s = kv_b[o];
        for (int k = 0; k < 256; ++k) s += xs[k]*wr[k];
        row[o] = s;
    }
    __syncthreads();
    if (t < 8) {
        float s = 0.f;
        for (int dd = 0; dd < 32; ++dd) { float v = row[t*32+dd]; s += v*v; }
        inv[t] = 1.0f / fmaxf(sqrtf(s), EPSF);
    }
    __syncthreads();
    const int b = blk >> 6, p = blk & 63, h = t >> 5, dd = t & 31;
    size_t o = ((((size_t)(b*8+h))*64 + p) << 5) + dd;
    kpool[o] = row[t] * inv[h];
    vpool[o] = row[256 + t];
}

// ---------------------------------------------------------------------------
__global__ __launch_bounds__(256) void cpb_kernel(
    const float* __restrict__ tbl,
    const float* __restrict__ w1, const float* __restrict__ b1,
    const float* __restrict__ w2, const float* __restrict__ b2,
    float* __restrict__ cpb)
{
    __shared__ float hid[512];
    const int r = blockIdx.x, t = threadIdx.x;
    const float c0 = tbl[(size_t)r*2], c1 = tbl[(size_t)r*2+1];
    for (int i = t; i < 512; i += 256)
        hid[i] = fmaxf(c0*w1[i*2] + c1*w1[i*2+1] + b1[i], 0.f);
    __syncthreads();
    const int h = t >> 5, dd = t & 31;
    float s = 0.f;
    for (int i = dd; i < 512; i += 32) s += hid[i] * w2[h*512+i];
    for (int off = 16; off; off >>= 1) s += __shfl_xor(s, off, 32);
    if (dd == 0) cpb[((size_t)r << 3) + h] = s + b2[h];
}

// ---------------------------------------------------------------------------
// Tiled attention (round-3 structure; output now bf16 compact 16384x256).
// ---------------------------------------------------------------------------
__global__ __launch_bounds__(256, 3) void attn_tiled(
    const float* __restrict__ buf,
    unsigned short* __restrict__ ao,          // (16384,256) bf16
    const float* __restrict__ kpool,
    const float* __restrict__ vpool,
    const float* __restrict__ cpb,
    const int*   __restrict__ rpi,
    const float* __restrict__ temp,
    const float* __restrict__ qe,
    const float* __restrict__ rpb,
    const float* __restrict__ lt,    // (8,32,9)
    const float* __restrict__ lb,    // (8,1,9)
    const float* __restrict__ gate)
{
    __shared__ float kvh[100*36];
    __shared__ float kpL[64*36];
    __shared__ float aw[64*74];
    __shared__ float ltb[9*64];
    __shared__ float dq[12];
    const int tile = blockIdx.x;
    const int h    = blockIdx.y;
    const int b    = blockIdx.z;
    const int ty0  = (tile >> 3) << 3;
    const int tx0  = (tile & 7) << 3;
    const int t    = threadIdx.x;

    for (int i = t; i < 3200; i += 256) {
        int r = i >> 5, d = i & 31;
        int hy = ty0 + r/10 - 1, hx = tx0 + r%10 - 1;
        float v = 0.f;
        if (hy >= 0 && hy < 64 && hx >= 0 && hx < 64)
            v = buf[(((size_t)(b*4096 + ((hy<<6)|hx))) << 10) + 256 + h*32 + d];
        kvh[r*36 + d] = v;
    }
    {
        const float* src = kpool + ((size_t)(b*8+h) << 11);
        for (int i = t; i < 2048; i += 256)
            kpL[(i >> 5)*36 + (i & 31)] = src[i];
    }
    if (t < 9) {
        float s = 0.f;
        for (int dd = 0; dd < 32; ++dd)
            s += qe[h*32+dd] * lt[(h*32+dd)*9 + t];
        dq[t] = s;
    }

    const int n   = t & 63;
    const int g   = t >> 6;
    const int y   = ty0 + (n >> 3);
    const int x   = tx0 + (n & 7);
    const int ngl = (y << 6) | x;
    const float spt = log1pf(expf(temp[h]));
    const int cy = (y == 0 || y == 63) ? 2 : 3;
    const int cx = (x == 0 || x == 63) ? 2 : 3;
    const float sc = spt * logf((float)(cy*cx) + 64.0f);
    const float inv_sc = 1.0f / sc;
    float4 q4[8];
    {
        const float4* qp = (const float4*)(buf + (((size_t)(b*4096 + ngl)) << 10) + h*32);
        const float4* qep = (const float4*)(qe + h*32);
#pragma unroll
        for (int i = 0; i < 8; ++i) {
            float4 qv = qp[i], e = qep[i];
            q4[i].x = (qv.x + e.x) * sc;
            q4[i].y = (qv.y + e.y) * sc;
            q4[i].z = (qv.z + e.z) * sc;
            q4[i].w = (qv.w + e.w) * sc;
        }
    }
    __syncthreads();

    for (int j = g; j < 73; j += 4) {
        float acc;
        if (j < 9) {
            int hr = ((n>>3) + j/3)*10 + (n&7) + (j%3);
            const float4* kr = (const float4*)(kvh + hr*36);
            float d0 = 0.f;
#pragma unroll
            for (int dd = 0; dd < 8; ++dd) {
                float4 kv = kr[dd];
                d0 += q4[dd].x*kv.x + q4[dd].y*kv.y + q4[dd].z*kv.z + q4[dd].w*kv.w;
            }
            acc = d0 + rpb[h*9 + j];
            const float* lp = lt + (h*32)*9 + j;
            float s = 0.f;
#pragma unroll
            for (int dd = 0; dd < 8; ++dd) {
                s += q4[dd].x * lp[(4*dd+0)*9] + q4[dd].y * lp[(4*dd+1)*9]
                   + q4[dd].z * lp[(4*dd+2)*9] + q4[dd].w * lp[(4*dd+3)*9];
            }
            ltb[j*64 + n] = s * inv_sc - dq[j] + lb[h*9 + j];
        } else {
            int p = j - 9;
            const float4* kr = (const float4*)(kpL + p*36);
            float d0 = 0.f;
#pragma unroll
            for (int dd = 0; dd < 8; ++dd) {
                float4 kv = kr[dd];
                d0 += q4[dd].x*kv.x + q4[dd].y*kv.y + q4[dd].z*kv.z + q4[dd].w*kv.w;
            }
            acc = d0 + cpb[((size_t)rpi[(size_t)ngl*64 + p] << 3) + h];
        }
        aw[n*74 + j] = acc;
    }
    __syncthreads();

    for (int i = t; i < 3200; i += 256) {
        int r = i >> 5, d = i & 31;
        int hy = ty0 + r/10 - 1, hx = tx0 + r%10 - 1;
        float v = 0.f;
        if (hy >= 0 && hy < 64 && hx >= 0 && hx < 64)
            v = buf[(((size_t)(b*4096 + ((hy<<6)|hx))) << 10) + 512 + h*32 + d];
        kvh[r*36 + d] = v;
    }
    {
        const float* src = vpool + ((size_t)(b*8+h) << 11);
        for (int i = t; i < 2048; i += 256)
            kpL[(i >> 5)*36 + (i & 31)] = src[i];
    }

    {
        const int sn = t >> 2, sub = t & 3;
        float m = -1e30f;
        for (int j = sub; j < 73; j += 4) m = fmaxf(m, aw[sn*74 + j]);
        m = fmaxf(m, __shfl_xor(m, 1, 4));
        m = fmaxf(m, __shfl_xor(m, 2, 4));
        float ssum = 0.f;
        for (int j = sub; j < 73; j += 4) ssum += __builtin_expf(aw[sn*74 + j] - m);
        ssum += __shfl_xor(ssum, 1, 4);
        ssum += __shfl_xor(ssum, 2, 4);
        float iv = 1.0f / ssum;
        for (int j = sub; j < 73; j += 4) {
            float w = __builtin_expf(aw[sn*74 + j] - m) * iv;
            if (j < 9) w += ltb[j*64 + sn];
            aw[sn*74 + j] = w;
        }
    }
    __syncthreads();

    {
        const int sn = t >> 2, sub = t & 3;
        const int d0 = sub << 3;
        float4 a0 = {0.f,0.f,0.f,0.f}, a1 = {0.f,0.f,0.f,0.f};
#pragma unroll
        for (int j = 0; j < 9; ++j) {
            float w = aw[sn*74 + j];
            int hr = ((sn>>3) + j/3)*10 + (sn&7) + (j%3);
            const float4* vr = (const float4*)(kvh + hr*36 + d0);
            float4 v0 = vr[0], v1 = vr[1];
            a0.x += w*v0.x; a0.y += w*v0.y; a0.z += w*v0.z; a0.w += w*v0.w;
            a1.x += w*v1.x; a1.y += w*v1.y; a1.z += w*v1.z; a1.w += w*v1.w;
        }
#pragma unroll 4
        for (int p = 0; p < 64; ++p) {
            float w = aw[sn*74 + 9 + p];
            const float4* vr = (const float4*)(kpL + p*36 + d0);
            float4 v0 = vr[0], v1 = vr[1];
            a0.x += w*v0.x; a0.y += w*v0.y; a0.z += w*v0.z; a0.w += w*v0.w;
            a1.x += w*v1.x; a1.y += w*v1.y; a1.z += w*v1.z; a1.w += w*v1.w;
        }
        const int sy = ty0 + (sn >> 3), sx = tx0 + (sn & 7);
        const int sng = (sy << 6) | sx;
        float gt = gate[((size_t)(b*4096 + sng) << 3) + h];
        uint4 o;
        o.x = (unsigned)f2bf(a0.x*gt) | ((unsigned)f2bf(a0.y*gt) << 16);
        o.y = (unsigned)f2bf(a0.z*gt) | ((unsigned)f2bf(a0.w*gt) << 16);
        o.z = (unsigned)f2bf(a1.x*gt) | ((unsigned)f2bf(a1.y*gt) << 16);
        o.w = (unsigned)f2bf(a1.z*gt) | ((unsigned)f2bf(a1.w*gt) << 16);
        *(uint4*)(ao + (size_t)(b*4096 + sng)*256 + h*32 + d0) = o;
    }
}

// ---------------------------------------------------------------------------
extern "C" void kernel_launch(void* const* d_in, const int* in_sizes, int n_in,
                              void* d_out, int out_size, void* d_ws, size_t ws_size,
                              hipStream_t stream)
{
    const float* x    = (const float*)d_in[0];
    const float* tbl  = (const float*)d_in[1];
    const float* q_w  = (const float*)d_in[2];
    const float* q_b  = (const float*)d_in[3];
    const float* kv_w = (const float*)d_in[4];
    const float* kv_b = (const float*)d_in[5];
    const float* temp = (const float*)d_in[6];
    const float* qe   = (const float*)d_in[7];
    const float* rpb  = (const float*)d_in[8];
    const float* lt   = (const float*)d_in[9];
    const float* lb   = (const float*)d_in[10];
    const float* c1w  = (const float*)d_in[11];
    const float* c1b  = (const float*)d_in[12];
    const float* c2w  = (const float*)d_in[13];
    const float* c2b  = (const float*)d_in[14];
    const float* sr_w = (const float*)d_in[15];
    const float* sr_b = (const float*)d_in[16];
    const float* ng   = (const float*)d_in[17];
    const float* nbias= (const float*)d_in[18];
    const float* wg   = (const float*)d_in[19];
    const float* wg0  = (const float*)d_in[20];
    const float* wg1  = (const float*)d_in[21];
    const float* pw   = (const float*)d_in[22];
    const float* pb   = (const float*)d_in[23];
    const int*   rpi  = (const int*)d_in[24];
    (void)in_sizes; (void)n_in; (void)out_size; (void)ws_size;

    // workspace layout (floats):
    float* buf   = (float*)d_ws;                       // 16384x1024
    float* xp    = buf + (size_t)16384*1024;           // 65536
    float* kpool = xp + 65536;                         // 65536
    float* vpool = kpool + 65536;                      // 65536
    float* cpbb  = vpool + 65536;                      // 32768
    float* gateb = cpbb + 32768;                       // 131072
    unsigned short* xbf  = (unsigned short*)(gateb + 131072); // 4.19M ush (shared with ao)
    unsigned short* ao   = xbf;                        // attn out bf16 (x_bf dead by then)
    unsigned short* wcat = xbf + (size_t)16384*256;    // 262144 ush
    unsigned short* pwbf = wcat + 262144;              // 65536 ush
    float* out   = (float*)d_out;

    // 0) dtype conversions
    convert_x<<<4096,256,0,stream>>>(x, xbf);
    convert_w<<<320,256,0,stream>>>(q_w, kv_w, sr_w, pw, wcat, pwbf);
    // 1) fused MFMA GEMM: q (cols 0-255, L2-normed), k (256-511, L2-normed),
    //    v (512-767), gelu(sr) (768-1023)
    gemm_mfma<<<dim3(8,128),256,0,stream>>>(xbf, wcat, q_b, kv_b, sr_b,
                                            256, 768, 512, 768, buf, 1024);
    // 2) MoE gates
    gate_kernel<<<16384,64,0,stream>>>(x, wg, wg0, wg1, gateb);
    // 3) 8x8 avg-pool + LayerNorm of gelu(sr)
    pool_ln_kernel<<<256,256,0,stream>>>(buf, ng, nbias, xp);
    // 4) pooled kv + k-norm (fp32, exact)
    kvpool_kernel<<<256,256,0,stream>>>(xp, kv_w, kv_b, kpool, vpool);
    // 5) CPB bias table
    cpb_kernel<<<4096,256,0,stream>>>(tbl, c1w, c1b, c2w, c2b, cpbb);
    // 6) tiled attention -> bf16 compact (reuses x_bf region)
    attn_tiled<<<dim3(64,8,4),256,0,stream>>>(buf, ao, kpool, vpool, cpbb, rpi,
                                              temp, qe, rpb, lt, lb, gateb);
    // 7) output projection (MFMA)
    gemm_mfma<<<dim3(2,128),256,0,stream>>>(ao, pwbf, pb, pb, pb,
                                            1<<30, 1<<30, 0, 1<<30, out, 256);
}

// Round 5
// 318.457 us; speedup vs baseline: 1.8775x; 1.0041x over previous
//
#include <hip/hip_runtime.h>
#include <math.h>

#define EPSF 1.1920929e-07f

typedef __attribute__((ext_vector_type(8))) short short8;
typedef __attribute__((ext_vector_type(4))) float f32x4;

// float -> bf16 (RNE)
static __device__ __forceinline__ unsigned short f2bf(float f) {
    unsigned int u = __float_as_uint(f);
    return (unsigned short)((u + 0x7FFFu + ((u >> 16) & 1u)) >> 16);
}
static __device__ __forceinline__ float bf2f(unsigned short u) {
    return __uint_as_float((unsigned int)u << 16);
}

// ---------------------------------------------------------------------------
// x (16384x256 f32) -> bf16
// ---------------------------------------------------------------------------
__global__ __launch_bounds__(256) void convert_x(
    const float* __restrict__ x, unsigned short* __restrict__ xbf)
{
    const int e = (blockIdx.x * 256 + threadIdx.x) * 4;
    float4 v = *(const float4*)(x + e);
    ushort4 o;
    o.x = f2bf(v.x); o.y = f2bf(v.y); o.z = f2bf(v.z); o.w = f2bf(v.w);
    *(ushort4*)(xbf + e) = o;
}

// ---------------------------------------------------------------------------
// weights -> bf16: wcat rows 0..255 = q_w, 256..767 = kv_w, 768..1023 = sr_w;
// then pw (256x256).
// ---------------------------------------------------------------------------
__global__ __launch_bounds__(256) void convert_w(
    const float* __restrict__ q_w, const float* __restrict__ kv_w,
    const float* __restrict__ sr_w, const float* __restrict__ pw,
    unsigned short* __restrict__ wcat, unsigned short* __restrict__ pwbf)
{
    const int e = (blockIdx.x * 256 + threadIdx.x) * 4;
    if (e < 262144) {
        int n = e >> 8, k = e & 255;
        const float* src = (n < 256) ? (q_w + n*256) :
                           (n < 768) ? (kv_w + (n-256)*256) : (sr_w + (n-768)*256);
        float4 v = *(const float4*)(src + k);
        ushort4 o;
        o.x = f2bf(v.x); o.y = f2bf(v.y); o.z = f2bf(v.z); o.w = f2bf(v.w);
        *(ushort4*)(wcat + e) = o;
    } else {
        int e2 = e - 262144;
        float4 v = *(const float4*)(pw + e2);
        ushort4 o;
        o.x = f2bf(v.x); o.y = f2bf(v.y); o.z = f2bf(v.z); o.w = f2bf(v.w);
        *(ushort4*)(pwbf + e2) = o;
    }
}

// ---------------------------------------------------------------------------
// MFMA bf16 GEMM, K=256 (unchanged from round 4).
// ---------------------------------------------------------------------------
__global__ __launch_bounds__(256) void gemm_mfma(
    const unsigned short* __restrict__ A,
    const unsigned short* __restrict__ W,
    const float* __restrict__ B0, const float* __restrict__ B1,
    const float* __restrict__ B2,
    int r1, int r2, int normUntil, int geluFrom,
    float* __restrict__ C, int ldc)
{
    __shared__ unsigned short At[128*32];
    __shared__ unsigned short Bt[128*32];
    const int m0 = blockIdx.y << 7;
    const int n0 = blockIdx.x << 7;
    const int t  = threadIdx.x;
    const int w  = t >> 6;
    const int l  = t & 63;
    const int wm = (w >> 1) << 6;
    const int wn = (w & 1) << 6;
    const int col16 = l & 15;
    const int quad  = l >> 4;
    const int srow = t >> 2;
    const int skp  = (t & 3) << 3;

    const float* Bp; int noff;
    if (n0 < r1)      { Bp = B0; noff = 0;  }
    else if (n0 < r2) { Bp = B1; noff = r1; }
    else              { Bp = B2; noff = r2; }

    f32x4 acc[4][4];
#pragma unroll
    for (int r = 0; r < 4; ++r)
#pragma unroll
        for (int c = 0; c < 4; ++c)
            acc[r][c] = (f32x4){0.f, 0.f, 0.f, 0.f};

    for (int k0 = 0; k0 < 256; k0 += 32) {
        uint4 a0 = *(const uint4*)(A + (size_t)(m0 + srow)      * 256 + k0 + skp);
        uint4 a1 = *(const uint4*)(A + (size_t)(m0 + 64 + srow) * 256 + k0 + skp);
        uint4 b0 = *(const uint4*)(W + (size_t)(n0 + srow)      * 256 + k0 + skp);
        uint4 b1 = *(const uint4*)(W + (size_t)(n0 + 64 + srow) * 256 + k0 + skp);
        __syncthreads();
        *(uint4*)(At + srow*32 + skp)      = a0;
        *(uint4*)(At + (64+srow)*32 + skp) = a1;
        *(uint4*)(Bt + srow*32 + skp)      = b0;
        *(uint4*)(Bt + (64+srow)*32 + skp) = b1;
        __syncthreads();
        short8 af[4], bf[4];
#pragma unroll
        for (int r = 0; r < 4; ++r)
            af[r] = *(const short8*)(At + (wm + 16*r + col16)*32 + quad*8);
#pragma unroll
        for (int c = 0; c < 4; ++c)
            bf[c] = *(const short8*)(Bt + (wn + 16*c + col16)*32 + quad*8);
#pragma unroll
        for (int r = 0; r < 4; ++r)
#pragma unroll
            for (int c = 0; c < 4; ++c)
                acc[r][c] = __builtin_amdgcn_mfma_f32_16x16x32_bf16(
                    af[r], bf[c], acc[r][c], 0, 0, 0);
    }

    float bias_c[4];
#pragma unroll
    for (int c = 0; c < 4; ++c)
        bias_c[c] = Bp[n0 + wn + 16*c + col16 - noff];
    const bool doNorm = (n0 < normUntil);
    const bool doGelu = (n0 >= geluFrom);
#pragma unroll
    for (int r = 0; r < 4; ++r) {
#pragma unroll
        for (int reg = 0; reg < 4; ++reg) {
            const int row = m0 + wm + 16*r + quad*4 + reg;
            float v[4];
#pragma unroll
            for (int c = 0; c < 4; ++c) v[c] = acc[r][c][reg] + bias_c[c];
            if (doNorm) {
#pragma unroll
                for (int hp = 0; hp < 2; ++hp) {
                    float s = v[2*hp]*v[2*hp] + v[2*hp+1]*v[2*hp+1];
                    s += __shfl_xor(s, 1); s += __shfl_xor(s, 2);
                    s += __shfl_xor(s, 4); s += __shfl_xor(s, 8);
                    float inv = 1.0f / fmaxf(sqrtf(s), EPSF);
                    v[2*hp]   *= inv;
                    v[2*hp+1] *= inv;
                }
            }
            if (doGelu) {
#pragma unroll
                for (int c = 0; c < 4; ++c)
                    v[c] = 0.5f * v[c] * (1.0f + erff(v[c] * 0.70710678118654752f));
            }
#pragma unroll
            for (int c = 0; c < 4; ++c)
                C[(size_t)row * ldc + n0 + wn + 16*c + col16] = v[c];
        }
    }
}

// ---------------------------------------------------------------------------
__global__ __launch_bounds__(64) void gate_kernel(
    const float* __restrict__ x,
    const float* __restrict__ wg,
    const float* __restrict__ wg0,
    const float* __restrict__ wg1,
    float* __restrict__ gate)
{
    __shared__ float xs[256];
    __shared__ float dots[10];
    const int r = blockIdx.x;
    const int t = threadIdx.x;
    const float* xr = x + ((size_t)r << 8);
    xs[t] = xr[t]; xs[t+64] = xr[t+64]; xs[t+128] = xr[t+128]; xs[t+192] = xr[t+192];
    __syncthreads();
    for (int f = 0; f < 10; ++f) {
        const float* wf = (f < 4) ? (wg + f*256) : (f < 6) ? (wg0 + (f-4)*256) : (wg1 + (f-6)*256);
        float s = xs[t]*wf[t] + xs[t+64]*wf[t+64] + xs[t+128]*wf[t+128] + xs[t+192]*wf[t+192];
        for (int off = 32; off; off >>= 1) s += __shfl_xor(s, off, 64);
        if (t == 0) dots[f] = s;
    }
    __syncthreads();
    if (t == 0) {
        float e[4];
        float m = fmaxf(fmaxf(dots[0],dots[1]), fmaxf(dots[2],dots[3]));
        float ssum = 0.f;
        for (int i = 0; i < 4; ++i) { e[i] = expf(dots[i]-m); ssum += e[i]; }
        for (int i = 0; i < 4; ++i) e[i] /= ssum;
        int i1 = 0;
        for (int i = 1; i < 4; ++i) if (e[i] > e[i1]) i1 = i;
        int i2 = -1;
        for (int i = 0; i < 4; ++i) if (i != i1 && (i2 < 0 || e[i] > e[i2])) i2 = i;
        float rs = fmaxf(e[i1] + e[i2], EPSF);
        float rg[4] = {0.f,0.f,0.f,0.f};
        rg[i1] = e[i1] / rs * 2.f;
        rg[i2] = e[i2] / rs * 2.f;
        float sh[4];
        float m1 = fmaxf(fmaxf(dots[6],dots[7]), fmaxf(dots[8],dots[9]));
        float s1 = 0.f;
        for (int i = 0; i < 4; ++i) { sh[i] = expf(dots[6+i]-m1); s1 += sh[i]; }
        float mm = fmaxf(dots[4], dots[5]);
        float e0 = expf(dots[4]-mm), e1 = expf(dots[5]-mm);
        float w00 = e0/(e0+e1)*2.f, w01 = e1/(e0+e1)*2.f;
        float* gr = gate + ((size_t)r << 3);
        for (int i = 0; i < 4; ++i) gr[i]   = w00 * (sh[i]/s1*4.f);
        for (int i = 0; i < 4; ++i) gr[4+i] = w01 * rg[i];
    }
}

// ---------------------------------------------------------------------------
__global__ __launch_bounds__(256) void pool_ln_kernel(
    const float* __restrict__ buf,
    const float* __restrict__ g, const float* __restrict__ bb,
    float* __restrict__ xp)
{
    __shared__ float r1[256], r2[256];
    const int blk = blockIdx.x;
    const int b = blk >> 6, p = blk & 63;
    const int py = p >> 3, px = p & 7;
    const int t = threadIdx.x;
    float acc = 0.f;
    for (int dy = 0; dy < 8; ++dy)
#pragma unroll
        for (int dx = 0; dx < 8; ++dx) {
            int s = ((py*8+dy) << 6) + px*8 + dx;
            acc += buf[(((size_t)(b*4096+s)) << 10) + 768 + t];
        }
    acc *= (1.0f/64.0f);
    r1[t] = acc; r2[t] = acc*acc;
    __syncthreads();
    for (int off = 128; off; off >>= 1) {
        if (t < off) { r1[t] += r1[t+off]; r2[t] += r2[t+off]; }
        __syncthreads();
    }
    float mu  = r1[0] * (1.0f/256.0f);
    float var = r2[0] * (1.0f/256.0f) - mu*mu;
    float rstd = rsqrtf(var + 1e-5f);
    xp[((size_t)blk << 8) + t] = (acc - mu) * rstd * g[t] + bb[t];
}

// ---------------------------------------------------------------------------
__global__ __launch_bounds__(256) void kvpool_kernel(
    const float* __restrict__ xp,
    const float* __restrict__ kv_w, const float* __restrict__ kv_b,
    float* __restrict__ kpool, float* __restrict__ vpool)
{
    __shared__ float xs[256];
    __shared__ float row[512];
    __shared__ float inv[8];
    const int blk = blockIdx.x;
    const int t = threadIdx.x;
    xs[t] = xp[((size_t)blk << 8) + t];
    __syncthreads();
    for (int o = t; o < 512; o += 256) {
        const float* wr = kv_w + ((size_t)o << 8);
        float s = kv_b[o];
        for (int k = 0; k < 256; ++k) s += xs[k]*wr[k];
        row[o] = s;
    }
    __syncthreads();
    if (t < 8) {
        float s = 0.f;
        for (int dd = 0; dd < 32; ++dd) { float v = row[t*32+dd]; s += v*v; }
        inv[t] = 1.0f / fmaxf(sqrtf(s), EPSF);
    }
    __syncthreads();
    const int b = blk >> 6, p = blk & 63, h = t >> 5, dd = t & 31;
    size_t o = ((((size_t)(b*8+h))*64 + p) << 5) + dd;
    kpool[o] = row[t] * inv[h];
    vpool[o] = row[256 + t];
}

// ---------------------------------------------------------------------------
__global__ __launch_bounds__(256) void cpb_kernel(
    const float* __restrict__ tbl,
    const float* __restrict__ w1, const float* __restrict__ b1,
    const float* __restrict__ w2, const float* __restrict__ b2,
    float* __restrict__ cpb)
{
    __shared__ float hid[512];
    const int r = blockIdx.x, t = threadIdx.x;
    const float c0 = tbl[(size_t)r*2], c1 = tbl[(size_t)r*2+1];
    for (int i = t; i < 512; i += 256)
        hid[i] = fmaxf(c0*w1[i*2] + c1*w1[i*2+1] + b1[i], 0.f);
    __syncthreads();
    const int h = t >> 5, dd = t & 31;
    float s = 0.f;
    for (int i = dd; i < 512; i += 32) s += hid[i] * w2[h*512+i];
    for (int off = 16; off; off >>= 1) s += __shfl_xor(s, off, 32);
    if (dd == 0) cpb[((size_t)r << 3) + h] = s + b2[h];
}

// ---------------------------------------------------------------------------
// MFMA attention: one block per (b, h, 8x8 token tile), 4 waves, wave = m-tile.
// Logits: 64x112 (halo, invalid slots masked -1e30) + 64x64 (pooled) via
// 16x16x32 MFMA (K=32 = head dim, one k-step). Softmax in C-layout regs.
// P (softmaxed weights) -> LDS bf16 [64][200]; learnable-token term = one
// MFMA (qs . lt^T) scaled by 1/sc, scatter-added into P. PV: one GEMM over
// K=192 (128 halo-pad + 64 pooled) with V staged transposed (b128 B-frags).
// All LDS rows 16B-aligned strides with <=2-way bank aliasing (free, m136).
// ---------------------------------------------------------------------------
__global__ __launch_bounds__(256, 2) void attn_mfma(
    const float* __restrict__ buf,
    unsigned short* __restrict__ ao,          // (16384,256) bf16
    const float* __restrict__ kpool,
    const float* __restrict__ vpool,
    const float* __restrict__ cpb,
    const int*   __restrict__ rpi,
    const float* __restrict__ temp,
    const float* __restrict__ qe,
    const float* __restrict__ rpb,
    const float* __restrict__ lt,    // (8,32,9)
    const float* __restrict__ lb,    // (8,1,9)
    const float* __restrict__ gate)
{
    __shared__ __attribute__((aligned(16))) unsigned short KH[112*40]; // halo K [key][dim], rows 100..111 zero
    __shared__ __attribute__((aligned(16))) unsigned short KP[64*40];  // pooled K
    __shared__ __attribute__((aligned(16))) unsigned short QS[64*40];  // scaled q
    __shared__ __attribute__((aligned(16))) unsigned short VT[32*136]; // halo V^T [dim][key], cols 100..127 zero
    __shared__ __attribute__((aligned(16))) unsigned short VPT[32*72]; // pooled V^T [dim][key]
    __shared__ __attribute__((aligned(16))) unsigned short P[64*200];  // weights [tok][192], cols 112..127 zero
    __shared__ __attribute__((aligned(16))) unsigned short LTT[16*40]; // lt^T [j][dim], rows 9..15 zero
    __shared__ float biasP[64*68];   // pooled cpb bias (f32)
    __shared__ float scL[64], invscL[64], gateL[64], rpbL[9], dqvL[16];

    const int tile = blockIdx.x;
    const int h    = blockIdx.y;
    const int b    = blockIdx.z;
    const int ty0  = (tile >> 3) << 3;
    const int tx0  = (tile & 7) << 3;
    const int t    = threadIdx.x;

    // ---- S0: per-token scales, gates, per-head tables ----
    const float spt = log1pf(expf(temp[h]));
    if (t < 64) {
        int y = ty0 + (t >> 3), x = tx0 + (t & 7);
        int cy = (y == 0 || y == 63) ? 2 : 3;
        int cx = (x == 0 || x == 63) ? 2 : 3;
        float sc = spt * logf((float)(cy*cx) + 64.0f);
        scL[t] = sc; invscL[t] = 1.0f / sc;
        gateL[t] = gate[(((size_t)(b*4096 + ((y<<6)|x))) << 3) + h];
    } else if (t < 80) {
        int j = t - 64;
        float s = 0.f;
        if (j < 9) {
            s = lb[h*9 + j];
            for (int dd = 0; dd < 32; ++dd)
                s -= qe[h*32+dd] * lt[(h*32+dd)*9 + j];
        }
        dqvL[j] = s;                       // lb - dot(qe, lt_j)
    } else if (t < 89) {
        rpbL[t-89+9] = rpb[h*9 + (t-80)];  // rpbL[t-80]
    }
    for (int i = t; i < 16*32; i += 256) {
        int j = i >> 5, dd = i & 31;
        LTT[j*40 + dd] = (j < 9) ? f2bf(lt[(h*32+dd)*9 + j]) : (unsigned short)0;
    }
    __syncthreads();

    // ---- S1: stage K/V/Q/pool/bias ----
    for (int i = t; i < 112*32; i += 256) {          // halo K (+zero rows)
        int r = i >> 5, d = i & 31;
        float v = 0.f;
        if (r < 100) {
            int y = ty0 + r/10 - 1, x = tx0 + r%10 - 1;
            if (y >= 0 && y < 64 && x >= 0 && x < 64)
                v = buf[(((size_t)(b*4096 + ((y<<6)|x))) << 10) + 256 + h*32 + d];
        }
        KH[r*40 + d] = f2bf(v);
    }
    for (int i = t; i < 112*32; i += 256) {          // halo V transposed
        int r = i >> 5, d = i & 31;
        float v = 0.f;
        if (r < 100) {
            int y = ty0 + r/10 - 1, x = tx0 + r%10 - 1;
            if (y >= 0 && y < 64 && x >= 0 && x < 64)
                v = buf[(((size_t)(b*4096 + ((y<<6)|x))) << 10) + 512 + h*32 + d];
        }
        VT[d*136 + r] = f2bf(v);
    }
    for (int i = t; i < 16*32; i += 256) {           // VT zero cols 112..127
        int r = 112 + (i >> 5), d = i & 31;
        VT[d*136 + r] = 0;
    }
    for (int i = t; i < 2048; i += 256) {            // pooled K
        int p = i >> 5, d = i & 31;
        KP[p*40 + d] = f2bf(kpool[(((size_t)(b*8+h))*64 + p)*32 + d]);
    }
    for (int i = t; i < 2048; i += 256) {            // pooled V transposed
        int p = i >> 5, d = i & 31;
        VPT[d*72 + p] = f2bf(vpool[(((size_t)(b*8+h))*64 + p)*32 + d]);
    }
    for (int i = t; i < 2048; i += 256) {            // scaled q
        int n = i >> 5, d = i & 31;
        int y = ty0 + (n >> 3), x = tx0 + (n & 7);
        float qv = buf[(((size_t)(b*4096 + ((y<<6)|x))) << 10) + h*32 + d];
        QS[n*40 + d] = f2bf((qv + qe[h*32+d]) * scL[n]);
    }
    for (int i = t; i < 4096; i += 256) {            // pooled cpb bias
        int n = i >> 6, p = i & 63;
        int y = ty0 + (n >> 3), x = tx0 + (n & 7);
        int ngl = (y << 6) | x;
        biasP[n*68 + p] = cpb[((size_t)rpi[(size_t)ngl*64 + p] << 3) + h];
    }
    for (int i = t; i < 1024; i += 256) {            // P zero cols 112..127
        int n = i >> 4, c = 112 + (i & 15);
        P[n*200 + c] = 0;
    }
    __syncthreads();

    // ---- QK logits (wave = m-tile) ----
    const int lane  = t & 63;
    const int w     = t >> 6;
    const int col16 = lane & 15;
    const int quad  = lane >> 4;
    short8 aq = *(const short8*)(QS + (w*16 + col16)*40 + quad*8);
    f32x4 cl[7], cp[4];
    {
        const f32x4 z = {0.f, 0.f, 0.f, 0.f};
#pragma unroll
        for (int ct = 0; ct < 7; ++ct) {
            short8 bk = *(const short8*)(KH + (ct*16 + col16)*40 + quad*8);
            cl[ct] = __builtin_amdgcn_mfma_f32_16x16x32_bf16(aq, bk, z, 0, 0, 0);
        }
#pragma unroll
        for (int ct = 0; ct < 4; ++ct) {
            short8 bp = *(const short8*)(KP + (ct*16 + col16)*40 + quad*8);
            cp[ct] = __builtin_amdgcn_mfma_f32_16x16x32_bf16(aq, bp, z, 0, 0, 0);
        }
    }
    // bias + mask
#pragma unroll
    for (int ct = 0; ct < 7; ++ct) {
        int hk = ct*16 + col16;
        int ky = hk / 10, kx = hk - ky*10;
#pragma unroll
        for (int reg = 0; reg < 4; ++reg) {
            int n = w*16 + quad*4 + reg;
            int dy = ky - (n >> 3), dx = kx - (n & 7);
            bool valid = (dy >= 0 && dy <= 2 && dx >= 0 && dx <= 2);
            cl[ct][reg] = valid ? (cl[ct][reg] + rpbL[dy*3 + dx]) : -1e30f;
        }
    }
#pragma unroll
    for (int ct = 0; ct < 4; ++ct) {
        int p = ct*16 + col16;
#pragma unroll
        for (int reg = 0; reg < 4; ++reg) {
            int n = w*16 + quad*4 + reg;
            cp[ct][reg] += biasP[n*68 + p];
        }
    }
    // softmax (row = (quad,reg); reduce over 16 col-lanes)
    float inv[4];
#pragma unroll
    for (int reg = 0; reg < 4; ++reg) {
        float m = -1e30f;
#pragma unroll
        for (int ct = 0; ct < 7; ++ct) m = fmaxf(m, cl[ct][reg]);
#pragma unroll
        for (int ct = 0; ct < 4; ++ct) m = fmaxf(m, cp[ct][reg]);
        m = fmaxf(m, __shfl_xor(m, 1)); m = fmaxf(m, __shfl_xor(m, 2));
        m = fmaxf(m, __shfl_xor(m, 4)); m = fmaxf(m, __shfl_xor(m, 8));
        float s = 0.f;
#pragma unroll
        for (int ct = 0; ct < 7; ++ct) {
            float e = __builtin_expf(cl[ct][reg] - m); cl[ct][reg] = e; s += e;
        }
#pragma unroll
        for (int ct = 0; ct < 4; ++ct) {
            float e = __builtin_expf(cp[ct][reg] - m); cp[ct][reg] = e; s += e;
        }
        s += __shfl_xor(s, 1); s += __shfl_xor(s, 2);
        s += __shfl_xor(s, 4); s += __shfl_xor(s, 8);
        inv[reg] = 1.0f / s;
    }
    // write P (bf16)
#pragma unroll
    for (int ct = 0; ct < 7; ++ct)
#pragma unroll
        for (int reg = 0; reg < 4; ++reg) {
            int n = w*16 + quad*4 + reg;
            P[n*200 + ct*16 + col16] = f2bf(cl[ct][reg] * inv[reg]);
        }
#pragma unroll
    for (int ct = 0; ct < 4; ++ct)
#pragma unroll
        for (int reg = 0; reg < 4; ++reg) {
            int n = w*16 + quad*4 + reg;
            P[n*200 + 128 + ct*16 + col16] = f2bf(cp[ct][reg] * inv[reg]);
        }
    __syncthreads();

    // ---- learnable-token add (post-softmax): one MFMA + scatter ----
    {
        const f32x4 z = {0.f, 0.f, 0.f, 0.f};
        short8 blt = *(const short8*)(LTT + col16*40 + quad*8);
        f32x4 cd = __builtin_amdgcn_mfma_f32_16x16x32_bf16(aq, blt, z, 0, 0, 0);
        if (col16 < 9) {
            int dy = col16 / 3, dx = col16 - dy*3;
#pragma unroll
            for (int reg = 0; reg < 4; ++reg) {
                int n = w*16 + quad*4 + reg;
                float ltv = cd[reg] * invscL[n] + dqvL[col16];
                int hk = ((n >> 3) + dy)*10 + (n & 7) + dx;
                P[n*200 + hk] = f2bf(bf2f(P[n*200 + hk]) + ltv);
            }
        }
    }
    __syncthreads();

    // ---- PV: K = 192 (128 halo-pad + 64 pooled) ----
    f32x4 o0 = {0.f,0.f,0.f,0.f}, o1 = {0.f,0.f,0.f,0.f};
#pragma unroll
    for (int ks = 0; ks < 6; ++ks) {
        short8 a = *(const short8*)(P + (w*16 + col16)*200 + ks*32 + quad*8);
        short8 b0, b1;
        if (ks < 4) {
            b0 = *(const short8*)(VT + col16*136      + ks*32 + quad*8);
            b1 = *(const short8*)(VT + (16+col16)*136 + ks*32 + quad*8);
        } else {
            b0 = *(const short8*)(VPT + col16*72      + (ks-4)*32 + quad*8);
            b1 = *(const short8*)(VPT + (16+col16)*72 + (ks-4)*32 + quad*8);
        }
        o0 = __builtin_amdgcn_mfma_f32_16x16x32_bf16(a, b0, o0, 0, 0, 0);
        o1 = __builtin_amdgcn_mfma_f32_16x16x32_bf16(a, b1, o1, 0, 0, 0);
    }
    // ---- epilogue: gate + bf16 store ----
#pragma unroll
    for (int reg = 0; reg < 4; ++reg) {
        int n = w*16 + quad*4 + reg;
        int y = ty0 + (n >> 3), x = tx0 + (n & 7);
        size_t rowo = (size_t)(b*4096 + ((y<<6)|x))*256 + h*32;
        float g = gateL[n];
        ao[rowo + col16]      = f2bf(o0[reg] * g);
        ao[rowo + 16 + col16] = f2bf(o1[reg] * g);
    }
}

// ---------------------------------------------------------------------------
extern "C" void kernel_launch(void* const* d_in, const int* in_sizes, int n_in,
                              void* d_out, int out_size, void* d_ws, size_t ws_size,
                              hipStream_t stream)
{
    const float* x    = (const float*)d_in[0];
    const float* tbl  = (const float*)d_in[1];
    const float* q_w  = (const float*)d_in[2];
    const float* q_b  = (const float*)d_in[3];
    const float* kv_w = (const float*)d_in[4];
    const float* kv_b = (const float*)d_in[5];
    const float* temp = (const float*)d_in[6];
    const float* qe   = (const float*)d_in[7];
    const float* rpb  = (const float*)d_in[8];
    const float* lt   = (const float*)d_in[9];
    const float* lb   = (const float*)d_in[10];
    const float* c1w  = (const float*)d_in[11];
    const float* c1b  = (const float*)d_in[12];
    const float* c2w  = (const float*)d_in[13];
    const float* c2b  = (const float*)d_in[14];
    const float* sr_w = (const float*)d_in[15];
    const float* sr_b = (const float*)d_in[16];
    const float* ng   = (const float*)d_in[17];
    const float* nbias= (const float*)d_in[18];
    const float* wg   = (const float*)d_in[19];
    const float* wg0  = (const float*)d_in[20];
    const float* wg1  = (const float*)d_in[21];
    const float* pw   = (const float*)d_in[22];
    const float* pb   = (const float*)d_in[23];
    const int*   rpi  = (const int*)d_in[24];
    (void)in_sizes; (void)n_in; (void)out_size; (void)ws_size;

    float* buf   = (float*)d_ws;                       // 16384x1024
    float* xp    = buf + (size_t)16384*1024;
    float* kpool = xp + 65536;
    float* vpool = kpool + 65536;
    float* cpbb  = vpool + 65536;
    float* gateb = cpbb + 32768;
    unsigned short* xbf  = (unsigned short*)(gateb + 131072);
    unsigned short* ao   = xbf;                        // reuses x_bf (dead by then)
    unsigned short* wcat = xbf + (size_t)16384*256;
    unsigned short* pwbf = wcat + 262144;
    float* out   = (float*)d_out;

    // 0) dtype conversions
    convert_x<<<4096,256,0,stream>>>(x, xbf);
    convert_w<<<320,256,0,stream>>>(q_w, kv_w, sr_w, pw, wcat, pwbf);
    // 1) fused MFMA GEMM: q (L2-normed) | k (L2-normed) | v | gelu(sr)
    gemm_mfma<<<dim3(8,128),256,0,stream>>>(xbf, wcat, q_b, kv_b, sr_b,
                                            256, 768, 512, 768, buf, 1024);
    // 2) MoE gates
    gate_kernel<<<16384,64,0,stream>>>(x, wg, wg0, wg1, gateb);
    // 3) 8x8 avg-pool + LayerNorm of gelu(sr)
    pool_ln_kernel<<<256,256,0,stream>>>(buf, ng, nbias, xp);
    // 4) pooled kv + k-norm (fp32, exact)
    kvpool_kernel<<<256,256,0,stream>>>(xp, kv_w, kv_b, kpool, vpool);
    // 5) CPB bias table
    cpb_kernel<<<4096,256,0,stream>>>(tbl, c1w, c1b, c2w, c2b, cpbb);
    // 6) MFMA attention -> bf16 compact
    attn_mfma<<<dim3(64,8,4),256,0,stream>>>(buf, ao, kpool, vpool, cpbb, rpi,
                                             temp, qe, rpb, lt, lb, gateb);
    // 7) output projection (MFMA)
    gemm_mfma<<<dim3(2,128),256,0,stream>>>(ao, pwbf, pb, pb, pb,
                                            1<<30, 1<<30, 0, 1<<30, out, 256);
}

// Round 6
// 312.250 us; speedup vs baseline: 1.9149x; 1.0199x over previous
//
#include <hip/hip_runtime.h>
#include <math.h>

#define EPSF 1.1920929e-07f

typedef __attribute__((ext_vector_type(8))) short short8;
typedef __attribute__((ext_vector_type(4))) float f32x4;

// float -> bf16 (RNE)
static __device__ __forceinline__ unsigned short f2bf(float f) {
    unsigned int u = __float_as_uint(f);
    return (unsigned short)((u + 0x7FFFu + ((u >> 16) & 1u)) >> 16);
}
static __device__ __forceinline__ float bf2f(unsigned short u) {
    return __uint_as_float((unsigned int)u << 16);
}

// ---------------------------------------------------------------------------
// x (16384x256 f32) -> bf16
// ---------------------------------------------------------------------------
__global__ __launch_bounds__(256) void convert_x(
    const float* __restrict__ x, unsigned short* __restrict__ xbf)
{
    const int e = (blockIdx.x * 256 + threadIdx.x) * 4;
    float4 v = *(const float4*)(x + e);
    ushort4 o;
    o.x = f2bf(v.x); o.y = f2bf(v.y); o.z = f2bf(v.z); o.w = f2bf(v.w);
    *(ushort4*)(xbf + e) = o;
}

// ---------------------------------------------------------------------------
// weights -> bf16
// ---------------------------------------------------------------------------
__global__ __launch_bounds__(256) void convert_w(
    const float* __restrict__ q_w, const float* __restrict__ kv_w,
    const float* __restrict__ sr_w, const float* __restrict__ pw,
    unsigned short* __restrict__ wcat, unsigned short* __restrict__ pwbf)
{
    const int e = (blockIdx.x * 256 + threadIdx.x) * 4;
    if (e < 262144) {
        int n = e >> 8, k = e & 255;
        const float* src = (n < 256) ? (q_w + n*256) :
                           (n < 768) ? (kv_w + (n-256)*256) : (sr_w + (n-768)*256);
        float4 v = *(const float4*)(src + k);
        ushort4 o;
        o.x = f2bf(v.x); o.y = f2bf(v.y); o.z = f2bf(v.z); o.w = f2bf(v.w);
        *(ushort4*)(wcat + e) = o;
    } else {
        int e2 = e - 262144;
        float4 v = *(const float4*)(pw + e2);
        ushort4 o;
        o.x = f2bf(v.x); o.y = f2bf(v.y); o.z = f2bf(v.z); o.w = f2bf(v.w);
        *(ushort4*)(pwbf + e2) = o;
    }
}

// ---------------------------------------------------------------------------
// MFMA bf16 GEMM, K=256. mode 0: fused q|k|v|sr producer — q/k L2-normed,
// q fully scaled ((qn+qe)*softplus(temp)*sls), q/k/v stored bf16 packed at
// qkv[row*2048 + col] (col 0..767); sr gelu'd -> f32 C. mode 1: plain
// bias-add f32 GEMM (projection).
// ---------------------------------------------------------------------------
__global__ __launch_bounds__(256) void gemm_mfma(
    const unsigned short* __restrict__ A,
    const unsigned short* __restrict__ W,
    const float* __restrict__ B0, const float* __restrict__ B1,
    const float* __restrict__ B2,
    int r1, int r2, int mode,
    float* __restrict__ C, int ldc,
    unsigned short* __restrict__ qkv,
    const float* __restrict__ temp, const float* __restrict__ qe)
{
    __shared__ unsigned short At[128*32];
    __shared__ unsigned short Bt[128*32];
    const int m0 = blockIdx.y << 7;
    const int n0 = blockIdx.x << 7;
    const int t  = threadIdx.x;
    const int w  = t >> 6;
    const int l  = t & 63;
    const int wm = (w >> 1) << 6;
    const int wn = (w & 1) << 6;
    const int col16 = l & 15;
    const int quad  = l >> 4;
    const int srow = t >> 2;
    const int skp  = (t & 3) << 3;

    const float* Bp; int noff;
    if (n0 < r1)      { Bp = B0; noff = 0;  }
    else if (n0 < r2) { Bp = B1; noff = r1; }
    else              { Bp = B2; noff = r2; }

    f32x4 acc[4][4];
#pragma unroll
    for (int r = 0; r < 4; ++r)
#pragma unroll
        for (int c = 0; c < 4; ++c)
            acc[r][c] = (f32x4){0.f, 0.f, 0.f, 0.f};

    for (int k0 = 0; k0 < 256; k0 += 32) {
        uint4 a0 = *(const uint4*)(A + (size_t)(m0 + srow)      * 256 + k0 + skp);
        uint4 a1 = *(const uint4*)(A + (size_t)(m0 + 64 + srow) * 256 + k0 + skp);
        uint4 b0 = *(const uint4*)(W + (size_t)(n0 + srow)      * 256 + k0 + skp);
        uint4 b1 = *(const uint4*)(W + (size_t)(n0 + 64 + srow) * 256 + k0 + skp);
        __syncthreads();
        *(uint4*)(At + srow*32 + skp)      = a0;
        *(uint4*)(At + (64+srow)*32 + skp) = a1;
        *(uint4*)(Bt + srow*32 + skp)      = b0;
        *(uint4*)(Bt + (64+srow)*32 + skp) = b1;
        __syncthreads();
        short8 af[4], bf[4];
#pragma unroll
        for (int r = 0; r < 4; ++r)
            af[r] = *(const short8*)(At + (wm + 16*r + col16)*32 + quad*8);
#pragma unroll
        for (int c = 0; c < 4; ++c)
            bf[c] = *(const short8*)(Bt + (wn + 16*c + col16)*32 + quad*8);
#pragma unroll
        for (int r = 0; r < 4; ++r)
#pragma unroll
            for (int c = 0; c < 4; ++c)
                acc[r][c] = __builtin_amdgcn_mfma_f32_16x16x32_bf16(
                    af[r], bf[c], acc[r][c], 0, 0, 0);
    }

    float bias_c[4];
#pragma unroll
    for (int c = 0; c < 4; ++c)
        bias_c[c] = Bp[n0 + wn + 16*c + col16 - noff];

    if (mode == 0) {
        const int region = n0 >> 8;    // 0=q, 1=k, 2=v, 3=sr
#pragma unroll
        for (int r = 0; r < 4; ++r) {
#pragma unroll
            for (int reg = 0; reg < 4; ++reg) {
                const int row = m0 + wm + 16*r + quad*4 + reg;
                float v[4];
#pragma unroll
                for (int c = 0; c < 4; ++c) v[c] = acc[r][c][reg] + bias_c[c];
                if (region <= 1) {             // q,k: per-head L2 norm
#pragma unroll
                    for (int hp = 0; hp < 2; ++hp) {
                        float s = v[2*hp]*v[2*hp] + v[2*hp+1]*v[2*hp+1];
                        s += __shfl_xor(s, 1); s += __shfl_xor(s, 2);
                        s += __shfl_xor(s, 4); s += __shfl_xor(s, 8);
                        float inv = 1.0f / fmaxf(sqrtf(s), EPSF);
                        v[2*hp]   *= inv;
                        v[2*hp+1] *= inv;
                    }
                }
                if (region == 0) {             // q: (qn+qe)*softplus(temp)*sls
                    int n = row & 4095;
                    int y = n >> 6, x = n & 63;
                    int cy = (y == 0 || y == 63) ? 2 : 3;
                    int cx = (x == 0 || x == 63) ? 2 : 3;
                    float sls = logf((float)(cy*cx) + 64.0f);
#pragma unroll
                    for (int c = 0; c < 4; ++c) {
                        int col = n0 + wn + 16*c + col16;
                        float spt = log1pf(expf(temp[(col >> 5) & 7]));
                        v[c] = (v[c] + qe[col]) * (spt * sls);
                    }
                }
                if (region == 3) {             // sr: gelu -> f32
#pragma unroll
                    for (int c = 0; c < 4; ++c) {
                        float g = 0.5f * v[c] * (1.0f + erff(v[c] * 0.70710678118654752f));
                        C[(size_t)row * ldc + n0 + wn + 16*c + col16] = g;
                    }
                } else {                       // q/k/v: packed bf16
#pragma unroll
                    for (int c = 0; c < 4; ++c)
                        qkv[(size_t)row * 2048 + n0 + wn + 16*c + col16] = f2bf(v[c]);
                }
            }
        }
    } else {
#pragma unroll
        for (int r = 0; r < 4; ++r)
#pragma unroll
            for (int reg = 0; reg < 4; ++reg) {
                const int row = m0 + wm + 16*r + quad*4 + reg;
#pragma unroll
                for (int c = 0; c < 4; ++c)
                    C[(size_t)row * ldc + n0 + wn + 16*c + col16] =
                        acc[r][c][reg] + bias_c[c];
            }
    }
}

// ---------------------------------------------------------------------------
__global__ __launch_bounds__(64) void gate_kernel(
    const float* __restrict__ x,
    const float* __restrict__ wg,
    const float* __restrict__ wg0,
    const float* __restrict__ wg1,
    float* __restrict__ gate)
{
    __shared__ float xs[256];
    __shared__ float dots[10];
    const int r = blockIdx.x;
    const int t = threadIdx.x;
    const float* xr = x + ((size_t)r << 8);
    xs[t] = xr[t]; xs[t+64] = xr[t+64]; xs[t+128] = xr[t+128]; xs[t+192] = xr[t+192];
    __syncthreads();
    for (int f = 0; f < 10; ++f) {
        const float* wf = (f < 4) ? (wg + f*256) : (f < 6) ? (wg0 + (f-4)*256) : (wg1 + (f-6)*256);
        float s = xs[t]*wf[t] + xs[t+64]*wf[t+64] + xs[t+128]*wf[t+128] + xs[t+192]*wf[t+192];
        for (int off = 32; off; off >>= 1) s += __shfl_xor(s, off, 64);
        if (t == 0) dots[f] = s;
    }
    __syncthreads();
    if (t == 0) {
        float e[4];
        float m = fmaxf(fmaxf(dots[0],dots[1]), fmaxf(dots[2],dots[3]));
        float ssum = 0.f;
        for (int i = 0; i < 4; ++i) { e[i] = expf(dots[i]-m); ssum += e[i]; }
        for (int i = 0; i < 4; ++i) e[i] /= ssum;
        int i1 = 0;
        for (int i = 1; i < 4; ++i) if (e[i] > e[i1]) i1 = i;
        int i2 = -1;
        for (int i = 0; i < 4; ++i) if (i != i1 && (i2 < 0 || e[i] > e[i2])) i2 = i;
        float rs = fmaxf(e[i1] + e[i2], EPSF);
        float rg[4] = {0.f,0.f,0.f,0.f};
        rg[i1] = e[i1] / rs * 2.f;
        rg[i2] = e[i2] / rs * 2.f;
        float sh[4];
        float m1 = fmaxf(fmaxf(dots[6],dots[7]), fmaxf(dots[8],dots[9]));
        float s1 = 0.f;
        for (int i = 0; i < 4; ++i) { sh[i] = expf(dots[6+i]-m1); s1 += sh[i]; }
        float mm = fmaxf(dots[4], dots[5]);
        float e0 = expf(dots[4]-mm), e1 = expf(dots[5]-mm);
        float w00 = e0/(e0+e1)*2.f, w01 = e1/(e0+e1)*2.f;
        float* gr = gate + ((size_t)r << 3);
        for (int i = 0; i < 4; ++i) gr[i]   = w00 * (sh[i]/s1*4.f);
        for (int i = 0; i < 4; ++i) gr[4+i] = w01 * rg[i];
    }
}

// ---------------------------------------------------------------------------
__global__ __launch_bounds__(256) void pool_ln_kernel(
    const float* __restrict__ buf,
    const float* __restrict__ g, const float* __restrict__ bb,
    float* __restrict__ xp)
{
    __shared__ float r1[256], r2[256];
    const int blk = blockIdx.x;
    const int b = blk >> 6, p = blk & 63;
    const int py = p >> 3, px = p & 7;
    const int t = threadIdx.x;
    float acc = 0.f;
    for (int dy = 0; dy < 8; ++dy)
#pragma unroll
        for (int dx = 0; dx < 8; ++dx) {
            int s = ((py*8+dy) << 6) + px*8 + dx;
            acc += buf[(((size_t)(b*4096+s)) << 10) + 768 + t];
        }
    acc *= (1.0f/64.0f);
    r1[t] = acc; r2[t] = acc*acc;
    __syncthreads();
    for (int off = 128; off; off >>= 1) {
        if (t < off) { r1[t] += r1[t+off]; r2[t] += r2[t+off]; }
        __syncthreads();
    }
    float mu  = r1[0] * (1.0f/256.0f);
    float var = r2[0] * (1.0f/256.0f) - mu*mu;
    float rstd = rsqrtf(var + 1e-5f);
    xp[((size_t)blk << 8) + t] = (acc - mu) * rstd * g[t] + bb[t];
}

// ---------------------------------------------------------------------------
// pooled kv (fp32 math) -> bf16 outputs
// ---------------------------------------------------------------------------
__global__ __launch_bounds__(256) void kvpool_kernel(
    const float* __restrict__ xp,
    const float* __restrict__ kv_w, const float* __restrict__ kv_b,
    unsigned short* __restrict__ kpb, unsigned short* __restrict__ vpb)
{
    __shared__ float xs[256];
    __shared__ float row[512];
    __shared__ float inv[8];
    const int blk = blockIdx.x;
    const int t = threadIdx.x;
    xs[t] = xp[((size_t)blk << 8) + t];
    __syncthreads();
    for (int o = t; o < 512; o += 256) {
        const float* wr = kv_w + ((size_t)o << 8);
        float s = kv_b[o];
        for (int k = 0; k < 256; ++k) s += xs[k]*wr[k];
        row[o] = s;
    }
    __syncthreads();
    if (t < 8) {
        float s = 0.f;
        for (int dd = 0; dd < 32; ++dd) { float v = row[t*32+dd]; s += v*v; }
        inv[t] = 1.0f / fmaxf(sqrtf(s), EPSF);
    }
    __syncthreads();
    const int b = blk >> 6, p = blk & 63, h = t >> 5, dd = t & 31;
    size_t o = ((((size_t)(b*8+h))*64 + p) << 5) + dd;
    kpb[o] = f2bf(row[t] * inv[h]);
    vpb[o] = f2bf(row[256 + t]);
}

// ---------------------------------------------------------------------------
__global__ __launch_bounds__(256) void cpb_kernel(
    const float* __restrict__ tbl,
    const float* __restrict__ w1, const float* __restrict__ b1,
    const float* __restrict__ w2, const float* __restrict__ b2,
    float* __restrict__ cpb)
{
    __shared__ float hid[512];
    const int r = blockIdx.x, t = threadIdx.x;
    const float c0 = tbl[(size_t)r*2], c1 = tbl[(size_t)r*2+1];
    for (int i = t; i < 512; i += 256)
        hid[i] = fmaxf(c0*w1[i*2] + c1*w1[i*2+1] + b1[i], 0.f);
    __syncthreads();
    const int h = t >> 5, dd = t & 31;
    float s = 0.f;
    for (int i = dd; i < 512; i += 32) s += hid[i] * w2[h*512+i];
    for (int off = 16; off; off >>= 1) s += __shfl_xor(s, off, 32);
    if (dd == 0) cpb[((size_t)r << 3) + h] = s + b2[h];
}

// ---------------------------------------------------------------------------
// MFMA attention v3: all-bf16 staging (pure copies — qkv packed bf16 is
// produced by gemm1), 47 KB LDS (3 blocks/CU), cpb pooled bias gathered
// into registers before the QK MFMAs, VT transpose with ~2-way bank pattern.
// ---------------------------------------------------------------------------
__global__ __launch_bounds__(256, 3) void attn_mfma(
    const unsigned short* __restrict__ qkv,   // (16384,2048) packed: q|k|v bf16
    unsigned short* __restrict__ ao,          // (16384,256) bf16
    const unsigned short* __restrict__ kpb,   // (B,H,64,32) bf16
    const unsigned short* __restrict__ vpb,
    const float* __restrict__ cpb,
    const int*   __restrict__ rpi,
    const float* __restrict__ temp,
    const float* __restrict__ qe,
    const float* __restrict__ rpb,
    const float* __restrict__ lt,    // (8,32,9)
    const float* __restrict__ lb,    // (8,1,9)
    const float* __restrict__ gate)
{
    __shared__ __attribute__((aligned(16))) unsigned short U0[112*40]; // KH, then VT[32*136]
    __shared__ __attribute__((aligned(16))) unsigned short U1[64*40];  // KP, then VPT[32*72]
    __shared__ __attribute__((aligned(16))) unsigned short QS[64*40];
    __shared__ __attribute__((aligned(16))) unsigned short P[64*200];
    __shared__ __attribute__((aligned(16))) unsigned short LTT[16*40];
    __shared__ float invscL[64], gateL[64], rpbL[9], dqvL[16];

    const int tile = blockIdx.x;
    const int h    = blockIdx.y;
    const int b    = blockIdx.z;
    const int ty0  = (tile >> 3) << 3;
    const int tx0  = (tile & 7) << 3;
    const int t    = threadIdx.x;

    // ---- S0: tables ----
    const float spt = log1pf(expf(temp[h]));
    if (t < 64) {
        int y = ty0 + (t >> 3), x = tx0 + (t & 7);
        int cy = (y == 0 || y == 63) ? 2 : 3;
        int cx = (x == 0 || x == 63) ? 2 : 3;
        invscL[t] = 1.0f / (spt * logf((float)(cy*cx) + 64.0f));
        gateL[t] = gate[(((size_t)(b*4096 + ((y<<6)|x))) << 3) + h];
    } else if (t < 80) {
        int j = t - 64;
        float s = 0.f;
        if (j < 9) {
            s = lb[h*9 + j];
            for (int dd = 0; dd < 32; ++dd)
                s -= qe[h*32+dd] * lt[(h*32+dd)*9 + j];
        }
        dqvL[j] = s;
    } else if (t < 89) {
        rpbL[t-80] = rpb[h*9 + (t-80)];
    }
    for (int i = t; i < 16*32; i += 256) {
        int j = i >> 5, dd = i & 31;
        LTT[j*40 + dd] = (j < 9) ? f2bf(lt[(h*32+dd)*9 + j]) : (unsigned short)0;
    }

    // ---- S1: stage KH / KP / QS (pure bf16 copies), zero P pad cols ----
    unsigned short* KH = U0;
    unsigned short* KP = U1;
    for (int i = t; i < 112*8; i += 256) {           // halo K, uint2 chunks
        int r = i >> 3, sg = i & 7;
        uint2 val = {0u, 0u};
        if (r < 100) {
            int y = ty0 + r/10 - 1, x = tx0 + r%10 - 1;
            if (y >= 0 && y < 64 && x >= 0 && x < 64)
                val = *(const uint2*)(qkv + (size_t)(b*4096 + ((y<<6)|x))*2048 + 256 + h*32 + sg*4);
        }
        *(uint2*)(KH + r*40 + sg*4) = val;
    }
    {
        const unsigned short* src = kpb + (size_t)(b*8+h)*2048;
        for (int i = t; i < 512; i += 256)           // pooled K
            *(uint2*)(KP + (i >> 3)*40 + (i & 7)*4) = *(const uint2*)(src + i*4);
    }
    for (int i = t; i < 512; i += 256) {             // scaled q (pre-scaled)
        int n = i >> 3, sg = i & 7;
        int y = ty0 + (n >> 3), x = tx0 + (n & 7);
        *(uint2*)(QS + n*40 + sg*4) =
            *(const uint2*)(qkv + (size_t)(b*4096 + ((y<<6)|x))*2048 + h*32 + sg*4);
    }
    for (int i = t; i < 1024; i += 256) {            // P zero cols 112..127
        int n = i >> 4, c = 112 + (i & 15);
        P[n*200 + c] = 0;
    }
    __syncthreads();

    // ---- QK phase ----
    const int lane  = t & 63;
    const int w     = t >> 6;
    const int col16 = lane & 15;
    const int quad  = lane >> 4;

    // pooled bias gather first (global loads fly under the MFMAs)
    float pbias[4][4];
#pragma unroll
    for (int ct = 0; ct < 4; ++ct) {
        int p = ct*16 + col16;
#pragma unroll
        for (int reg = 0; reg < 4; ++reg) {
            int n = w*16 + quad*4 + reg;
            int y = ty0 + (n >> 3), x = tx0 + (n & 7);
            int ngl = (y << 6) | x;
            pbias[ct][reg] = cpb[((size_t)rpi[(size_t)ngl*64 + p] << 3) + h];
        }
    }

    short8 aq = *(const short8*)(QS + (w*16 + col16)*40 + quad*8);
    f32x4 cl[7], cp[4];
    {
        const f32x4 z = {0.f, 0.f, 0.f, 0.f};
#pragma unroll
        for (int ct = 0; ct < 7; ++ct) {
            short8 bk = *(const short8*)(KH + (ct*16 + col16)*40 + quad*8);
            cl[ct] = __builtin_amdgcn_mfma_f32_16x16x32_bf16(aq, bk, z, 0, 0, 0);
        }
#pragma unroll
        for (int ct = 0; ct < 4; ++ct) {
            short8 bp = *(const short8*)(KP + (ct*16 + col16)*40 + quad*8);
            cp[ct] = __builtin_amdgcn_mfma_f32_16x16x32_bf16(aq, bp, z, 0, 0, 0);
        }
    }
    // bias + window mask
#pragma unroll
    for (int ct = 0; ct < 7; ++ct) {
        int hk = ct*16 + col16;
        int ky = hk / 10, kx = hk - ky*10;
#pragma unroll
        for (int reg = 0; reg < 4; ++reg) {
            int n = w*16 + quad*4 + reg;
            int dy = ky - (n >> 3), dx = kx - (n & 7);
            bool valid = (dy >= 0 && dy <= 2 && dx >= 0 && dx <= 2);
            cl[ct][reg] = valid ? (cl[ct][reg] + rpbL[dy*3 + dx]) : -1e30f;
        }
    }
#pragma unroll
    for (int ct = 0; ct < 4; ++ct)
#pragma unroll
        for (int reg = 0; reg < 4; ++reg)
            cp[ct][reg] += pbias[ct][reg];
    // softmax (reduce over the 16 col-lanes)
    float inv[4];
#pragma unroll
    for (int reg = 0; reg < 4; ++reg) {
        float m = -1e30f;
#pragma unroll
        for (int ct = 0; ct < 7; ++ct) m = fmaxf(m, cl[ct][reg]);
#pragma unroll
        for (int ct = 0; ct < 4; ++ct) m = fmaxf(m, cp[ct][reg]);
        m = fmaxf(m, __shfl_xor(m, 1)); m = fmaxf(m, __shfl_xor(m, 2));
        m = fmaxf(m, __shfl_xor(m, 4)); m = fmaxf(m, __shfl_xor(m, 8));
        float s = 0.f;
#pragma unroll
        for (int ct = 0; ct < 7; ++ct) {
            float e = __builtin_expf(cl[ct][reg] - m); cl[ct][reg] = e; s += e;
        }
#pragma unroll
        for (int ct = 0; ct < 4; ++ct) {
            float e = __builtin_expf(cp[ct][reg] - m); cp[ct][reg] = e; s += e;
        }
        s += __shfl_xor(s, 1); s += __shfl_xor(s, 2);
        s += __shfl_xor(s, 4); s += __shfl_xor(s, 8);
        inv[reg] = 1.0f / s;
    }
    // write P (rows are wave-private: w*16..w*16+15)
#pragma unroll
    for (int ct = 0; ct < 7; ++ct)
#pragma unroll
        for (int reg = 0; reg < 4; ++reg) {
            int n = w*16 + quad*4 + reg;
            P[n*200 + ct*16 + col16] = f2bf(cl[ct][reg] * inv[reg]);
        }
#pragma unroll
    for (int ct = 0; ct < 4; ++ct)
#pragma unroll
        for (int reg = 0; reg < 4; ++reg) {
            int n = w*16 + quad*4 + reg;
            P[n*200 + 128 + ct*16 + col16] = f2bf(cp[ct][reg] * inv[reg]);
        }
    // learnable-token add (same-wave rows; in-wave LDS ordering suffices)
    {
        const f32x4 z = {0.f, 0.f, 0.f, 0.f};
        short8 blt = *(const short8*)(LTT + col16*40 + quad*8);
        f32x4 cd = __builtin_amdgcn_mfma_f32_16x16x32_bf16(aq, blt, z, 0, 0, 0);
        if (col16 < 9) {
            int dy = col16 / 3, dx = col16 - dy*3;
#pragma unroll
            for (int reg = 0; reg < 4; ++reg) {
                int n = w*16 + quad*4 + reg;
                float ltv = cd[reg] * invscL[n] + dqvL[col16];
                int hk = ((n >> 3) + dy)*10 + (n & 7) + dx;
                P[n*200 + hk] = f2bf(bf2f(P[n*200 + hk]) + ltv);
            }
        }
    }
    __syncthreads();   // all KH/KP reads done -> overwrite with V

    // ---- S2: stage V transposed (lane-major over rows: ~2-way banks) ----
    unsigned short* VT  = U0;   // [32][136], cols 112..127 zero
    unsigned short* VPT = U1;   // [32][72]
    for (int i = t; i < 1792; i += 256) {            // halo V
        int rlo = i & 15, rest = i >> 4;             // rest 0..111
        int dp = rest & 15, r = (rest >> 4)*16 + rlo;
        unsigned val = 0;
        if (r < 100) {
            int y = ty0 + r/10 - 1, x = tx0 + r%10 - 1;
            if (y >= 0 && y < 64 && x >= 0 && x < 64)
                val = *(const unsigned*)(qkv + (size_t)(b*4096 + ((y<<6)|x))*2048 + 512 + h*32 + dp*2);
        }
        VT[(2*dp)*136 + r]   = (unsigned short)(val & 0xffffu);
        VT[(2*dp+1)*136 + r] = (unsigned short)(val >> 16);
    }
    for (int i = t; i < 512; i += 256) {             // VT zero cols 112..127
        int r = 112 + (i & 15), d = i >> 4;
        VT[d*136 + r] = 0;
    }
    for (int i = t; i < 1024; i += 256) {            // pooled V
        int plo = i & 15, rest = i >> 4;
        int dp = rest & 15, p = (rest >> 4)*16 + plo;
        unsigned val = *(const unsigned*)(vpb + (size_t)(b*8+h)*2048 + p*32 + dp*2);
        VPT[(2*dp)*72 + p]   = (unsigned short)(val & 0xffffu);
        VPT[(2*dp+1)*72 + p] = (unsigned short)(val >> 16);
    }
    __syncthreads();

    // ---- PV: K = 192 (128 halo-pad + 64 pooled) ----
    f32x4 o0 = {0.f,0.f,0.f,0.f}, o1 = {0.f,0.f,0.f,0.f};
#pragma unroll
    for (int ks = 0; ks < 6; ++ks) {
        short8 a = *(const short8*)(P + (w*16 + col16)*200 + ks*32 + quad*8);
        short8 b0, b1;
        if (ks < 4) {
            b0 = *(const short8*)(VT + col16*136      + ks*32 + quad*8);
            b1 = *(const short8*)(VT + (16+col16)*136 + ks*32 + quad*8);
        } else {
            b0 = *(const short8*)(VPT + col16*72      + (ks-4)*32 + quad*8);
            b1 = *(const short8*)(VPT + (16+col16)*72 + (ks-4)*32 + quad*8);
        }
        o0 = __builtin_amdgcn_mfma_f32_16x16x32_bf16(a, b0, o0, 0, 0, 0);
        o1 = __builtin_amdgcn_mfma_f32_16x16x32_bf16(a, b1, o1, 0, 0, 0);
    }
    // ---- epilogue: gate + bf16 store ----
#pragma unroll
    for (int reg = 0; reg < 4; ++reg) {
        int n = w*16 + quad*4 + reg;
        int y = ty0 + (n >> 3), x = tx0 + (n & 7);
        size_t rowo = (size_t)(b*4096 + ((y<<6)|x))*256 + h*32;
        float g = gateL[n];
        ao[rowo + col16]      = f2bf(o0[reg] * g);
        ao[rowo + 16 + col16] = f2bf(o1[reg] * g);
    }
}

// ---------------------------------------------------------------------------
extern "C" void kernel_launch(void* const* d_in, const int* in_sizes, int n_in,
                              void* d_out, int out_size, void* d_ws, size_t ws_size,
                              hipStream_t stream)
{
    const float* x    = (const float*)d_in[0];
    const float* tbl  = (const float*)d_in[1];
    const float* q_w  = (const float*)d_in[2];
    const float* q_b  = (const float*)d_in[3];
    const float* kv_w = (const float*)d_in[4];
    const float* kv_b = (const float*)d_in[5];
    const float* temp = (const float*)d_in[6];
    const float* qe   = (const float*)d_in[7];
    const float* rpb  = (const float*)d_in[8];
    const float* lt   = (const float*)d_in[9];
    const float* lb   = (const float*)d_in[10];
    const float* c1w  = (const float*)d_in[11];
    const float* c1b  = (const float*)d_in[12];
    const float* c2w  = (const float*)d_in[13];
    const float* c2b  = (const float*)d_in[14];
    const float* sr_w = (const float*)d_in[15];
    const float* sr_b = (const float*)d_in[16];
    const float* ng   = (const float*)d_in[17];
    const float* nbias= (const float*)d_in[18];
    const float* wg   = (const float*)d_in[19];
    const float* wg0  = (const float*)d_in[20];
    const float* wg1  = (const float*)d_in[21];
    const float* pw   = (const float*)d_in[22];
    const float* pb   = (const float*)d_in[23];
    const int*   rpi  = (const int*)d_in[24];
    (void)in_sizes; (void)n_in; (void)out_size; (void)ws_size;

    // buf row (4KB): bytes [0,1536) = packed bf16 q|k|v (ushort at 2*col),
    // bytes [3072,4096) = f32 sr (cols 768..1023). No extra workspace needed.
    float* buf   = (float*)d_ws;                       // 16384x1024 f32 layout
    unsigned short* qkvb = (unsigned short*)d_ws;      // (16384, 2048) ushort view
    float* xp    = buf + (size_t)16384*1024;
    float* kpoolf= xp + 65536;                         // reused as bf16 pools
    unsigned short* kpb = (unsigned short*)kpoolf;
    unsigned short* vpb = kpb + 131072;
    float* cpbb  = kpoolf + 131072;
    float* gateb = cpbb + 32768;
    unsigned short* xbf  = (unsigned short*)(gateb + 131072);
    unsigned short* ao   = xbf;                        // reuses x_bf (dead after gemm1)
    unsigned short* wcat = xbf + (size_t)16384*256;
    unsigned short* pwbf = wcat + 262144;
    float* out   = (float*)d_out;

    // 0) dtype conversions
    convert_x<<<4096,256,0,stream>>>(x, xbf);
    convert_w<<<320,256,0,stream>>>(q_w, kv_w, sr_w, pw, wcat, pwbf);
    // 1) fused MFMA GEMM -> packed bf16 q(scaled)|k(normed)|v + f32 gelu(sr)
    gemm_mfma<<<dim3(8,128),256,0,stream>>>(xbf, wcat, q_b, kv_b, sr_b,
                                            256, 768, 0, buf, 1024,
                                            qkvb, temp, qe);
    // 2) MoE gates
    gate_kernel<<<16384,64,0,stream>>>(x, wg, wg0, wg1, gateb);
    // 3) 8x8 avg-pool + LayerNorm of gelu(sr)
    pool_ln_kernel<<<256,256,0,stream>>>(buf, ng, nbias, xp);
    // 4) pooled kv + k-norm (fp32 math, bf16 out)
    kvpool_kernel<<<256,256,0,stream>>>(xp, kv_w, kv_b, kpb, vpb);
    // 5) CPB bias table
    cpb_kernel<<<4096,256,0,stream>>>(tbl, c1w, c1b, c2w, c2b, cpbb);
    // 6) MFMA attention -> bf16 compact
    attn_mfma<<<dim3(64,8,4),256,0,stream>>>(qkvb, ao, kpb, vpb, cpbb, rpi,
                                             temp, qe, rpb, lt, lb, gateb);
    // 7) output projection (MFMA)
    gemm_mfma<<<dim3(2,128),256,0,stream>>>(ao, pwbf, pb, pb, pb,
                                            1<<30, 1<<30, 1, out, 256,
                                            (unsigned short*)nullptr, nullptr, nullptr);
}

// Round 7
// 278.531 us; speedup vs baseline: 2.1467x; 1.1211x over previous
//
#include <hip/hip_runtime.h>
#include <math.h>

#define EPSF 1.1920929e-07f

typedef __attribute__((ext_vector_type(8))) short short8;
typedef __attribute__((ext_vector_type(4))) float f32x4;

// float -> bf16 (RNE)
static __device__ __forceinline__ unsigned short f2bf(float f) {
    unsigned int u = __float_as_uint(f);
    return (unsigned short)((u + 0x7FFFu + ((u >> 16) & 1u)) >> 16);
}
static __device__ __forceinline__ float bf2f(unsigned short u) {
    return __uint_as_float((unsigned int)u << 16);
}

// async global->LDS, 16B per lane; LDS dest = wave-uniform base + lane*16
static __device__ __forceinline__ void gld_lds16(
    const unsigned short* g, unsigned short* l)
{
    __builtin_amdgcn_global_load_lds(
        (const __attribute__((address_space(1))) void*)g,
        (__attribute__((address_space(3))) void*)l,
        16, 0, 0);
}

// ---------------------------------------------------------------------------
// x (16384x256 f32) -> bf16
// ---------------------------------------------------------------------------
__global__ __launch_bounds__(256) void convert_x(
    const float* __restrict__ x, unsigned short* __restrict__ xbf)
{
    const int e = (blockIdx.x * 256 + threadIdx.x) * 4;
    float4 v = *(const float4*)(x + e);
    ushort4 o;
    o.x = f2bf(v.x); o.y = f2bf(v.y); o.z = f2bf(v.z); o.w = f2bf(v.w);
    *(ushort4*)(xbf + e) = o;
}

// ---------------------------------------------------------------------------
// weights -> bf16
// ---------------------------------------------------------------------------
__global__ __launch_bounds__(256) void convert_w(
    const float* __restrict__ q_w, const float* __restrict__ kv_w,
    const float* __restrict__ sr_w, const float* __restrict__ pw,
    unsigned short* __restrict__ wcat, unsigned short* __restrict__ pwbf)
{
    const int e = (blockIdx.x * 256 + threadIdx.x) * 4;
    if (e < 262144) {
        int n = e >> 8, k = e & 255;
        const float* src = (n < 256) ? (q_w + n*256) :
                           (n < 768) ? (kv_w + (n-256)*256) : (sr_w + (n-768)*256);
        float4 v = *(const float4*)(src + k);
        ushort4 o;
        o.x = f2bf(v.x); o.y = f2bf(v.y); o.z = f2bf(v.z); o.w = f2bf(v.w);
        *(ushort4*)(wcat + e) = o;
    } else {
        int e2 = e - 262144;
        float4 v = *(const float4*)(pw + e2);
        ushort4 o;
        o.x = f2bf(v.x); o.y = f2bf(v.y); o.z = f2bf(v.z); o.w = f2bf(v.w);
        *(ushort4*)(pwbf + e2) = o;
    }
}

// ---------------------------------------------------------------------------
// MFMA bf16 GEMM, K=256, software-pipelined: global_load_lds width=16 into
// double-buffered LDS, ONE barrier per k-step, prefetch of step k+1 issued
// right after the barrier (latency hides under 16 MFMAs + 8 ds_read_b128).
// mode 0: fused q|k|v|sr producer (q/k L2-normed, q fully scaled, bf16 out
// packed at qkv[row*2048+col]; sr gelu'd -> f32 C). mode 1: bias-add f32 GEMM.
// ---------------------------------------------------------------------------
__global__ __launch_bounds__(256) void gemm_mfma(
    const unsigned short* __restrict__ A,
    const unsigned short* __restrict__ W,
    const float* __restrict__ B0, const float* __restrict__ B1,
    const float* __restrict__ B2,
    int r1, int r2, int mode,
    float* __restrict__ C, int ldc,
    unsigned short* __restrict__ qkv,
    const float* __restrict__ temp, const float* __restrict__ qe)
{
    __shared__ __attribute__((aligned(16))) unsigned short At[2][4096];
    __shared__ __attribute__((aligned(16))) unsigned short Bt[2][4096];
    const int m0 = blockIdx.y << 7;
    const int n0 = blockIdx.x << 7;
    const int t  = threadIdx.x;
    const int w  = t >> 6;
    const int l  = t & 63;
    const int wm = (w >> 1) << 6;
    const int wn = (w & 1) << 6;
    const int col16 = l & 15;
    const int quad  = l >> 4;

    const float* Bp; int noff;
    if (n0 < r1)      { Bp = B0; noff = 0;  }
    else if (n0 < r2) { Bp = B1; noff = r1; }
    else              { Bp = B2; noff = r2; }

    // per-lane global pointers (thread t stages row t>>2, 16B chunk t&3)
    const unsigned short* gA0 = A + (size_t)(m0 + (t >> 2)) * 256 + ((t & 3) << 3);
    const unsigned short* gA1 = gA0 + 64*256;
    const unsigned short* gB0 = W + (size_t)(n0 + (t >> 2)) * 256 + ((t & 3) << 3);
    const unsigned short* gB1 = gB0 + 64*256;
    // wave-uniform LDS slice base (elements): wave w covers [w*512, w*512+512)
    const int ldsW = (t >> 6) << 9;

    f32x4 acc[4][4];
#pragma unroll
    for (int r = 0; r < 4; ++r)
#pragma unroll
        for (int c = 0; c < 4; ++c)
            acc[r][c] = (f32x4){0.f, 0.f, 0.f, 0.f};

    // prologue: stage k-step 0 into buffer 0
    gld_lds16(gA0, &At[0][ldsW]);
    gld_lds16(gA1, &At[0][2048 + ldsW]);
    gld_lds16(gB0, &Bt[0][ldsW]);
    gld_lds16(gB1, &Bt[0][2048 + ldsW]);

    for (int ks = 0; ks < 8; ++ks) {
        const int cur = ks & 1;
        __syncthreads();               // drains vmcnt: buffer `cur` is ready
        if (ks < 7) {                  // prefetch next step into other buffer
            const int k0 = (ks + 1) << 5;
            gld_lds16(gA0 + k0, &At[cur ^ 1][ldsW]);
            gld_lds16(gA1 + k0, &At[cur ^ 1][2048 + ldsW]);
            gld_lds16(gB0 + k0, &Bt[cur ^ 1][ldsW]);
            gld_lds16(gB1 + k0, &Bt[cur ^ 1][2048 + ldsW]);
        }
        short8 af[4], bf[4];
#pragma unroll
        for (int r = 0; r < 4; ++r)
            af[r] = *(const short8*)(&At[cur][(wm + 16*r + col16)*32 + quad*8]);
#pragma unroll
        for (int c = 0; c < 4; ++c)
            bf[c] = *(const short8*)(&Bt[cur][(wn + 16*c + col16)*32 + quad*8]);
#pragma unroll
        for (int r = 0; r < 4; ++r)
#pragma unroll
            for (int c = 0; c < 4; ++c)
                acc[r][c] = __builtin_amdgcn_mfma_f32_16x16x32_bf16(
                    af[r], bf[c], acc[r][c], 0, 0, 0);
    }

    float bias_c[4];
#pragma unroll
    for (int c = 0; c < 4; ++c)
        bias_c[c] = Bp[n0 + wn + 16*c + col16 - noff];

    if (mode == 0) {
        const int region = n0 >> 8;    // 0=q, 1=k, 2=v, 3=sr
        float qe_c[4], spt_c[4];
        if (region == 0) {
#pragma unroll
            for (int c = 0; c < 4; ++c) {
                int col = n0 + wn + 16*c + col16;
                spt_c[c] = log1pf(expf(temp[(col >> 5) & 7]));
                qe_c[c]  = qe[col];
            }
        }
#pragma unroll
        for (int r = 0; r < 4; ++r) {
#pragma unroll
            for (int reg = 0; reg < 4; ++reg) {
                const int row = m0 + wm + 16*r + quad*4 + reg;
                float v[4];
#pragma unroll
                for (int c = 0; c < 4; ++c) v[c] = acc[r][c][reg] + bias_c[c];
                if (region <= 1) {             // q,k: per-head L2 norm
#pragma unroll
                    for (int hp = 0; hp < 2; ++hp) {
                        float s = v[2*hp]*v[2*hp] + v[2*hp+1]*v[2*hp+1];
                        s += __shfl_xor(s, 1); s += __shfl_xor(s, 2);
                        s += __shfl_xor(s, 4); s += __shfl_xor(s, 8);
                        float inv = 1.0f / fmaxf(sqrtf(s), EPSF);
                        v[2*hp]   *= inv;
                        v[2*hp+1] *= inv;
                    }
                }
                if (region == 0) {             // q: (qn+qe)*softplus(temp)*sls
                    int n = row & 4095;
                    int y = n >> 6, x = n & 63;
                    int cy = (y == 0 || y == 63) ? 2 : 3;
                    int cx = (x == 0 || x == 63) ? 2 : 3;
                    float sls = logf((float)(cy*cx) + 64.0f);
#pragma unroll
                    for (int c = 0; c < 4; ++c)
                        v[c] = (v[c] + qe_c[c]) * (spt_c[c] * sls);
                }
                if (region == 3) {             // sr: gelu -> f32
#pragma unroll
                    for (int c = 0; c < 4; ++c) {
                        float g = 0.5f * v[c] * (1.0f + erff(v[c] * 0.70710678118654752f));
                        C[(size_t)row * ldc + n0 + wn + 16*c + col16] = g;
                    }
                } else {                       // q/k/v: packed bf16
#pragma unroll
                    for (int c = 0; c < 4; ++c)
                        qkv[(size_t)row * 2048 + n0 + wn + 16*c + col16] = f2bf(v[c]);
                }
            }
        }
    } else {
#pragma unroll
        for (int r = 0; r < 4; ++r)
#pragma unroll
            for (int reg = 0; reg < 4; ++reg) {
                const int row = m0 + wm + 16*r + quad*4 + reg;
#pragma unroll
                for (int c = 0; c < 4; ++c)
                    C[(size_t)row * ldc + n0 + wn + 16*c + col16] =
                        acc[r][c][reg] + bias_c[c];
            }
    }
}

// ---------------------------------------------------------------------------
__global__ __launch_bounds__(64) void gate_kernel(
    const float* __restrict__ x,
    const float* __restrict__ wg,
    const float* __restrict__ wg0,
    const float* __restrict__ wg1,
    float* __restrict__ gate)
{
    __shared__ float xs[256];
    __shared__ float dots[10];
    const int r = blockIdx.x;
    const int t = threadIdx.x;
    const float* xr = x + ((size_t)r << 8);
    xs[t] = xr[t]; xs[t+64] = xr[t+64]; xs[t+128] = xr[t+128]; xs[t+192] = xr[t+192];
    __syncthreads();
    for (int f = 0; f < 10; ++f) {
        const float* wf = (f < 4) ? (wg + f*256) : (f < 6) ? (wg0 + (f-4)*256) : (wg1 + (f-6)*256);
        float s = xs[t]*wf[t] + xs[t+64]*wf[t+64] + xs[t+128]*wf[t+128] + xs[t+192]*wf[t+192];
        for (int off = 32; off; off >>= 1) s += __shfl_xor(s, off, 64);
        if (t == 0) dots[f] = s;
    }
    __syncthreads();
    if (t == 0) {
        float e[4];
        float m = fmaxf(fmaxf(dots[0],dots[1]), fmaxf(dots[2],dots[3]));
        float ssum = 0.f;
        for (int i = 0; i < 4; ++i) { e[i] = expf(dots[i]-m); ssum += e[i]; }
        for (int i = 0; i < 4; ++i) e[i] /= ssum;
        int i1 = 0;
        for (int i = 1; i < 4; ++i) if (e[i] > e[i1]) i1 = i;
        int i2 = -1;
        for (int i = 0; i < 4; ++i) if (i != i1 && (i2 < 0 || e[i] > e[i2])) i2 = i;
        float rs = fmaxf(e[i1] + e[i2], EPSF);
        float rg[4] = {0.f,0.f,0.f,0.f};
        rg[i1] = e[i1] / rs * 2.f;
        rg[i2] = e[i2] / rs * 2.f;
        float sh[4];
        float m1 = fmaxf(fmaxf(dots[6],dots[7]), fmaxf(dots[8],dots[9]));
        float s1 = 0.f;
        for (int i = 0; i < 4; ++i) { sh[i] = expf(dots[6+i]-m1); s1 += sh[i]; }
        float mm = fmaxf(dots[4], dots[5]);
        float e0 = expf(dots[4]-mm), e1 = expf(dots[5]-mm);
        float w00 = e0/(e0+e1)*2.f, w01 = e1/(e0+e1)*2.f;
        float* gr = gate + ((size_t)r << 3);
        for (int i = 0; i < 4; ++i) gr[i]   = w00 * (sh[i]/s1*4.f);
        for (int i = 0; i < 4; ++i) gr[4+i] = w01 * rg[i];
    }
}

// ---------------------------------------------------------------------------
__global__ __launch_bounds__(256) void pool_ln_kernel(
    const float* __restrict__ buf,
    const float* __restrict__ g, const float* __restrict__ bb,
    float* __restrict__ xp)
{
    __shared__ float r1[256], r2[256];
    const int blk = blockIdx.x;
    const int b = blk >> 6, p = blk & 63;
    const int py = p >> 3, px = p & 7;
    const int t = threadIdx.x;
    float acc = 0.f;
    for (int dy = 0; dy < 8; ++dy)
#pragma unroll
        for (int dx = 0; dx < 8; ++dx) {
            int s = ((py*8+dy) << 6) + px*8 + dx;
            acc += buf[(((size_t)(b*4096+s)) << 10) + 768 + t];
        }
    acc *= (1.0f/64.0f);
    r1[t] = acc; r2[t] = acc*acc;
    __syncthreads();
    for (int off = 128; off; off >>= 1) {
        if (t < off) { r1[t] += r1[t+off]; r2[t] += r2[t+off]; }
        __syncthreads();
    }
    float mu  = r1[0] * (1.0f/256.0f);
    float var = r2[0] * (1.0f/256.0f) - mu*mu;
    float rstd = rsqrtf(var + 1e-5f);
    xp[((size_t)blk << 8) + t] = (acc - mu) * rstd * g[t] + bb[t];
}

// ---------------------------------------------------------------------------
__global__ __launch_bounds__(256) void kvpool_kernel(
    const float* __restrict__ xp,
    const float* __restrict__ kv_w, const float* __restrict__ kv_b,
    unsigned short* __restrict__ kpb, unsigned short* __restrict__ vpb)
{
    __shared__ float xs[256];
    __shared__ float row[512];
    __shared__ float inv[8];
    const int blk = blockIdx.x;
    const int t = threadIdx.x;
    xs[t] = xp[((size_t)blk << 8) + t];
    __syncthreads();
    for (int o = t; o < 512; o += 256) {
        const float* wr = kv_w + ((size_t)o << 8);
        float s = kv_b[o];
        for (int k = 0; k < 256; ++k) s += xs[k]*wr[k];
        row[o] = s;
    }
    __syncthreads();
    if (t < 8) {
        float s = 0.f;
        for (int dd = 0; dd < 32; ++dd) { float v = row[t*32+dd]; s += v*v; }
        inv[t] = 1.0f / fmaxf(sqrtf(s), EPSF);
    }
    __syncthreads();
    const int b = blk >> 6, p = blk & 63, h = t >> 5, dd = t & 31;
    size_t o = ((((size_t)(b*8+h))*64 + p) << 5) + dd;
    kpb[o] = f2bf(row[t] * inv[h]);
    vpb[o] = f2bf(row[256 + t]);
}

// ---------------------------------------------------------------------------
__global__ __launch_bounds__(256) void cpb_kernel(
    const float* __restrict__ tbl,
    const float* __restrict__ w1, const float* __restrict__ b1,
    const float* __restrict__ w2, const float* __restrict__ b2,
    float* __restrict__ cpb)
{
    __shared__ float hid[512];
    const int r = blockIdx.x, t = threadIdx.x;
    const float c0 = tbl[(size_t)r*2], c1 = tbl[(size_t)r*2+1];
    for (int i = t; i < 512; i += 256)
        hid[i] = fmaxf(c0*w1[i*2] + c1*w1[i*2+1] + b1[i], 0.f);
    __syncthreads();
    const int h = t >> 5, dd = t & 31;
    float s = 0.f;
    for (int i = dd; i < 512; i += 32) s += hid[i] * w2[h*512+i];
    for (int off = 16; off; off >>= 1) s += __shfl_xor(s, off, 32);
    if (dd == 0) cpb[((size_t)r << 3) + h] = s + b2[h];
}

// ---------------------------------------------------------------------------
// MFMA attention (round-6 structure, unchanged).
// ---------------------------------------------------------------------------
__global__ __launch_bounds__(256, 3) void attn_mfma(
    const unsigned short* __restrict__ qkv,   // (16384,2048) packed: q|k|v bf16
    unsigned short* __restrict__ ao,          // (16384,256) bf16
    const unsigned short* __restrict__ kpb,   // (B,H,64,32) bf16
    const unsigned short* __restrict__ vpb,
    const float* __restrict__ cpb,
    const int*   __restrict__ rpi,
    const float* __restrict__ temp,
    const float* __restrict__ qe,
    const float* __restrict__ rpb,
    const float* __restrict__ lt,    // (8,32,9)
    const float* __restrict__ lb,    // (8,1,9)
    const float* __restrict__ gate)
{
    __shared__ __attribute__((aligned(16))) unsigned short U0[112*40];
    __shared__ __attribute__((aligned(16))) unsigned short U1[64*40];
    __shared__ __attribute__((aligned(16))) unsigned short QS[64*40];
    __shared__ __attribute__((aligned(16))) unsigned short P[64*200];
    __shared__ __attribute__((aligned(16))) unsigned short LTT[16*40];
    __shared__ float invscL[64], gateL[64], rpbL[9], dqvL[16];

    const int tile = blockIdx.x;
    const int h    = blockIdx.y;
    const int b    = blockIdx.z;
    const int ty0  = (tile >> 3) << 3;
    const int tx0  = (tile & 7) << 3;
    const int t    = threadIdx.x;

    const float spt = log1pf(expf(temp[h]));
    if (t < 64) {
        int y = ty0 + (t >> 3), x = tx0 + (t & 7);
        int cy = (y == 0 || y == 63) ? 2 : 3;
        int cx = (x == 0 || x == 63) ? 2 : 3;
        invscL[t] = 1.0f / (spt * logf((float)(cy*cx) + 64.0f));
        gateL[t] = gate[(((size_t)(b*4096 + ((y<<6)|x))) << 3) + h];
    } else if (t < 80) {
        int j = t - 64;
        float s = 0.f;
        if (j < 9) {
            s = lb[h*9 + j];
            for (int dd = 0; dd < 32; ++dd)
                s -= qe[h*32+dd] * lt[(h*32+dd)*9 + j];
        }
        dqvL[j] = s;
    } else if (t < 89) {
        rpbL[t-80] = rpb[h*9 + (t-80)];
    }
    for (int i = t; i < 16*32; i += 256) {
        int j = i >> 5, dd = i & 31;
        LTT[j*40 + dd] = (j < 9) ? f2bf(lt[(h*32+dd)*9 + j]) : (unsigned short)0;
    }

    unsigned short* KH = U0;
    unsigned short* KP = U1;
    for (int i = t; i < 112*8; i += 256) {
        int r = i >> 3, sg = i & 7;
        uint2 val = {0u, 0u};
        if (r < 100) {
            int y = ty0 + r/10 - 1, x = tx0 + r%10 - 1;
            if (y >= 0 && y < 64 && x >= 0 && x < 64)
                val = *(const uint2*)(qkv + (size_t)(b*4096 + ((y<<6)|x))*2048 + 256 + h*32 + sg*4);
        }
        *(uint2*)(KH + r*40 + sg*4) = val;
    }
    {
        const unsigned short* src = kpb + (size_t)(b*8+h)*2048;
        for (int i = t; i < 512; i += 256)
            *(uint2*)(KP + (i >> 3)*40 + (i & 7)*4) = *(const uint2*)(src + i*4);
    }
    for (int i = t; i < 512; i += 256) {
        int n = i >> 3, sg = i & 7;
        int y = ty0 + (n >> 3), x = tx0 + (n & 7);
        *(uint2*)(QS + n*40 + sg*4) =
            *(const uint2*)(qkv + (size_t)(b*4096 + ((y<<6)|x))*2048 + h*32 + sg*4);
    }
    for (int i = t; i < 1024; i += 256) {
        int n = i >> 4, c = 112 + (i & 15);
        P[n*200 + c] = 0;
    }
    __syncthreads();

    const int lane  = t & 63;
    const int w     = t >> 6;
    const int col16 = lane & 15;
    const int quad  = lane >> 4;

    float pbias[4][4];
#pragma unroll
    for (int ct = 0; ct < 4; ++ct) {
        int p = ct*16 + col16;
#pragma unroll
        for (int reg = 0; reg < 4; ++reg) {
            int n = w*16 + quad*4 + reg;
            int y = ty0 + (n >> 3), x = tx0 + (n & 7);
            int ngl = (y << 6) | x;
            pbias[ct][reg] = cpb[((size_t)rpi[(size_t)ngl*64 + p] << 3) + h];
        }
    }

    short8 aq = *(const short8*)(QS + (w*16 + col16)*40 + quad*8);
    f32x4 cl[7], cp[4];
    {
        const f32x4 z = {0.f, 0.f, 0.f, 0.f};
#pragma unroll
        for (int ct = 0; ct < 7; ++ct) {
            short8 bk = *(const short8*)(KH + (ct*16 + col16)*40 + quad*8);
            cl[ct] = __builtin_amdgcn_mfma_f32_16x16x32_bf16(aq, bk, z, 0, 0, 0);
        }
#pragma unroll
        for (int ct = 0; ct < 4; ++ct) {
            short8 bp = *(const short8*)(KP + (ct*16 + col16)*40 + quad*8);
            cp[ct] = __builtin_amdgcn_mfma_f32_16x16x32_bf16(aq, bp, z, 0, 0, 0);
        }
    }
#pragma unroll
    for (int ct = 0; ct < 7; ++ct) {
        int hk = ct*16 + col16;
        int ky = hk / 10, kx = hk - ky*10;
#pragma unroll
        for (int reg = 0; reg < 4; ++reg) {
            int n = w*16 + quad*4 + reg;
            int dy = ky - (n >> 3), dx = kx - (n & 7);
            bool valid = (dy >= 0 && dy <= 2 && dx >= 0 && dx <= 2);
            cl[ct][reg] = valid ? (cl[ct][reg] + rpbL[dy*3 + dx]) : -1e30f;
        }
    }
#pragma unroll
    for (int ct = 0; ct < 4; ++ct)
#pragma unroll
        for (int reg = 0; reg < 4; ++reg)
            cp[ct][reg] += pbias[ct][reg];
    float inv[4];
#pragma unroll
    for (int reg = 0; reg < 4; ++reg) {
        float m = -1e30f;
#pragma unroll
        for (int ct = 0; ct < 7; ++ct) m = fmaxf(m, cl[ct][reg]);
#pragma unroll
        for (int ct = 0; ct < 4; ++ct) m = fmaxf(m, cp[ct][reg]);
        m = fmaxf(m, __shfl_xor(m, 1)); m = fmaxf(m, __shfl_xor(m, 2));
        m = fmaxf(m, __shfl_xor(m, 4)); m = fmaxf(m, __shfl_xor(m, 8));
        float s = 0.f;
#pragma unroll
        for (int ct = 0; ct < 7; ++ct) {
            float e = __builtin_expf(cl[ct][reg] - m); cl[ct][reg] = e; s += e;
        }
#pragma unroll
        for (int ct = 0; ct < 4; ++ct) {
            float e = __builtin_expf(cp[ct][reg] - m); cp[ct][reg] = e; s += e;
        }
        s += __shfl_xor(s, 1); s += __shfl_xor(s, 2);
        s += __shfl_xor(s, 4); s += __shfl_xor(s, 8);
        inv[reg] = 1.0f / s;
    }
#pragma unroll
    for (int ct = 0; ct < 7; ++ct)
#pragma unroll
        for (int reg = 0; reg < 4; ++reg) {
            int n = w*16 + quad*4 + reg;
            P[n*200 + ct*16 + col16] = f2bf(cl[ct][reg] * inv[reg]);
        }
#pragma unroll
    for (int ct = 0; ct < 4; ++ct)
#pragma unroll
        for (int reg = 0; reg < 4; ++reg) {
            int n = w*16 + quad*4 + reg;
            P[n*200 + 128 + ct*16 + col16] = f2bf(cp[ct][reg] * inv[reg]);
        }
    {
        const f32x4 z = {0.f, 0.f, 0.f, 0.f};
        short8 blt = *(const short8*)(LTT + col16*40 + quad*8);
        f32x4 cd = __builtin_amdgcn_mfma_f32_16x16x32_bf16(aq, blt, z, 0, 0, 0);
        if (col16 < 9) {
            int dy = col16 / 3, dx = col16 - dy*3;
#pragma unroll
            for (int reg = 0; reg < 4; ++reg) {
                int n = w*16 + quad*4 + reg;
                float ltv = cd[reg] * invscL[n] + dqvL[col16];
                int hk = ((n >> 3) + dy)*10 + (n & 7) + dx;
                P[n*200 + hk] = f2bf(bf2f(P[n*200 + hk]) + ltv);
            }
        }
    }
    __syncthreads();

    unsigned short* VT  = U0;   // [32][136]
    unsigned short* VPT = U1;   // [32][72]
    for (int i = t; i < 1792; i += 256) {
        int rlo = i & 15, rest = i >> 4;
        int dp = rest & 15, r = (rest >> 4)*16 + rlo;
        unsigned val = 0;
        if (r < 100) {
            int y = ty0 + r/10 - 1, x = tx0 + r%10 - 1;
            if (y >= 0 && y < 64 && x >= 0 && x < 64)
                val = *(const unsigned*)(qkv + (size_t)(b*4096 + ((y<<6)|x))*2048 + 512 + h*32 + dp*2);
        }
        VT[(2*dp)*136 + r]   = (unsigned short)(val & 0xffffu);
        VT[(2*dp+1)*136 + r] = (unsigned short)(val >> 16);
    }
    for (int i = t; i < 512; i += 256) {
        int r = 112 + (i & 15), d = i >> 4;
        VT[d*136 + r] = 0;
    }
    for (int i = t; i < 1024; i += 256) {
        int plo = i & 15, rest = i >> 4;
        int dp = rest & 15, p = (rest >> 4)*16 + plo;
        unsigned val = *(const unsigned*)(vpb + (size_t)(b*8+h)*2048 + p*32 + dp*2);
        VPT[(2*dp)*72 + p]   = (unsigned short)(val & 0xffffu);
        VPT[(2*dp+1)*72 + p] = (unsigned short)(val >> 16);
    }
    __syncthreads();

    f32x4 o0 = {0.f,0.f,0.f,0.f}, o1 = {0.f,0.f,0.f,0.f};
#pragma unroll
    for (int ks = 0; ks < 6; ++ks) {
        short8 a = *(const short8*)(P + (w*16 + col16)*200 + ks*32 + quad*8);
        short8 b0, b1;
        if (ks < 4) {
            b0 = *(const short8*)(VT + col16*136      + ks*32 + quad*8);
            b1 = *(const short8*)(VT + (16+col16)*136 + ks*32 + quad*8);
        } else {
            b0 = *(const short8*)(VPT + col16*72      + (ks-4)*32 + quad*8);
            b1 = *(const short8*)(VPT + (16+col16)*72 + (ks-4)*32 + quad*8);
        }
        o0 = __builtin_amdgcn_mfma_f32_16x16x32_bf16(a, b0, o0, 0, 0, 0);
        o1 = __builtin_amdgcn_mfma_f32_16x16x32_bf16(a, b1, o1, 0, 0, 0);
    }
#pragma unroll
    for (int reg = 0; reg < 4; ++reg) {
        int n = w*16 + quad*4 + reg;
        int y = ty0 + (n >> 3), x = tx0 + (n & 7);
        size_t rowo = (size_t)(b*4096 + ((y<<6)|x))*256 + h*32;
        float g = gateL[n];
        ao[rowo + col16]      = f2bf(o0[reg] * g);
        ao[rowo + 16 + col16] = f2bf(o1[reg] * g);
    }
}

// ---------------------------------------------------------------------------
extern "C" void kernel_launch(void* const* d_in, const int* in_sizes, int n_in,
                              void* d_out, int out_size, void* d_ws, size_t ws_size,
                              hipStream_t stream)
{
    const float* x    = (const float*)d_in[0];
    const float* tbl  = (const float*)d_in[1];
    const float* q_w  = (const float*)d_in[2];
    const float* q_b  = (const float*)d_in[3];
    const float* kv_w = (const float*)d_in[4];
    const float* kv_b = (const float*)d_in[5];
    const float* temp = (const float*)d_in[6];
    const float* qe   = (const float*)d_in[7];
    const float* rpb  = (const float*)d_in[8];
    const float* lt   = (const float*)d_in[9];
    const float* lb   = (const float*)d_in[10];
    const float* c1w  = (const float*)d_in[11];
    const float* c1b  = (const float*)d_in[12];
    const float* c2w  = (const float*)d_in[13];
    const float* c2b  = (const float*)d_in[14];
    const float* sr_w = (const float*)d_in[15];
    const float* sr_b = (const float*)d_in[16];
    const float* ng   = (const float*)d_in[17];
    const float* nbias= (const float*)d_in[18];
    const float* wg   = (const float*)d_in[19];
    const float* wg0  = (const float*)d_in[20];
    const float* wg1  = (const float*)d_in[21];
    const float* pw   = (const float*)d_in[22];
    const float* pb   = (const float*)d_in[23];
    const int*   rpi  = (const int*)d_in[24];
    (void)in_sizes; (void)n_in; (void)out_size; (void)ws_size;

    float* buf   = (float*)d_ws;                       // 16384x1024 f32 layout
    unsigned short* qkvb = (unsigned short*)d_ws;      // (16384, 2048) ushort view
    float* xp    = buf + (size_t)16384*1024;
    float* kpoolf= xp + 65536;
    unsigned short* kpb = (unsigned short*)kpoolf;
    unsigned short* vpb = kpb + 131072;
    float* cpbb  = kpoolf + 131072;
    float* gateb = cpbb + 32768;
    unsigned short* xbf  = (unsigned short*)(gateb + 131072);
    unsigned short* ao   = xbf;
    unsigned short* wcat = xbf + (size_t)16384*256;
    unsigned short* pwbf = wcat + 262144;
    float* out   = (float*)d_out;

    // 0) dtype conversions
    convert_x<<<4096,256,0,stream>>>(x, xbf);
    convert_w<<<320,256,0,stream>>>(q_w, kv_w, sr_w, pw, wcat, pwbf);
    // 1) fused MFMA GEMM -> packed bf16 q(scaled)|k(normed)|v + f32 gelu(sr)
    gemm_mfma<<<dim3(8,128),256,0,stream>>>(xbf, wcat, q_b, kv_b, sr_b,
                                            256, 768, 0, buf, 1024,
                                            qkvb, temp, qe);
    // 2) MoE gates
    gate_kernel<<<16384,64,0,stream>>>(x, wg, wg0, wg1, gateb);
    // 3) 8x8 avg-pool + LayerNorm of gelu(sr)
    pool_ln_kernel<<<256,256,0,stream>>>(buf, ng, nbias, xp);
    // 4) pooled kv + k-norm (fp32 math, bf16 out)
    kvpool_kernel<<<256,256,0,stream>>>(xp, kv_w, kv_b, kpb, vpb);
    // 5) CPB bias table
    cpb_kernel<<<4096,256,0,stream>>>(tbl, c1w, c1b, c2w, c2b, cpbb);
    // 6) MFMA attention -> bf16 compact
    attn_mfma<<<dim3(64,8,4),256,0,stream>>>(qkvb, ao, kpb, vpb, cpbb, rpi,
                                             temp, qe, rpb, lt, lb, gateb);
    // 7) output projection (MFMA)
    gemm_mfma<<<dim3(2,128),256,0,stream>>>(ao, pwbf, pb, pb, pb,
                                            1<<30, 1<<30, 1, out, 256,
                                            (unsigned short*)nullptr, nullptr, nullptr);
}

// Round 8
// 267.607 us; speedup vs baseline: 2.2343x; 1.0408x over previous
//
#include <hip/hip_runtime.h>
#include <math.h>

#define EPSF 1.1920929e-07f

typedef __attribute__((ext_vector_type(8))) short short8;
typedef __attribute__((ext_vector_type(4))) float f32x4;

// float -> bf16 (RNE)
static __device__ __forceinline__ unsigned short f2bf(float f) {
    unsigned int u = __float_as_uint(f);
    return (unsigned short)((u + 0x7FFFu + ((u >> 16) & 1u)) >> 16);
}
static __device__ __forceinline__ float bf2f(unsigned short u) {
    return __uint_as_float((unsigned int)u << 16);
}

// ---------------------------------------------------------------------------
// x (16384x256 f32) -> bf16
// ---------------------------------------------------------------------------
__global__ __launch_bounds__(256) void convert_x(
    const float* __restrict__ x, unsigned short* __restrict__ xbf)
{
    const int e = (blockIdx.x * 256 + threadIdx.x) * 4;
    float4 v = *(const float4*)(x + e);
    ushort4 o;
    o.x = f2bf(v.x); o.y = f2bf(v.y); o.z = f2bf(v.z); o.w = f2bf(v.w);
    *(ushort4*)(xbf + e) = o;
}

// ---------------------------------------------------------------------------
// weights -> bf16
// ---------------------------------------------------------------------------
__global__ __launch_bounds__(256) void convert_w(
    const float* __restrict__ q_w, const float* __restrict__ kv_w,
    const float* __restrict__ sr_w, const float* __restrict__ pw,
    unsigned short* __restrict__ wcat, unsigned short* __restrict__ pwbf)
{
    const int e = (blockIdx.x * 256 + threadIdx.x) * 4;
    if (e < 262144) {
        int n = e >> 8, k = e & 255;
        const float* src = (n < 256) ? (q_w + n*256) :
                           (n < 768) ? (kv_w + (n-256)*256) : (sr_w + (n-768)*256);
        float4 v = *(const float4*)(src + k);
        ushort4 o;
        o.x = f2bf(v.x); o.y = f2bf(v.y); o.z = f2bf(v.z); o.w = f2bf(v.w);
        *(ushort4*)(wcat + e) = o;
    } else {
        int e2 = e - 262144;
        float4 v = *(const float4*)(pw + e2);
        ushort4 o;
        o.x = f2bf(v.x); o.y = f2bf(v.y); o.z = f2bf(v.z); o.w = f2bf(v.w);
        *(ushort4*)(pwbf + e2) = o;
    }
}

// ---------------------------------------------------------------------------
// MFMA bf16 GEMM, K=256, SINGLE K-PASS: 64x64 tile with the full K staged
// once into LDS (rows padded to 264 ushorts -> 2-way banks, 16B aligned),
// ONE barrier per block, then 8 k-steps of ds_read_b128 + MFMA. No k-loop
// barrier drain (the round-6/7 latency problem was structural to the k-loop).
// mode 0: fused q|k|v|sr producer (q/k L2-normed, q fully scaled, bf16 out
// packed at qkv[row*2048+col]; sr gelu'd -> f32 C). mode 1: bias-add f32 GEMM.
// ---------------------------------------------------------------------------
__global__ __launch_bounds__(256) void gemm_mfma(
    const unsigned short* __restrict__ A,
    const unsigned short* __restrict__ W,
    const float* __restrict__ B0, const float* __restrict__ B1,
    const float* __restrict__ B2,
    int r1, int r2, int mode,
    float* __restrict__ C, int ldc,
    unsigned short* __restrict__ qkv,
    const float* __restrict__ temp, const float* __restrict__ qe)
{
    __shared__ __attribute__((aligned(16))) unsigned short At[64*264];
    __shared__ __attribute__((aligned(16))) unsigned short Bt[64*264];
    const int m0 = blockIdx.y << 6;
    const int n0 = blockIdx.x << 6;
    const int t  = threadIdx.x;
    const int w  = t >> 6;
    const int col16 = t & 15;
    const int quad  = (t & 63) >> 4;

    const float* Bp; int noff;
    if (n0 < r1)      { Bp = B0; noff = 0;  }
    else if (n0 < r2) { Bp = B1; noff = r1; }
    else              { Bp = B2; noff = r2; }

    // ---- stage full 64x256 A and B tiles (8 uint4 each per thread) ----
    uint4 av[8], bv[8];
#pragma unroll
    for (int j = 0; j < 8; ++j) {
        int ci = j*256 + t;            // 16B-chunk id: row = ci>>5, chunk = ci&31
        int r = ci >> 5, c = ci & 31;
        av[j] = *(const uint4*)(A + (size_t)(m0 + r)*256 + c*8);
        bv[j] = *(const uint4*)(W + (size_t)(n0 + r)*256 + c*8);
    }
#pragma unroll
    for (int j = 0; j < 8; ++j) {
        int ci = j*256 + t;
        int r = ci >> 5, c = ci & 31;
        *(uint4*)(At + r*264 + c*8) = av[j];
        *(uint4*)(Bt + r*264 + c*8) = bv[j];
    }
    __syncthreads();

    // ---- compute: wave w = 16-row m-strip x 64 cols, 32 MFMAs ----
    f32x4 acc[4];
#pragma unroll
    for (int ct = 0; ct < 4; ++ct) acc[ct] = (f32x4){0.f, 0.f, 0.f, 0.f};
#pragma unroll
    for (int kk = 0; kk < 8; ++kk) {
        short8 af = *(const short8*)(At + (w*16 + col16)*264 + kk*32 + quad*8);
#pragma unroll
        for (int ct = 0; ct < 4; ++ct) {
            short8 bf = *(const short8*)(Bt + (ct*16 + col16)*264 + kk*32 + quad*8);
            acc[ct] = __builtin_amdgcn_mfma_f32_16x16x32_bf16(af, bf, acc[ct], 0, 0, 0);
        }
    }

    float bias_c[4];
#pragma unroll
    for (int ct = 0; ct < 4; ++ct)
        bias_c[ct] = Bp[n0 + ct*16 + col16 - noff];

    if (mode == 0) {
        const int region = n0 >> 8;    // 0=q, 1=k, 2=v, 3=sr
        float qe_c[4], spt_c[4];
        if (region == 0) {
#pragma unroll
            for (int c = 0; c < 4; ++c) {
                int col = n0 + c*16 + col16;
                spt_c[c] = log1pf(expf(temp[(col >> 5) & 7]));
                qe_c[c]  = qe[col];
            }
        }
#pragma unroll
        for (int reg = 0; reg < 4; ++reg) {
            const int row = m0 + w*16 + quad*4 + reg;
            float v[4];
#pragma unroll
            for (int c = 0; c < 4; ++c) v[c] = acc[c][reg] + bias_c[c];
            if (region <= 1) {             // q,k: per-head L2 norm (head = 2 c-tiles)
#pragma unroll
                for (int hp = 0; hp < 2; ++hp) {
                    float s = v[2*hp]*v[2*hp] + v[2*hp+1]*v[2*hp+1];
                    s += __shfl_xor(s, 1); s += __shfl_xor(s, 2);
                    s += __shfl_xor(s, 4); s += __shfl_xor(s, 8);
                    float inv = 1.0f / fmaxf(sqrtf(s), EPSF);
                    v[2*hp]   *= inv;
                    v[2*hp+1] *= inv;
                }
            }
            if (region == 0) {             // q: (qn+qe)*softplus(temp)*sls
                int n = row & 4095;
                int y = n >> 6, x = n & 63;
                int cy = (y == 0 || y == 63) ? 2 : 3;
                int cx = (x == 0 || x == 63) ? 2 : 3;
                float sls = logf((float)(cy*cx) + 64.0f);
#pragma unroll
                for (int c = 0; c < 4; ++c)
                    v[c] = (v[c] + qe_c[c]) * (spt_c[c] * sls);
            }
            if (region == 3) {             // sr: gelu -> f32
#pragma unroll
                for (int c = 0; c < 4; ++c) {
                    float g = 0.5f * v[c] * (1.0f + erff(v[c] * 0.70710678118654752f));
                    C[(size_t)row * ldc + n0 + c*16 + col16] = g;
                }
            } else {                       // q/k/v: packed bf16
#pragma unroll
                for (int c = 0; c < 4; ++c)
                    qkv[(size_t)row * 2048 + n0 + c*16 + col16] = f2bf(v[c]);
            }
        }
    } else {
#pragma unroll
        for (int reg = 0; reg < 4; ++reg) {
            const int row = m0 + w*16 + quad*4 + reg;
#pragma unroll
            for (int c = 0; c < 4; ++c)
                C[(size_t)row * ldc + n0 + c*16 + col16] = acc[c][reg] + bias_c[c];
        }
    }
}

// ---------------------------------------------------------------------------
// MoE gating v2: 64 tokens/block, 4 lanes/token (64B each), weights staged
// in LDS with bank-padded rows (stride 272, sub-block base sub*68 -> distinct
// banks, 16B aligned). Exact fp32.
// ---------------------------------------------------------------------------
__global__ __launch_bounds__(256) void gate_kernel(
    const float* __restrict__ x,
    const float* __restrict__ wg,
    const float* __restrict__ wg0,
    const float* __restrict__ wg1,
    float* __restrict__ gate)
{
    __shared__ float wsm[10*272];
    const int t  = threadIdx.x;
    const int t0 = blockIdx.x << 6;
    for (int i = t; i < 2560; i += 256) {
        int f = i >> 8, k = i & 255;
        const float* src = (f < 4) ? (wg + f*256) : (f < 6) ? (wg0 + (f-4)*256) : (wg1 + (f-6)*256);
        wsm[f*272 + (k & 63) + (k >> 6)*68] = src[k];
    }
    __syncthreads();
    const int tok = t >> 2, sub = t & 3;
    const float4* xr = (const float4*)(x + (size_t)(t0 + tok)*256 + sub*64);
    float4 xv[16];
#pragma unroll
    for (int i = 0; i < 16; ++i) xv[i] = xr[i];
    float d[10];
#pragma unroll
    for (int f = 0; f < 10; ++f) {
        const float* wrow = wsm + f*272 + sub*68;
        float s = 0.f;
#pragma unroll
        for (int i = 0; i < 16; ++i) {
            float4 wv = *(const float4*)(wrow + i*4);
            s += xv[i].x*wv.x + xv[i].y*wv.y + xv[i].z*wv.z + xv[i].w*wv.w;
        }
        s += __shfl_xor(s, 1, 4);
        s += __shfl_xor(s, 2, 4);
        d[f] = s;
    }
    if (sub == 0) {
        float e[4];
        float m = fmaxf(fmaxf(d[0],d[1]), fmaxf(d[2],d[3]));
        float ssum = 0.f;
        for (int i = 0; i < 4; ++i) { e[i] = expf(d[i]-m); ssum += e[i]; }
        for (int i = 0; i < 4; ++i) e[i] /= ssum;
        int i1 = 0;
        for (int i = 1; i < 4; ++i) if (e[i] > e[i1]) i1 = i;
        int i2 = -1;
        for (int i = 0; i < 4; ++i) if (i != i1 && (i2 < 0 || e[i] > e[i2])) i2 = i;
        float rs = fmaxf(e[i1] + e[i2], EPSF);
        float rg[4] = {0.f,0.f,0.f,0.f};
        rg[i1] = e[i1] / rs * 2.f;
        rg[i2] = e[i2] / rs * 2.f;
        float sh[4];
        float m1 = fmaxf(fmaxf(d[6],d[7]), fmaxf(d[8],d[9]));
        float s1 = 0.f;
        for (int i = 0; i < 4; ++i) { sh[i] = expf(d[6+i]-m1); s1 += sh[i]; }
        float mm = fmaxf(d[4], d[5]);
        float e0 = expf(d[4]-mm), e1 = expf(d[5]-mm);
        float w00 = e0/(e0+e1)*2.f, w01 = e1/(e0+e1)*2.f;
        float* gr = gate + ((size_t)(t0 + tok) << 3);
        for (int i = 0; i < 4; ++i) gr[i]   = w00 * (sh[i]/s1*4.f);
        for (int i = 0; i < 4; ++i) gr[4+i] = w01 * rg[i];
    }
}

// ---------------------------------------------------------------------------
__global__ __launch_bounds__(256) void pool_ln_kernel(
    const float* __restrict__ buf,
    const float* __restrict__ g, const float* __restrict__ bb,
    float* __restrict__ xp)
{
    __shared__ float r1[256], r2[256];
    const int blk = blockIdx.x;
    const int b = blk >> 6, p = blk & 63;
    const int py = p >> 3, px = p & 7;
    const int t = threadIdx.x;
    float acc = 0.f;
    for (int dy = 0; dy < 8; ++dy)
#pragma unroll
        for (int dx = 0; dx < 8; ++dx) {
            int s = ((py*8+dy) << 6) + px*8 + dx;
            acc += buf[(((size_t)(b*4096+s)) << 10) + 768 + t];
        }
    acc *= (1.0f/64.0f);
    r1[t] = acc; r2[t] = acc*acc;
    __syncthreads();
    for (int off = 128; off; off >>= 1) {
        if (t < off) { r1[t] += r1[t+off]; r2[t] += r2[t+off]; }
        __syncthreads();
    }
    float mu  = r1[0] * (1.0f/256.0f);
    float var = r2[0] * (1.0f/256.0f) - mu*mu;
    float rstd = rsqrtf(var + 1e-5f);
    xp[((size_t)blk << 8) + t] = (acc - mu) * rstd * g[t] + bb[t];
}

// ---------------------------------------------------------------------------
__global__ __launch_bounds__(256) void kvpool_kernel(
    const float* __restrict__ xp,
    const float* __restrict__ kv_w, const float* __restrict__ kv_b,
    unsigned short* __restrict__ kpb, unsigned short* __restrict__ vpb)
{
    __shared__ float xs[256];
    __shared__ float row[512];
    __shared__ float inv[8];
    const int blk = blockIdx.x;
    const int t = threadIdx.x;
    xs[t] = xp[((size_t)blk << 8) + t];
    __syncthreads();
    for (int o = t; o < 512; o += 256) {
        const float* wr = kv_w + ((size_t)o << 8);
        float s = kv_b[o];
        for (int k = 0; k < 256; ++k) s += xs[k]*wr[k];
        row[o] = s;
    }
    __syncthreads();
    if (t < 8) {
        float s = 0.f;
        for (int dd = 0; dd < 32; ++dd) { float v = row[t*32+dd]; s += v*v; }
        inv[t] = 1.0f / fmaxf(sqrtf(s), EPSF);
    }
    __syncthreads();
    const int b = blk >> 6, p = blk & 63, h = t >> 5, dd = t & 31;
    size_t o = ((((size_t)(b*8+h))*64 + p) << 5) + dd;
    kpb[o] = f2bf(row[t] * inv[h]);
    vpb[o] = f2bf(row[256 + t]);
}

// ---------------------------------------------------------------------------
__global__ __launch_bounds__(256) void cpb_kernel(
    const float* __restrict__ tbl,
    const float* __restrict__ w1, const float* __restrict__ b1,
    const float* __restrict__ w2, const float* __restrict__ b2,
    float* __restrict__ cpb)
{
    __shared__ float hid[512];
    const int r = blockIdx.x, t = threadIdx.x;
    const float c0 = tbl[(size_t)r*2], c1 = tbl[(size_t)r*2+1];
    for (int i = t; i < 512; i += 256)
        hid[i] = fmaxf(c0*w1[i*2] + c1*w1[i*2+1] + b1[i], 0.f);
    __syncthreads();
    const int h = t >> 5, dd = t & 31;
    float s = 0.f;
    for (int i = dd; i < 512; i += 32) s += hid[i] * w2[h*512+i];
    for (int off = 16; off; off >>= 1) s += __shfl_xor(s, off, 32);
    if (dd == 0) cpb[((size_t)r << 3) + h] = s + b2[h];
}

// ---------------------------------------------------------------------------
// MFMA attention v4: wave-local halo tiling. Wave w's 16 tokens only see
// halo keys [20w, 20w+40) which fit in 4 aligned 16-key tiles starting at
// s_w = (20w) & ~15. QK: 4 halo + 4 pooled MFMAs (was 7+4); PV K=128
// (64 wave-local halo + 64 pooled, 4 k-steps, was 6). P row = 136 ushorts.
// LDS 38.5 KB -> 4 blocks/CU.
// ---------------------------------------------------------------------------
__global__ __launch_bounds__(256, 4) void attn_mfma(
    const unsigned short* __restrict__ qkv,   // (16384,2048) packed: q|k|v bf16
    unsigned short* __restrict__ ao,          // (16384,256) bf16
    const unsigned short* __restrict__ kpb,   // (B,H,64,32) bf16
    const unsigned short* __restrict__ vpb,
    const float* __restrict__ cpb,
    const int*   __restrict__ rpi,
    const float* __restrict__ temp,
    const float* __restrict__ qe,
    const float* __restrict__ rpb,
    const float* __restrict__ lt,    // (8,32,9)
    const float* __restrict__ lb,    // (8,1,9)
    const float* __restrict__ gate)
{
    __shared__ __attribute__((aligned(16))) unsigned short U0[112*40]; // KH -> VT[32*136]
    __shared__ __attribute__((aligned(16))) unsigned short U1[64*40];  // KP -> VPT[32*72]
    __shared__ __attribute__((aligned(16))) unsigned short QS[64*40];
    __shared__ __attribute__((aligned(16))) unsigned short P[64*136];  // [tok][64 halo | 64 pool | 8 pad]
    __shared__ __attribute__((aligned(16))) unsigned short LTT[16*40];
    __shared__ float invscL[64], gateL[64], rpbL[9], dqvL[16];

    const int tile = blockIdx.x;
    const int h    = blockIdx.y;
    const int b    = blockIdx.z;
    const int ty0  = (tile >> 3) << 3;
    const int tx0  = (tile & 7) << 3;
    const int t    = threadIdx.x;

    const float spt = log1pf(expf(temp[h]));
    if (t < 64) {
        int y = ty0 + (t >> 3), x = tx0 + (t & 7);
        int cy = (y == 0 || y == 63) ? 2 : 3;
        int cx = (x == 0 || x == 63) ? 2 : 3;
        invscL[t] = 1.0f / (spt * logf((float)(cy*cx) + 64.0f));
        gateL[t] = gate[(((size_t)(b*4096 + ((y<<6)|x))) << 3) + h];
    } else if (t < 80) {
        int j = t - 64;
        float s = 0.f;
        if (j < 9) {
            s = lb[h*9 + j];
            for (int dd = 0; dd < 32; ++dd)
                s -= qe[h*32+dd] * lt[(h*32+dd)*9 + j];
        }
        dqvL[j] = s;
    } else if (t < 89) {
        rpbL[t-80] = rpb[h*9 + (t-80)];
    }
    for (int i = t; i < 16*32; i += 256) {
        int j = i >> 5, dd = i & 31;
        LTT[j*40 + dd] = (j < 9) ? f2bf(lt[(h*32+dd)*9 + j]) : (unsigned short)0;
    }

    unsigned short* KH = U0;
    unsigned short* KP = U1;
    for (int i = t; i < 112*8; i += 256) {
        int r = i >> 3, sg = i & 7;
        uint2 val = {0u, 0u};
        if (r < 100) {
            int y = ty0 + r/10 - 1, x = tx0 + r%10 - 1;
            if (y >= 0 && y < 64 && x >= 0 && x < 64)
                val = *(const uint2*)(qkv + (size_t)(b*4096 + ((y<<6)|x))*2048 + 256 + h*32 + sg*4);
        }
        *(uint2*)(KH + r*40 + sg*4) = val;
    }
    {
        const unsigned short* src = kpb + (size_t)(b*8+h)*2048;
        for (int i = t; i < 512; i += 256)
            *(uint2*)(KP + (i >> 3)*40 + (i & 7)*4) = *(const uint2*)(src + i*4);
    }
    for (int i = t; i < 512; i += 256) {
        int n = i >> 3, sg = i & 7;
        int y = ty0 + (n >> 3), x = tx0 + (n & 7);
        *(uint2*)(QS + n*40 + sg*4) =
            *(const uint2*)(qkv + (size_t)(b*4096 + ((y<<6)|x))*2048 + h*32 + sg*4);
    }
    __syncthreads();

    const int lane  = t & 63;
    const int w     = t >> 6;
    const int col16 = lane & 15;
    const int quad  = lane >> 4;
    const int s_w   = (20*w) & ~15;    // wave-local halo tile base: 0,16,32,48

    // pooled bias gather first (global loads fly under the MFMAs)
    float pbias[4][4];
#pragma unroll
    for (int ct = 0; ct < 4; ++ct) {
        int p = ct*16 + col16;
#pragma unroll
        for (int reg = 0; reg < 4; ++reg) {
            int n = w*16 + quad*4 + reg;
            int y = ty0 + (n >> 3), x = tx0 + (n & 7);
            int ngl = (y << 6) | x;
            pbias[ct][reg] = cpb[((size_t)rpi[(size_t)ngl*64 + p] << 3) + h];
        }
    }

    short8 aq = *(const short8*)(QS + (w*16 + col16)*40 + quad*8);
    f32x4 cl[4], cp[4];
    {
        const f32x4 z = {0.f, 0.f, 0.f, 0.f};
#pragma unroll
        for (int ct = 0; ct < 4; ++ct) {
            short8 bk = *(const short8*)(KH + (s_w + ct*16 + col16)*40 + quad*8);
            cl[ct] = __builtin_amdgcn_mfma_f32_16x16x32_bf16(aq, bk, z, 0, 0, 0);
        }
#pragma unroll
        for (int ct = 0; ct < 4; ++ct) {
            short8 bp = *(const short8*)(KP + (ct*16 + col16)*40 + quad*8);
            cp[ct] = __builtin_amdgcn_mfma_f32_16x16x32_bf16(aq, bp, z, 0, 0, 0);
        }
    }
    // window mask + rpb (halo), cpb bias (pooled)
#pragma unroll
    for (int ct = 0; ct < 4; ++ct) {
        int hk = s_w + ct*16 + col16;
        int ky = hk / 10, kx = hk - ky*10;
#pragma unroll
        for (int reg = 0; reg < 4; ++reg) {
            int n = w*16 + quad*4 + reg;
            int dy = ky - (n >> 3), dx = kx - (n & 7);
            bool valid = (dy >= 0 && dy <= 2 && dx >= 0 && dx <= 2);
            cl[ct][reg] = valid ? (cl[ct][reg] + rpbL[dy*3 + dx]) : -1e30f;
        }
    }
#pragma unroll
    for (int ct = 0; ct < 4; ++ct)
#pragma unroll
        for (int reg = 0; reg < 4; ++reg)
            cp[ct][reg] += pbias[ct][reg];
    // softmax (reduce over the 16 col-lanes)
    float inv[4];
#pragma unroll
    for (int reg = 0; reg < 4; ++reg) {
        float m = -1e30f;
#pragma unroll
        for (int ct = 0; ct < 4; ++ct) m = fmaxf(m, cl[ct][reg]);
#pragma unroll
        for (int ct = 0; ct < 4; ++ct) m = fmaxf(m, cp[ct][reg]);
        m = fmaxf(m, __shfl_xor(m, 1)); m = fmaxf(m, __shfl_xor(m, 2));
        m = fmaxf(m, __shfl_xor(m, 4)); m = fmaxf(m, __shfl_xor(m, 8));
        float s = 0.f;
#pragma unroll
        for (int ct = 0; ct < 4; ++ct) {
            float e = __builtin_expf(cl[ct][reg] - m); cl[ct][reg] = e; s += e;
        }
#pragma unroll
        for (int ct = 0; ct < 4; ++ct) {
            float e = __builtin_expf(cp[ct][reg] - m); cp[ct][reg] = e; s += e;
        }
        s += __shfl_xor(s, 1); s += __shfl_xor(s, 2);
        s += __shfl_xor(s, 4); s += __shfl_xor(s, 8);
        inv[reg] = 1.0f / s;
    }
    // write P (rows wave-private; halo cols are wave-local keys s_w+c)
#pragma unroll
    for (int ct = 0; ct < 4; ++ct)
#pragma unroll
        for (int reg = 0; reg < 4; ++reg) {
            int n = w*16 + quad*4 + reg;
            P[n*136 + ct*16 + col16] = f2bf(cl[ct][reg] * inv[reg]);
        }
#pragma unroll
    for (int ct = 0; ct < 4; ++ct)
#pragma unroll
        for (int reg = 0; reg < 4; ++reg) {
            int n = w*16 + quad*4 + reg;
            P[n*136 + 64 + ct*16 + col16] = f2bf(cp[ct][reg] * inv[reg]);
        }
    // learnable-token add (post-softmax, same-wave rows)
    {
        const f32x4 z = {0.f, 0.f, 0.f, 0.f};
        short8 blt = *(const short8*)(LTT + col16*40 + quad*8);
        f32x4 cd = __builtin_amdgcn_mfma_f32_16x16x32_bf16(aq, blt, z, 0, 0, 0);
        if (col16 < 9) {
            int dy = col16 / 3, dx = col16 - dy*3;
#pragma unroll
            for (int reg = 0; reg < 4; ++reg) {
                int n = w*16 + quad*4 + reg;
                float ltv = cd[reg] * invscL[n] + dqvL[col16];
                int hk = ((n >> 3) + dy)*10 + (n & 7) + dx;   // in [20w, 20w+40)
                int pc = hk - s_w;                             // in [0, 64)
                P[n*136 + pc] = f2bf(bf2f(P[n*136 + pc]) + ltv);
            }
        }
    }
    __syncthreads();   // all KH/KP reads done -> overwrite with V

    unsigned short* VT  = U0;   // [32][136], keys 0..111 (rows >=100 zero)
    unsigned short* VPT = U1;   // [32][72]
    for (int i = t; i < 1792; i += 256) {
        int rlo = i & 15, rest = i >> 4;
        int dp = rest & 15, r = (rest >> 4)*16 + rlo;
        unsigned val = 0;
        if (r < 100) {
            int y = ty0 + r/10 - 1, x = tx0 + r%10 - 1;
            if (y >= 0 && y < 64 && x >= 0 && x < 64)
                val = *(const unsigned*)(qkv + (size_t)(b*4096 + ((y<<6)|x))*2048 + 512 + h*32 + dp*2);
        }
        VT[(2*dp)*136 + r]   = (unsigned short)(val & 0xffffu);
        VT[(2*dp+1)*136 + r] = (unsigned short)(val >> 16);
    }
    for (int i = t; i < 1024; i += 256) {
        int plo = i & 15, rest = i >> 4;
        int dp = rest & 15, p = (rest >> 4)*16 + plo;
        unsigned val = *(const unsigned*)(vpb + (size_t)(b*8+h)*2048 + p*32 + dp*2);
        VPT[(2*dp)*72 + p]   = (unsigned short)(val & 0xffffu);
        VPT[(2*dp+1)*72 + p] = (unsigned short)(val >> 16);
    }
    __syncthreads();

    // ---- PV: K = 128 (64 wave-local halo + 64 pooled) ----
    f32x4 o0 = {0.f,0.f,0.f,0.f}, o1 = {0.f,0.f,0.f,0.f};
#pragma unroll
    for (int ks = 0; ks < 4; ++ks) {
        short8 a = *(const short8*)(P + (w*16 + col16)*136 + ks*32 + quad*8);
        short8 b0, b1;
        if (ks < 2) {
            b0 = *(const short8*)(VT + col16*136      + s_w + ks*32 + quad*8);
            b1 = *(const short8*)(VT + (16+col16)*136 + s_w + ks*32 + quad*8);
        } else {
            b0 = *(const short8*)(VPT + col16*72      + (ks-2)*32 + quad*8);
            b1 = *(const short8*)(VPT + (16+col16)*72 + (ks-2)*32 + quad*8);
        }
        o0 = __builtin_amdgcn_mfma_f32_16x16x32_bf16(a, b0, o0, 0, 0, 0);
        o1 = __builtin_amdgcn_mfma_f32_16x16x32_bf16(a, b1, o1, 0, 0, 0);
    }
#pragma unroll
    for (int reg = 0; reg < 4; ++reg) {
        int n = w*16 + quad*4 + reg;
        int y = ty0 + (n >> 3), x = tx0 + (n & 7);
        size_t rowo = (size_t)(b*4096 + ((y<<6)|x))*256 + h*32;
        float g = gateL[n];
        ao[rowo + col16]      = f2bf(o0[reg] * g);
        ao[rowo + 16 + col16] = f2bf(o1[reg] * g);
    }
}

// ---------------------------------------------------------------------------
extern "C" void kernel_launch(void* const* d_in, const int* in_sizes, int n_in,
                              void* d_out, int out_size, void* d_ws, size_t ws_size,
                              hipStream_t stream)
{
    const float* x    = (const float*)d_in[0];
    const float* tbl  = (const float*)d_in[1];
    const float* q_w  = (const float*)d_in[2];
    const float* q_b  = (const float*)d_in[3];
    const float* kv_w = (const float*)d_in[4];
    const float* kv_b = (const float*)d_in[5];
    const float* temp = (const float*)d_in[6];
    const float* qe   = (const float*)d_in[7];
    const float* rpb  = (const float*)d_in[8];
    const float* lt   = (const float*)d_in[9];
    const float* lb   = (const float*)d_in[10];
    const float* c1w  = (const float*)d_in[11];
    const float* c1b  = (const float*)d_in[12];
    const float* c2w  = (const float*)d_in[13];
    const float* c2b  = (const float*)d_in[14];
    const float* sr_w = (const float*)d_in[15];
    const float* sr_b = (const float*)d_in[16];
    const float* ng   = (const float*)d_in[17];
    const float* nbias= (const float*)d_in[18];
    const float* wg   = (const float*)d_in[19];
    const float* wg0  = (const float*)d_in[20];
    const float* wg1  = (const float*)d_in[21];
    const float* pw   = (const float*)d_in[22];
    const float* pb   = (const float*)d_in[23];
    const int*   rpi  = (const int*)d_in[24];
    (void)in_sizes; (void)n_in; (void)out_size; (void)ws_size;

    float* buf   = (float*)d_ws;                       // 16384x1024 f32 layout
    unsigned short* qkvb = (unsigned short*)d_ws;      // (16384, 2048) ushort view
    float* xp    = buf + (size_t)16384*1024;
    float* kpoolf= xp + 65536;
    unsigned short* kpb = (unsigned short*)kpoolf;
    unsigned short* vpb = kpb + 131072;
    float* cpbb  = kpoolf + 131072;
    float* gateb = cpbb + 32768;
    unsigned short* xbf  = (unsigned short*)(gateb + 131072);
    unsigned short* ao   = xbf;                        // reuses x_bf (dead after gemm1)
    unsigned short* wcat = xbf + (size_t)16384*256;
    unsigned short* pwbf = wcat + 262144;
    float* out   = (float*)d_out;

    // 0) dtype conversions
    convert_x<<<4096,256,0,stream>>>(x, xbf);
    convert_w<<<320,256,0,stream>>>(q_w, kv_w, sr_w, pw, wcat, pwbf);
    // 1) fused MFMA GEMM -> packed bf16 q(scaled)|k(normed)|v + f32 gelu(sr)
    gemm_mfma<<<dim3(16,256),256,0,stream>>>(xbf, wcat, q_b, kv_b, sr_b,
                                             256, 768, 0, buf, 1024,
                                             qkvb, temp, qe);
    // 2) MoE gates
    gate_kernel<<<256,256,0,stream>>>(x, wg, wg0, wg1, gateb);
    // 3) 8x8 avg-pool + LayerNorm of gelu(sr)
    pool_ln_kernel<<<256,256,0,stream>>>(buf, ng, nbias, xp);
    // 4) pooled kv + k-norm (fp32 math, bf16 out)
    kvpool_kernel<<<256,256,0,stream>>>(xp, kv_w, kv_b, kpb, vpb);
    // 5) CPB bias table
    cpb_kernel<<<4096,256,0,stream>>>(tbl, c1w, c1b, c2w, c2b, cpbb);
    // 6) MFMA attention -> bf16 compact
    attn_mfma<<<dim3(64,8,4),256,0,stream>>>(qkvb, ao, kpb, vpb, cpbb, rpi,
                                             temp, qe, rpb, lt, lb, gateb);
    // 7) output projection (MFMA)
    gemm_mfma<<<dim3(4,256),256,0,stream>>>(ao, pwbf, pb, pb, pb,
                                            1<<30, 1<<30, 1, out, 256,
                                            (unsigned short*)nullptr, nullptr, nullptr);
}

// Round 9
// 260.340 us; speedup vs baseline: 2.2967x; 1.0279x over previous
//
#include <hip/hip_runtime.h>
#include <math.h>

#define EPSF 1.1920929e-07f

typedef __attribute__((ext_vector_type(8))) short short8;
typedef __attribute__((ext_vector_type(4))) float f32x4;

// float -> bf16 (RNE)
static __device__ __forceinline__ unsigned short f2bf(float f) {
    unsigned int u = __float_as_uint(f);
    return (unsigned short)((u + 0x7FFFu + ((u >> 16) & 1u)) >> 16);
}
static __device__ __forceinline__ float bf2f(unsigned short u) {
    return __uint_as_float((unsigned int)u << 16);
}

// ---------------------------------------------------------------------------
// prep: three block-uniform roles.
//  blk <  4096 : x->bf16 (4 rows/block) + fused MoE gate (exact fp32; 10
//                width-64 shuffle dots per row, wave = row).
//  blk <  4416 : weights->bf16 (wcat q|kv|sr, then pw).
//  else        : CPB table MLP row (4096 rows).
// ---------------------------------------------------------------------------
__global__ __launch_bounds__(256) void prep_kernel(
    const float* __restrict__ x,
    const float* __restrict__ wg,  const float* __restrict__ wg0,
    const float* __restrict__ wg1,
    const float* __restrict__ q_w, const float* __restrict__ kv_w,
    const float* __restrict__ sr_w, const float* __restrict__ pw,
    const float* __restrict__ tbl,
    const float* __restrict__ c1w, const float* __restrict__ c1b,
    const float* __restrict__ c2w, const float* __restrict__ c2b,
    unsigned short* __restrict__ xbf, float* __restrict__ gate,
    unsigned short* __restrict__ wcat, unsigned short* __restrict__ pwbf,
    float* __restrict__ cpb)
{
    __shared__ float shpad[512];
    const int blk = blockIdx.x;
    const int t   = threadIdx.x;
    if (blk < 4096) {
        const int j = t & 63;                 // lane within wave; wave = row
        const int row = (blk << 2) + (t >> 6);
        float4 v = *(const float4*)(x + (size_t)row*256 + j*4);
        ushort4 o;
        o.x = f2bf(v.x); o.y = f2bf(v.y); o.z = f2bf(v.z); o.w = f2bf(v.w);
        *(ushort4*)(xbf + (size_t)row*256 + j*4) = o;
        float d[10];
#pragma unroll
        for (int f = 0; f < 10; ++f) {
            const float* wf = (f < 4) ? (wg + f*256) : (f < 6) ? (wg0 + (f-4)*256)
                                                               : (wg1 + (f-6)*256);
            float4 wv = *(const float4*)(wf + j*4);
            float s = v.x*wv.x + v.y*wv.y + v.z*wv.z + v.w*wv.w;
            s += __shfl_xor(s, 32); s += __shfl_xor(s, 16); s += __shfl_xor(s, 8);
            s += __shfl_xor(s, 4);  s += __shfl_xor(s, 2);  s += __shfl_xor(s, 1);
            d[f] = s;
        }
        if (j == 0) {
            float e[4];
            float m = fmaxf(fmaxf(d[0],d[1]), fmaxf(d[2],d[3]));
            float ssum = 0.f;
            for (int i = 0; i < 4; ++i) { e[i] = expf(d[i]-m); ssum += e[i]; }
            for (int i = 0; i < 4; ++i) e[i] /= ssum;
            int i1 = 0;
            for (int i = 1; i < 4; ++i) if (e[i] > e[i1]) i1 = i;
            int i2 = -1;
            for (int i = 0; i < 4; ++i) if (i != i1 && (i2 < 0 || e[i] > e[i2])) i2 = i;
            float rs = fmaxf(e[i1] + e[i2], EPSF);
            float rg[4] = {0.f,0.f,0.f,0.f};
            rg[i1] = e[i1] / rs * 2.f;
            rg[i2] = e[i2] / rs * 2.f;
            float sh[4];
            float m1 = fmaxf(fmaxf(d[6],d[7]), fmaxf(d[8],d[9]));
            float s1 = 0.f;
            for (int i = 0; i < 4; ++i) { sh[i] = expf(d[6+i]-m1); s1 += sh[i]; }
            float mm = fmaxf(d[4], d[5]);
            float e0 = expf(d[4]-mm), e1 = expf(d[5]-mm);
            float w00 = e0/(e0+e1)*2.f, w01 = e1/(e0+e1)*2.f;
            float* gr = gate + ((size_t)row << 3);
            for (int i = 0; i < 4; ++i) gr[i]   = w00 * (sh[i]/s1*4.f);
            for (int i = 0; i < 4; ++i) gr[4+i] = w01 * rg[i];
        }
    } else if (blk < 4416) {
        const int e = ((blk - 4096)*256 + t)*4;
        if (e < 262144) {
            int n = e >> 8, k = e & 255;
            const float* src = (n < 256) ? (q_w + n*256) :
                               (n < 768) ? (kv_w + (n-256)*256) : (sr_w + (n-768)*256);
            float4 v = *(const float4*)(src + k);
            ushort4 o;
            o.x = f2bf(v.x); o.y = f2bf(v.y); o.z = f2bf(v.z); o.w = f2bf(v.w);
            *(ushort4*)(wcat + e) = o;
        } else {
            int e2 = e - 262144;
            float4 v = *(const float4*)(pw + e2);
            ushort4 o;
            o.x = f2bf(v.x); o.y = f2bf(v.y); o.z = f2bf(v.z); o.w = f2bf(v.w);
            *(ushort4*)(pwbf + e2) = o;
        }
    } else {
        const int r = blk - 4416;
        const float c0 = tbl[(size_t)r*2], c1 = tbl[(size_t)r*2+1];
        for (int i = t; i < 512; i += 256)
            shpad[i] = fmaxf(c0*c1w[i*2] + c1*c1w[i*2+1] + c1b[i], 0.f);
        __syncthreads();
        const int hh = t >> 5, dd = t & 31;
        float s = 0.f;
        for (int i = dd; i < 512; i += 32) s += shpad[i] * c2w[hh*512+i];
        for (int off = 16; off; off >>= 1) s += __shfl_xor(s, off, 32);
        if (dd == 0) cpb[((size_t)r << 3) + hh] = s + c2b[hh];
    }
}

// ---------------------------------------------------------------------------
// MFMA bf16 GEMM, K=256, single K-pass (R8 structure, unchanged).
// ---------------------------------------------------------------------------
__global__ __launch_bounds__(256) void gemm_mfma(
    const unsigned short* __restrict__ A,
    const unsigned short* __restrict__ W,
    const float* __restrict__ B0, const float* __restrict__ B1,
    const float* __restrict__ B2,
    int r1, int r2, int mode,
    float* __restrict__ C, int ldc,
    unsigned short* __restrict__ qkv,
    const float* __restrict__ temp, const float* __restrict__ qe)
{
    __shared__ __attribute__((aligned(16))) unsigned short At[64*264];
    __shared__ __attribute__((aligned(16))) unsigned short Bt[64*264];
    const int m0 = blockIdx.y << 6;
    const int n0 = blockIdx.x << 6;
    const int t  = threadIdx.x;
    const int w  = t >> 6;
    const int col16 = t & 15;
    const int quad  = (t & 63) >> 4;

    const float* Bp; int noff;
    if (n0 < r1)      { Bp = B0; noff = 0;  }
    else if (n0 < r2) { Bp = B1; noff = r1; }
    else              { Bp = B2; noff = r2; }

    uint4 av[8], bv[8];
#pragma unroll
    for (int j = 0; j < 8; ++j) {
        int ci = j*256 + t;
        int r = ci >> 5, c = ci & 31;
        av[j] = *(const uint4*)(A + (size_t)(m0 + r)*256 + c*8);
        bv[j] = *(const uint4*)(W + (size_t)(n0 + r)*256 + c*8);
    }
#pragma unroll
    for (int j = 0; j < 8; ++j) {
        int ci = j*256 + t;
        int r = ci >> 5, c = ci & 31;
        *(uint4*)(At + r*264 + c*8) = av[j];
        *(uint4*)(Bt + r*264 + c*8) = bv[j];
    }
    __syncthreads();

    f32x4 acc[4];
#pragma unroll
    for (int ct = 0; ct < 4; ++ct) acc[ct] = (f32x4){0.f, 0.f, 0.f, 0.f};
#pragma unroll
    for (int kk = 0; kk < 8; ++kk) {
        short8 af = *(const short8*)(At + (w*16 + col16)*264 + kk*32 + quad*8);
#pragma unroll
        for (int ct = 0; ct < 4; ++ct) {
            short8 bf = *(const short8*)(Bt + (ct*16 + col16)*264 + kk*32 + quad*8);
            acc[ct] = __builtin_amdgcn_mfma_f32_16x16x32_bf16(af, bf, acc[ct], 0, 0, 0);
        }
    }

    float bias_c[4];
#pragma unroll
    for (int ct = 0; ct < 4; ++ct)
        bias_c[ct] = Bp[n0 + ct*16 + col16 - noff];

    if (mode == 0) {
        const int region = n0 >> 8;
        float qe_c[4], spt_c[4];
        if (region == 0) {
#pragma unroll
            for (int c = 0; c < 4; ++c) {
                int col = n0 + c*16 + col16;
                spt_c[c] = log1pf(expf(temp[(col >> 5) & 7]));
                qe_c[c]  = qe[col];
            }
        }
#pragma unroll
        for (int reg = 0; reg < 4; ++reg) {
            const int row = m0 + w*16 + quad*4 + reg;
            float v[4];
#pragma unroll
            for (int c = 0; c < 4; ++c) v[c] = acc[c][reg] + bias_c[c];
            if (region <= 1) {
#pragma unroll
                for (int hp = 0; hp < 2; ++hp) {
                    float s = v[2*hp]*v[2*hp] + v[2*hp+1]*v[2*hp+1];
                    s += __shfl_xor(s, 1); s += __shfl_xor(s, 2);
                    s += __shfl_xor(s, 4); s += __shfl_xor(s, 8);
                    float inv = 1.0f / fmaxf(sqrtf(s), EPSF);
                    v[2*hp]   *= inv;
                    v[2*hp+1] *= inv;
                }
            }
            if (region == 0) {
                int n = row & 4095;
                int y = n >> 6, x = n & 63;
                int cy = (y == 0 || y == 63) ? 2 : 3;
                int cx = (x == 0 || x == 63) ? 2 : 3;
                float sls = logf((float)(cy*cx) + 64.0f);
#pragma unroll
                for (int c = 0; c < 4; ++c)
                    v[c] = (v[c] + qe_c[c]) * (spt_c[c] * sls);
            }
            if (region == 3) {
#pragma unroll
                for (int c = 0; c < 4; ++c) {
                    float g = 0.5f * v[c] * (1.0f + erff(v[c] * 0.70710678118654752f));
                    C[(size_t)row * ldc + n0 + c*16 + col16] = g;
                }
            } else {
#pragma unroll
                for (int c = 0; c < 4; ++c)
                    qkv[(size_t)row * 2048 + n0 + c*16 + col16] = f2bf(v[c]);
            }
        }
    } else {
#pragma unroll
        for (int reg = 0; reg < 4; ++reg) {
            const int row = m0 + w*16 + quad*4 + reg;
#pragma unroll
            for (int c = 0; c < 4; ++c)
                C[(size_t)row * ldc + n0 + c*16 + col16] = acc[c][reg] + bias_c[c];
        }
    }
}

// ---------------------------------------------------------------------------
// fused 8x8 avg-pool + LayerNorm + pooled kv + k-norm -> bf16 pools.
// ---------------------------------------------------------------------------
__global__ __launch_bounds__(256) void poolkv_kernel(
    const float* __restrict__ buf,
    const float* __restrict__ g, const float* __restrict__ bb,
    const float* __restrict__ kv_w, const float* __restrict__ kv_b,
    unsigned short* __restrict__ kpb, unsigned short* __restrict__ vpb)
{
    __shared__ float r1[256], r2[256];
    __shared__ float xs[256];
    __shared__ float rowv[512];
    __shared__ float inv[8];
    const int blk = blockIdx.x;          // b*64+p
    const int b = blk >> 6, p = blk & 63;
    const int py = p >> 3, px = p & 7;
    const int t = threadIdx.x;
    float acc = 0.f;
    for (int dy = 0; dy < 8; ++dy)
#pragma unroll
        for (int dx = 0; dx < 8; ++dx) {
            int s = ((py*8+dy) << 6) + px*8 + dx;
            acc += buf[(((size_t)(b*4096+s)) << 10) + 768 + t];
        }
    acc *= (1.0f/64.0f);
    r1[t] = acc; r2[t] = acc*acc;
    __syncthreads();
    for (int off = 128; off; off >>= 1) {
        if (t < off) { r1[t] += r1[t+off]; r2[t] += r2[t+off]; }
        __syncthreads();
    }
    float mu  = r1[0] * (1.0f/256.0f);
    float var = r2[0] * (1.0f/256.0f) - mu*mu;
    float rstd = rsqrtf(var + 1e-5f);
    xs[t] = (acc - mu) * rstd * g[t] + bb[t];
    __syncthreads();
    for (int o = t; o < 512; o += 256) {
        const float* wr = kv_w + ((size_t)o << 8);
        float s = kv_b[o];
        for (int k = 0; k < 256; ++k) s += xs[k]*wr[k];
        rowv[o] = s;
    }
    __syncthreads();
    if (t < 8) {
        float s = 0.f;
        for (int dd = 0; dd < 32; ++dd) { float v = rowv[t*32+dd]; s += v*v; }
        inv[t] = 1.0f / fmaxf(sqrtf(s), EPSF);
    }
    __syncthreads();
    const int h = t >> 5;
    size_t o = ((((size_t)(b*8+h))*64 + p) << 5) + (t & 31);
    kpb[o] = f2bf(rowv[t] * inv[h]);
    vpb[o] = f2bf(rowv[256 + t]);
}

// ---------------------------------------------------------------------------
// MFMA attention v5: R8 wave-local halo tiling + LDS halo-offset table
// (removes /10 %10 + bounds math from all staging loops; QS reuses it).
// ---------------------------------------------------------------------------
__global__ __launch_bounds__(256, 4) void attn_mfma(
    const unsigned short* __restrict__ qkv,   // (16384,2048) packed: q|k|v bf16
    unsigned short* __restrict__ ao,          // (16384,256) bf16
    const unsigned short* __restrict__ kpb,   // (B,H,64,32) bf16
    const unsigned short* __restrict__ vpb,
    const float* __restrict__ cpb,
    const int*   __restrict__ rpi,
    const float* __restrict__ temp,
    const float* __restrict__ qe,
    const float* __restrict__ rpb,
    const float* __restrict__ lt,    // (8,32,9)
    const float* __restrict__ lb,    // (8,1,9)
    const float* __restrict__ gate)
{
    __shared__ __attribute__((aligned(16))) unsigned short U0[112*40]; // KH -> VT[32*136]
    __shared__ __attribute__((aligned(16))) unsigned short U1[64*40];  // KP -> VPT[32*72]
    __shared__ __attribute__((aligned(16))) unsigned short QS[64*40];
    __shared__ __attribute__((aligned(16))) unsigned short P[64*136];
    __shared__ __attribute__((aligned(16))) unsigned short LTT[16*40];
    __shared__ float invscL[64], gateL[64], rpbL[9], dqvL[16];
    __shared__ int hofs[112];     // halo slot -> qkv element offset (+h*32), -1 = OOB

    const int tile = blockIdx.x;
    const int h    = blockIdx.y;
    const int b    = blockIdx.z;
    const int ty0  = (tile >> 3) << 3;
    const int tx0  = (tile & 7) << 3;
    const int t    = threadIdx.x;

    const float spt = log1pf(expf(temp[h]));
    if (t < 64) {
        int y = ty0 + (t >> 3), x = tx0 + (t & 7);
        int cy = (y == 0 || y == 63) ? 2 : 3;
        int cx = (x == 0 || x == 63) ? 2 : 3;
        invscL[t] = 1.0f / (spt * logf((float)(cy*cx) + 64.0f));
        gateL[t] = gate[(((size_t)(b*4096 + ((y<<6)|x))) << 3) + h];
    } else if (t < 80) {
        int j = t - 64;
        float s = 0.f;
        if (j < 9) {
            s = lb[h*9 + j];
            for (int dd = 0; dd < 32; ++dd)
                s -= qe[h*32+dd] * lt[(h*32+dd)*9 + j];
        }
        dqvL[j] = s;
    } else if (t < 89) {
        rpbL[t-80] = rpb[h*9 + (t-80)];
    } else if (t >= 128 && t < 240) {
        int r = t - 128;
        int off = -1;
        if (r < 100) {
            int y = ty0 + r/10 - 1, x = tx0 + r%10 - 1;
            if (y >= 0 && y < 64 && x >= 0 && x < 64)
                off = (b*4096 + ((y<<6)|x))*2048 + h*32;
        }
        hofs[r] = off;
        if (r >= 100) hofs[r] = -1;
    }
    for (int i = t; i < 16*32; i += 256) {
        int j = i >> 5, dd = i & 31;
        LTT[j*40 + dd] = (j < 9) ? f2bf(lt[(h*32+dd)*9 + j]) : (unsigned short)0;
    }
    __syncthreads();

    // ---- stage KH / KP / QS via hofs ----
    unsigned short* KH = U0;
    unsigned short* KP = U1;
    for (int i = t; i < 112*8; i += 256) {
        int r = i >> 3, sg = i & 7;
        int off = hofs[r];
        uint2 val = {0u, 0u};
        if (off >= 0)
            val = *(const uint2*)(qkv + (size_t)off + 256 + sg*4);
        *(uint2*)(KH + r*40 + sg*4) = val;
    }
    {
        const unsigned short* src = kpb + (size_t)(b*8+h)*2048;
        for (int i = t; i < 512; i += 256)
            *(uint2*)(KP + (i >> 3)*40 + (i & 7)*4) = *(const uint2*)(src + i*4);
    }
    for (int i = t; i < 512; i += 256) {
        int n = i >> 3, sg = i & 7;
        int off = hofs[(n >> 3)*10 + (n & 7) + 11];   // token's own halo slot
        *(uint2*)(QS + n*40 + sg*4) = *(const uint2*)(qkv + (size_t)off + sg*4);
    }
    __syncthreads();

    const int lane  = t & 63;
    const int w     = t >> 6;
    const int col16 = lane & 15;
    const int quad  = lane >> 4;
    const int s_w   = (20*w) & ~15;

    float pbias[4][4];
#pragma unroll
    for (int ct = 0; ct < 4; ++ct) {
        int p = ct*16 + col16;
#pragma unroll
        for (int reg = 0; reg < 4; ++reg) {
            int n = w*16 + quad*4 + reg;
            int y = ty0 + (n >> 3), x = tx0 + (n & 7);
            int ngl = (y << 6) | x;
            pbias[ct][reg] = cpb[((size_t)rpi[(size_t)ngl*64 + p] << 3) + h];
        }
    }

    short8 aq = *(const short8*)(QS + (w*16 + col16)*40 + quad*8);
    f32x4 cl[4], cp[4];
    {
        const f32x4 z = {0.f, 0.f, 0.f, 0.f};
#pragma unroll
        for (int ct = 0; ct < 4; ++ct) {
            short8 bk = *(const short8*)(KH + (s_w + ct*16 + col16)*40 + quad*8);
            cl[ct] = __builtin_amdgcn_mfma_f32_16x16x32_bf16(aq, bk, z, 0, 0, 0);
        }
#pragma unroll
        for (int ct = 0; ct < 4; ++ct) {
            short8 bp = *(const short8*)(KP + (ct*16 + col16)*40 + quad*8);
            cp[ct] = __builtin_amdgcn_mfma_f32_16x16x32_bf16(aq, bp, z, 0, 0, 0);
        }
    }
#pragma unroll
    for (int ct = 0; ct < 4; ++ct) {
        int hk = s_w + ct*16 + col16;
        int ky = hk / 10, kx = hk - ky*10;
#pragma unroll
        for (int reg = 0; reg < 4; ++reg) {
            int n = w*16 + quad*4 + reg;
            int dy = ky - (n >> 3), dx = kx - (n & 7);
            bool valid = (dy >= 0 && dy <= 2 && dx >= 0 && dx <= 2);
            cl[ct][reg] = valid ? (cl[ct][reg] + rpbL[dy*3 + dx]) : -1e30f;
        }
    }
#pragma unroll
    for (int ct = 0; ct < 4; ++ct)
#pragma unroll
        for (int reg = 0; reg < 4; ++reg)
            cp[ct][reg] += pbias[ct][reg];
    float inv[4];
#pragma unroll
    for (int reg = 0; reg < 4; ++reg) {
        float m = -1e30f;
#pragma unroll
        for (int ct = 0; ct < 4; ++ct) m = fmaxf(m, cl[ct][reg]);
#pragma unroll
        for (int ct = 0; ct < 4; ++ct) m = fmaxf(m, cp[ct][reg]);
        m = fmaxf(m, __shfl_xor(m, 1)); m = fmaxf(m, __shfl_xor(m, 2));
        m = fmaxf(m, __shfl_xor(m, 4)); m = fmaxf(m, __shfl_xor(m, 8));
        float s = 0.f;
#pragma unroll
        for (int ct = 0; ct < 4; ++ct) {
            float e = __builtin_expf(cl[ct][reg] - m); cl[ct][reg] = e; s += e;
        }
#pragma unroll
        for (int ct = 0; ct < 4; ++ct) {
            float e = __builtin_expf(cp[ct][reg] - m); cp[ct][reg] = e; s += e;
        }
        s += __shfl_xor(s, 1); s += __shfl_xor(s, 2);
        s += __shfl_xor(s, 4); s += __shfl_xor(s, 8);
        inv[reg] = 1.0f / s;
    }
#pragma unroll
    for (int ct = 0; ct < 4; ++ct)
#pragma unroll
        for (int reg = 0; reg < 4; ++reg) {
            int n = w*16 + quad*4 + reg;
            P[n*136 + ct*16 + col16] = f2bf(cl[ct][reg] * inv[reg]);
        }
#pragma unroll
    for (int ct = 0; ct < 4; ++ct)
#pragma unroll
        for (int reg = 0; reg < 4; ++reg) {
            int n = w*16 + quad*4 + reg;
            P[n*136 + 64 + ct*16 + col16] = f2bf(cp[ct][reg] * inv[reg]);
        }
    {
        const f32x4 z = {0.f, 0.f, 0.f, 0.f};
        short8 blt = *(const short8*)(LTT + col16*40 + quad*8);
        f32x4 cd = __builtin_amdgcn_mfma_f32_16x16x32_bf16(aq, blt, z, 0, 0, 0);
        if (col16 < 9) {
            int dy = col16 / 3, dx = col16 - dy*3;
#pragma unroll
            for (int reg = 0; reg < 4; ++reg) {
                int n = w*16 + quad*4 + reg;
                float ltv = cd[reg] * invscL[n] + dqvL[col16];
                int hk = ((n >> 3) + dy)*10 + (n & 7) + dx;
                int pc = hk - s_w;
                P[n*136 + pc] = f2bf(bf2f(P[n*136 + pc]) + ltv);
            }
        }
    }
    __syncthreads();

    unsigned short* VT  = U0;   // [32][136]
    unsigned short* VPT = U1;   // [32][72]
    for (int i = t; i < 1792; i += 256) {
        int rlo = i & 15, rest = i >> 4;
        int dp = rest & 15, r = (rest >> 4)*16 + rlo;
        int off = hofs[r];
        unsigned val = 0;
        if (off >= 0)
            val = *(const unsigned*)(qkv + (size_t)off + 512 + dp*2);
        VT[(2*dp)*136 + r]   = (unsigned short)(val & 0xffffu);
        VT[(2*dp+1)*136 + r] = (unsigned short)(val >> 16);
    }
    for (int i = t; i < 1024; i += 256) {
        int plo = i & 15, rest = i >> 4;
        int dp = rest & 15, p = (rest >> 4)*16 + plo;
        unsigned val = *(const unsigned*)(vpb + (size_t)(b*8+h)*2048 + p*32 + dp*2);
        VPT[(2*dp)*72 + p]   = (unsigned short)(val & 0xffffu);
        VPT[(2*dp+1)*72 + p] = (unsigned short)(val >> 16);
    }
    __syncthreads();

    f32x4 o0 = {0.f,0.f,0.f,0.f}, o1 = {0.f,0.f,0.f,0.f};
#pragma unroll
    for (int ks = 0; ks < 4; ++ks) {
        short8 a = *(const short8*)(P + (w*16 + col16)*136 + ks*32 + quad*8);
        short8 b0, b1;
        if (ks < 2) {
            b0 = *(const short8*)(VT + col16*136      + s_w + ks*32 + quad*8);
            b1 = *(const short8*)(VT + (16+col16)*136 + s_w + ks*32 + quad*8);
        } else {
            b0 = *(const short8*)(VPT + col16*72      + (ks-2)*32 + quad*8);
            b1 = *(const short8*)(VPT + (16+col16)*72 + (ks-2)*32 + quad*8);
        }
        o0 = __builtin_amdgcn_mfma_f32_16x16x32_bf16(a, b0, o0, 0, 0, 0);
        o1 = __builtin_amdgcn_mfma_f32_16x16x32_bf16(a, b1, o1, 0, 0, 0);
    }
#pragma unroll
    for (int reg = 0; reg < 4; ++reg) {
        int n = w*16 + quad*4 + reg;
        int y = ty0 + (n >> 3), x = tx0 + (n & 7);
        size_t rowo = (size_t)(b*4096 + ((y<<6)|x))*256 + h*32;
        float g = gateL[n];
        ao[rowo + col16]      = f2bf(o0[reg] * g);
        ao[rowo + 16 + col16] = f2bf(o1[reg] * g);
    }
}

// ---------------------------------------------------------------------------
extern "C" void kernel_launch(void* const* d_in, const int* in_sizes, int n_in,
                              void* d_out, int out_size, void* d_ws, size_t ws_size,
                              hipStream_t stream)
{
    const float* x    = (const float*)d_in[0];
    const float* tbl  = (const float*)d_in[1];
    const float* q_w  = (const float*)d_in[2];
    const float* q_b  = (const float*)d_in[3];
    const float* kv_w = (const float*)d_in[4];
    const float* kv_b = (const float*)d_in[5];
    const float* temp = (const float*)d_in[6];
    const float* qe   = (const float*)d_in[7];
    const float* rpb  = (const float*)d_in[8];
    const float* lt   = (const float*)d_in[9];
    const float* lb   = (const float*)d_in[10];
    const float* c1w  = (const float*)d_in[11];
    const float* c1b  = (const float*)d_in[12];
    const float* c2w  = (const float*)d_in[13];
    const float* c2b  = (const float*)d_in[14];
    const float* sr_w = (const float*)d_in[15];
    const float* sr_b = (const float*)d_in[16];
    const float* ng   = (const float*)d_in[17];
    const float* nbias= (const float*)d_in[18];
    const float* wg   = (const float*)d_in[19];
    const float* wg0  = (const float*)d_in[20];
    const float* wg1  = (const float*)d_in[21];
    const float* pw   = (const float*)d_in[22];
    const float* pb   = (const float*)d_in[23];
    const int*   rpi  = (const int*)d_in[24];
    (void)in_sizes; (void)n_in; (void)out_size; (void)ws_size;

    float* buf   = (float*)d_ws;                       // 16384x1024 f32 layout
    unsigned short* qkvb = (unsigned short*)d_ws;      // (16384, 2048) ushort view
    float* xp    = buf + (size_t)16384*1024;
    float* kpoolf= xp + 65536;
    unsigned short* kpb = (unsigned short*)kpoolf;
    unsigned short* vpb = kpb + 131072;
    float* cpbb  = kpoolf + 131072;
    float* gateb = cpbb + 32768;
    unsigned short* xbf  = (unsigned short*)(gateb + 131072);
    unsigned short* ao   = xbf;                        // reuses x_bf (dead after gemm1)
    unsigned short* wcat = xbf + (size_t)16384*256;
    unsigned short* pwbf = wcat + 262144;
    float* out   = (float*)d_out;

    // 1) prep: x->bf16 + gates | weights->bf16 | cpb table
    prep_kernel<<<8512,256,0,stream>>>(x, wg, wg0, wg1, q_w, kv_w, sr_w, pw,
                                       tbl, c1w, c1b, c2w, c2b,
                                       xbf, gateb, wcat, pwbf, cpbb);
    // 2) fused MFMA GEMM -> packed bf16 q(scaled)|k(normed)|v + f32 gelu(sr)
    gemm_mfma<<<dim3(16,256),256,0,stream>>>(xbf, wcat, q_b, kv_b, sr_b,
                                             256, 768, 0, buf, 1024,
                                             qkvb, temp, qe);
    // 3) pool + LN + pooled kv (bf16 out)
    poolkv_kernel<<<256,256,0,stream>>>(buf, ng, nbias, kv_w, kv_b, kpb, vpb);
    // 4) MFMA attention -> bf16 compact
    attn_mfma<<<dim3(64,8,4),256,0,stream>>>(qkvb, ao, kpb, vpb, cpbb, rpi,
                                             temp, qe, rpb, lt, lb, gateb);
    // 5) output projection (MFMA)
    gemm_mfma<<<dim3(4,256),256,0,stream>>>(ao, pwbf, pb, pb, pb,
                                            1<<30, 1<<30, 1, out, 256,
                                            (unsigned short*)nullptr, nullptr, nullptr);
}